// Round 6
// baseline (515.879 us; speedup 1.0000x reference)
//
#include <hip/hip_runtime.h>
#include <math.h>
#include <stddef.h>

#define NHEAD 4
#define DHEAD 40
#define HIDW 160
#define JKW 320
#define NGRAPH 32
#define BCAP 64   // edge bucket capacity per node (deg ~ Poisson(10); P(>63) ~ 1e-31)

typedef __attribute__((ext_vector_type(8))) short short8;
typedef __attribute__((ext_vector_type(4))) float f32x4;
typedef __attribute__((ext_vector_type(2))) float f32x2;
typedef __fp16 h2 __attribute__((ext_vector_type(2)));
typedef int i32x4 __attribute__((ext_vector_type(4)));
typedef int i32x2 __attribute__((ext_vector_type(2)));
typedef i32x4 i32x4_a4 __attribute__((aligned(4)));
typedef i32x2 i32x2_a4 __attribute__((aligned(4)));

__device__ inline unsigned short f2bf(float x){
  unsigned u = __float_as_uint(x);
  u += 0x7fff + ((u >> 16) & 1);
  return (unsigned short)(u >> 16);
}
__device__ inline float bf2f(unsigned short h){
  return __uint_as_float(((unsigned)h) << 16);
}
__device__ inline float fdot2(h2 a, h2 b, float c){
  return __builtin_amdgcn_fdot2(a, b, c, false);
}
__device__ inline h2 pk(float a, float b){
  return __builtin_amdgcn_cvt_pkrtz(a, b);
}
union HU { h2 h; int i; unsigned u; float f; };
__device__ inline h2 shfl_h2(h2 v, int xm){
  HU u; u.h = v; u.i = __shfl_xor(u.i, xm); return u.h;
}
__device__ inline h2 asH2(int i){ HU u; u.i = i; return u.h; }

__device__ inline int lbound(const int* __restrict__ b, int N, int g){
  int lo = 0, hi = N;
  while (lo < hi){ int mid = (lo + hi) >> 1; if (b[mid] < g) lo = mid + 1; else hi = mid; }
  return lo;
}

// ---------------- fused pre-pass: zero buffers + lin_in + weight pack ----------------
__global__ __launch_bounds__(256) void k_pre(const float* __restrict__ x, const float* __restrict__ W_in,
                                             const float* __restrict__ b_in, unsigned short* __restrict__ hb,
                                             const float* __restrict__ Wq, const float* __restrict__ Wk,
                                             const float* __restrict__ Wv, const float* __restrict__ Ws,
                                             const float* __restrict__ bq, const float* __restrict__ bk,
                                             const float* __restrict__ bv, const float* __restrict__ bs,
                                             const float* __restrict__ Wg1,
                                             unsigned short* __restrict__ Bth, float* __restrict__ bp,
                                             unsigned short* __restrict__ Btgh,
                                             int* __restrict__ cnt, float* __restrict__ gate,
                                             float* __restrict__ pooled, int N){
  int NL = (N*HIDW + 255)/256;
  int bid = blockIdx.x, tid = threadIdx.x;
  if (bid < NL){
    int idx = bid*256 + tid;
    if (idx >= N*HIDW) return;
    int n = idx / HIDW, j = idx % HIDW;
    const float* xr = x + n*5;
    float v = b_in[j];
    #pragma unroll
    for (int c = 0; c < 5; ++c) v += xr[c] * W_in[c*HIDW + j];
    hb[(size_t)n*JKW + j] = f2bf(v);
  } else if (bid < NL + 1005){
    int idx = (bid - NL)*256 + tid;
    if (idx < 204800){
      int l = idx / 102400, r = idx % 102400;
      int j = r / 160, i = r % 160;
      int sel = j / HIDW, jj = j % HIDW;
      const float* W = (sel==0) ? Wq : (sel==1) ? Wk : (sel==2) ? Wv : Ws;
      Bth[(size_t)l*102400 + (size_t)j*160 + i] = f2bf(W[(size_t)l*25600 + i*HIDW + jj]);
    } else if (idx < 256000){
      int r = idx - 204800;
      int j = r / 320, i = r % 320;
      Btgh[(size_t)j*320 + i] = f2bf(Wg1[(size_t)i*160 + j]);
    } else if (idx < 257280){
      int r = idx - 256000;
      int l = r / 640, j = r % 640;
      int sel = j / HIDW, jj = j % HIDW;
      const float* bb = (sel==0) ? bq : (sel==1) ? bk : (sel==2) ? bv : bs;
      bp[l*640 + j] = bb[l*160 + jj];
    }
  } else {
    int idx = (bid - NL - 1005)*256 + tid;
    if (idx < N){ cnt[idx] = 0; gate[idx] = 0.f; }
    if (idx < NGRAPH*JKW) pooled[idx] = 0.f;
  }
}

// ---------------- bucketed edge fill ----------------
__global__ __launch_bounds__(256) void k_fill(const int* __restrict__ dst, const int* __restrict__ src,
                                              const float* __restrict__ edge_attr, int E,
                                              int* __restrict__ cnt, int* __restrict__ esrc,
                                              uint2* __restrict__ eattr){
  int e = blockIdx.x*256 + threadIdx.x;
  if (e < E){
    int d = dst[e];
    int p = atomicAdd(&cnt[d], 1);
    if (p < BCAP){
      int slot = d*BCAP + p;
      esrc[slot] = src[e];
      float4 ea = *(const float4*)(edge_attr + (size_t)e*4);
      HU a, b; a.h = pk(ea.x, ea.y); b.h = pk(ea.z, ea.w);
      eattr[slot] = make_uint2(a.u, b.u);
    }
  }
}

// ---------------- bf16 MFMA GEMM v7: dbuf LDS B staging + XCD-pinned row-blocks ----------------
// MODE 1 (QKV): sel 0 -> qh fp16 (scale folded); sel 3 -> rskip fp16;
//               sel 1/2 (k,v) -> fp16 kvh[row*320 + slot*20 + (v?10:0)+j]
// MODE 2 (gate): gate[row] += sum_col relu(acc+bg1[col])*Wg2[col]
// v7: in-kernel bijective block remap (XCD L2 pinning). v8: kv stored fp16
// (was fp8) -- removes 10 cvt_pk_f16_fp8/lane-iter from k_attn's chain.
#define BSTR 40
template<int NSUB, int MODE>
__global__ __launch_bounds__(256) void k_mgemm(const unsigned short* __restrict__ A, int lda,
                                               const unsigned short* __restrict__ Bh,
                                               const float* __restrict__ bias,
                                               _Float16* __restrict__ qh,
                                               _Float16* __restrict__ kvh,
                                               _Float16* __restrict__ rskip,
                                               const float* __restrict__ Wg2,
                                               float* __restrict__ gate,
                                               int M, int K){
  __shared__ short sBh[2][16*NSUB*BSTR];
  int tid = threadIdx.x;
  int wv = tid >> 6, lane = tid & 63;
  int quad = lane >> 4, l16 = lane & 15;

  int P = gridDim.x, MBy = gridDim.y;
  int bid = blockIdx.y * P + blockIdx.x;       // dispatch-order linear id
  int fullRows = (MBy >> 3) << 3;
  int rowB, panel;
  if (bid < fullRows * P){
    int group = bid / (8*P), rem = bid % (8*P);
    rowB  = group*8 + (rem & 7);
    panel = rem >> 3;
  } else {
    int rem = bid - fullRows*P;
    int R = MBy - fullRows;                    // 1..7 tail rows
    panel = rem / R;
    rowB  = fullRows + rem % R;
  }
  int m0 = rowB*128 + wv*32;
  int col0 = panel * (16*NSUB);

  int ar0 = m0 + l16;      if (ar0 >= M) ar0 = M - 1;
  int ar1 = m0 + 16 + l16; if (ar1 >= M) ar1 = M - 1;
  const unsigned short* Ap0 = A + (size_t)ar0*lda + quad*8;
  const unsigned short* Ap1 = A + (size_t)ar1*lda + quad*8;

  f32x4 acc[2][NSUB];
  #pragma unroll
  for (int g = 0; g < 2; ++g)
    #pragma unroll
    for (int s = 0; s < NSUB; ++s) acc[g][s] = (f32x4){0.f,0.f,0.f,0.f};

  const int CH = K >> 5;
  for (int u = tid; u < 16*NSUB*4; u += 256){
    int col = u >> 2, q4 = u & 3;
    *(short8*)(&sBh[0][col*BSTR + q4*8]) =
      *(const short8*)(Bh + (size_t)(col0 + col)*K + q4*8);
  }
  __syncthreads();

  int buf = 0;
  for (int kk = 0; kk < CH; ++kk){
    int k0 = kk << 5;
    if (kk + 1 < CH){
      int kn = k0 + 32;
      for (int u = tid; u < 16*NSUB*4; u += 256){
        int col = u >> 2, q4 = u & 3;
        *(short8*)(&sBh[buf^1][col*BSTR + q4*8]) =
          *(const short8*)(Bh + (size_t)(col0 + col)*K + kn + q4*8);
      }
    }
    short8 ah0 = *(const short8*)(Ap0 + k0);
    short8 ah1 = *(const short8*)(Ap1 + k0);
    #pragma unroll
    for (int s = 0; s < NSUB; ++s){
      short8 bh = *(const short8*)(&sBh[buf][(s*16 + l16)*BSTR + quad*8]);
      acc[0][s] = __builtin_amdgcn_mfma_f32_16x16x32_bf16(ah0, bh, acc[0][s], 0, 0, 0);
      acc[1][s] = __builtin_amdgcn_mfma_f32_16x16x32_bf16(ah1, bh, acc[1][s], 0, 0, 0);
    }
    __syncthreads();
    buf ^= 1;
  }

  const float qscale = 0.15811388300841898f; // 1/sqrt(40)
  if (MODE == 1){
    #pragma unroll
    for (int g = 0; g < 2; ++g){
      #pragma unroll
      for (int s = 0; s < NSUB; ++s){
        int col = col0 + s*16 + l16;
        float bv = bias[col];
        int sel = col / 160, cc = col % 160;
        #pragma unroll
        for (int r = 0; r < 4; ++r){
          int row = m0 + g*16 + quad*4 + r;
          if (row >= M) continue;
          float v = acc[g][s][r] + bv;
          if (sel == 0)      qh[(size_t)row*160 + cc] = (_Float16)(v * qscale);
          else if (sel == 3) rskip[(size_t)row*160 + cc] = (_Float16)v;
          else {
            int slot = (cc/40)*4 + (cc%40)/10, j = cc%10;
            kvh[(size_t)row*320 + slot*20 + (sel==2?10:0) + j] = (_Float16)v;
          }
        }
      }
    }
  } else {
    float pg[2][4];
    #pragma unroll
    for (int g = 0; g < 2; ++g)
      #pragma unroll
      for (int r = 0; r < 4; ++r) pg[g][r] = 0.f;
    #pragma unroll
    for (int s = 0; s < NSUB; ++s){
      int col = col0 + s*16 + l16;
      float bv = bias[col], wg = Wg2[col];
      #pragma unroll
      for (int g = 0; g < 2; ++g)
        #pragma unroll
        for (int r = 0; r < 4; ++r)
          pg[g][r] += fmaxf(acc[g][s][r] + bv, 0.f) * wg;
    }
    #pragma unroll
    for (int g = 0; g < 2; ++g)
      #pragma unroll
      for (int r = 0; r < 4; ++r){
        float v = pg[g][r];
        v += __shfl_xor(v, 1); v += __shfl_xor(v, 2);
        v += __shfl_xor(v, 4); v += __shfl_xor(v, 8);
        int row = m0 + g*16 + quad*4 + r;
        if (l16 == 0 && row < M) atomicAdd(&gate[row], v);
      }
  }
}

// ---------------- per-node q-projection precompute ----------------
__global__ __launch_bounds__(256) void k_qprep(const _Float16* __restrict__ qh,
                                               const float* __restrict__ We, const float* __restrict__ be,
                                               float* __restrict__ qwb, int N){
  int idx = blockIdx.x*256 + threadIdx.x;
  if (idx >= N*4) return;
  int n = idx >> 2, h = idx & 3;
  const _Float16* qp = qh + (size_t)n*160 + h*40;
  float w0=0.f,w1=0.f,w2=0.f,w3=0.f,b=0.f;
  #pragma unroll
  for (int d = 0; d < 40; ++d){
    float q = (float)qp[d];
    int c = h*40 + d;
    w0 += q*We[c];     w1 += q*We[160+c];
    w2 += q*We[320+c]; w3 += q*We[480+c];
    b  += q*be[c];
  }
  float* o = qwb + (size_t)idx*5;
  o[0]=w0; o[1]=w1; o[2]=w2; o[3]=w3; o[4]=b;
}

// ---------------- fused edge attention + beta gate (fp16 kv, no-max softmax) ----------------
// scores are O(1) (0.05-scale weights) -> exp never overflows -> max-shift dropped (exact)
// v5: kv in fp16 -- loaded dwords feed fdot2 / v_pk_fma directly (no cvt8 on
//     the load->use chain). Pipeline: eattr +3, kv +2 (unchanged from v4).
__global__ __launch_bounds__(256) void k_attn(const _Float16* __restrict__ qh,
                                              const _Float16* __restrict__ kvh,
                                              const _Float16* __restrict__ rskip,
                                              const float* __restrict__ qwb,
                                              const uint2* __restrict__ eattr,
                                              const int* __restrict__ esrc,
                                              const int* __restrict__ cnt,
                                              const float* __restrict__ We, const float* __restrict__ be,
                                              const float* __restrict__ Wb,
                                              unsigned short* __restrict__ hb,
                                              int loff, int N){
  int n = blockIdx.x*4 + (threadIdx.x >> 6);
  if (n >= N) return;
  int lane = threadIdx.x & 63;
  int g4 = lane >> 4;
  int w  = lane & 15;
  int hh = w & 3, t = w >> 2;
  int cbase = DHEAD*hh + 10*t;
  int slot = hh*4 + t;

  h2 qh2[5];
  {
    const unsigned* qp = (const unsigned*)(qh + (size_t)n*160 + cbase);
    #pragma unroll
    for (int i = 0; i < 5; ++i){ HU u; u.u = qp[i]; qh2[i] = u.h; }
  }
  const float* qwp = qwb + ((size_t)n*4 + hh)*5;
  float qw0 = qwp[0], qw1 = qwp[1], qw2 = qwp[2], qw3 = qwp[3], qb = qwp[4];
  h2 qw01 = pk(qw0, qw1), qw23 = pk(qw2, qw3);

  float ssum = 0.f;
  h2 zh = pk(0.f, 0.f);
  h2 acch[5], sah[2];
  #pragma unroll
  for (int i = 0; i < 5; ++i) acch[i] = zh;
  sah[0] = zh; sah[1] = zh;

  int deg = cnt[n]; if (deg > BCAP) deg = BCAP;
  int st = n*BCAP, en = st + deg;
  int B = (deg + 3) >> 2;

  // pipeline state: A = processing, B = kv in flight, C = eattr arrived / kv issuing
  int snA=0, snB=0, snC=0; bool vA=false, vB=false, vC=false;
  h2 eaA0=zh, eaA1=zh, eaB0=zh, eaB1=zh, eaC0=zh, eaC1=zh;
  {
    int p0 = st + g4;       vA = (p0 < en);
    if (vA){ snA = esrc[p0]; uint2 e = eattr[p0]; HU a,b; a.u=e.x; b.u=e.y; eaA0=a.h; eaA1=b.h; }
    int p1 = st + 4 + g4;   vB = (p1 < en);
    if (vB){ snB = esrc[p1]; uint2 e = eattr[p1]; HU a,b; a.u=e.x; b.u=e.y; eaB0=a.h; eaB1=b.h; }
    int p2 = st + 8 + g4;   vC = (p2 < en);
    if (vC){ snC = esrc[p2]; uint2 e = eattr[p2]; HU a,b; a.u=e.x; b.u=e.y; eaC0=a.h; eaC1=b.h; }
  }
  // kv fragment per (edge,slot): 20 fp16 = k(5 dwords) + v(5 dwords)
  i32x4 cA0={0,0,0,0}, cA1={0,0,0,0}, cB0={0,0,0,0}, cB1={0,0,0,0};
  i32x2 cA2={0,0}, cB2={0,0};
  if (vA){
    const _Float16* kp = kvh + (size_t)snA*320 + slot*20;
    cA0 = *(const i32x4_a4*)kp; cA1 = *(const i32x4_a4*)(kp+8); cA2 = *(const i32x2_a4*)(kp+16);
  }
  if (vB){
    const _Float16* kp = kvh + (size_t)snB*320 + slot*20;
    cB0 = *(const i32x4_a4*)kp; cB1 = *(const i32x4_a4*)(kp+8); cB2 = *(const i32x2_a4*)(kp+16);
  }

  for (int b = 0; b < B; ++b){
    // prefetch eattr/esrc for edge b+3
    int snD = 0; h2 eaD0 = zh, eaD1 = zh; bool vD;
    int p3 = st + (b+3)*4 + g4;
    vD = (p3 < en);
    if (vD){ snD = esrc[p3]; uint2 e = eattr[p3]; HU a,b2; a.u=e.x; b2.u=e.y; eaD0=a.h; eaD1=b2.h; }
    // prefetch kv for edge b+2 (snC arrived last iteration)
    i32x4 cC0 = {0,0,0,0}, cC1 = {0,0,0,0}; i32x2 cC2 = {0,0};
    if (vC){
      const _Float16* kp = kvh + (size_t)snC*320 + slot*20;
      cC0 = *(const i32x4_a4*)kp; cC1 = *(const i32x4_a4*)(kp+8); cC2 = *(const i32x2_a4*)(kp+16);
    }
    // compute on A (kv issued 2 iterations ago) -- fp16 direct, no cvt
    float p = 0.f;
    if (vA){
      p = fdot2(qh2[0], asH2(cA0.x), p);
      p = fdot2(qh2[1], asH2(cA0.y), p);
      p = fdot2(qh2[2], asH2(cA0.z), p);
      p = fdot2(qh2[3], asH2(cA0.w), p);
      p = fdot2(qh2[4], asH2(cA1.x), p);
    }
    p += __shfl_xor(p, 4);
    p += __shfl_xor(p, 8);
    p += qb;
    p = fdot2(eaA0, qw01, p);
    p = fdot2(eaA1, qw23, p);

    if (vA){
      float ex = __expf(p);
      ssum += ex;
      h2 eh = pk(ex, ex);
      acch[0] += asH2(cA1.y)*eh;
      acch[1] += asH2(cA1.z)*eh;
      acch[2] += asH2(cA1.w)*eh;
      acch[3] += asH2(cA2.x)*eh;
      acch[4] += asH2(cA2.y)*eh;
      sah[0] += eaA0*eh;
      sah[1] += eaA1*eh;
    }
    snA = snB; vA = vB; eaA0 = eaB0; eaA1 = eaB1; cA0 = cB0; cA1 = cB1; cA2 = cB2;
    snB = snC; vB = vC; eaB0 = eaC0; eaB1 = eaC1; cB0 = cC0; cB1 = cC1; cB2 = cC2;
    snC = snD; vC = vD; eaC0 = eaD0; eaC1 = eaD1;
  }

  // merge the 4 edge-slots: butterfly -> EVERY lane holds the full sums
  #pragma unroll
  for (int xm = 16; xm < 64; xm <<= 1){
    ssum += __shfl_xor(ssum, xm);
    #pragma unroll
    for (int i = 0; i < 5; ++i) acch[i] += shfl_h2(acch[i], xm);
    sah[0] += shfl_h2(sah[0], xm);
    sah[1] += shfl_h2(sah[1], xm);
  }

  // distributed epilogue: lane (g4, w) handles cols cbase + {g4, g4+4, g4+8}
  {
    float inv = (ssum > 0.f) ? 1.f/ssum : 0.f;
    float sw0 = (float)sah[0].x*inv, sw1 = (float)sah[0].y*inv;
    float sw2 = (float)sah[1].x*inv, sw3 = (float)sah[1].y*inv;
    float bterm = (ssum > 0.f) ? 1.f : 0.f;

    // accf[j] for j = g4 + 4*jj, selected without runtime register indexing
    float a0 = (g4==0) ? (float)acch[0].x : (g4==1) ? (float)acch[0].y
             : (g4==2) ? (float)acch[1].x : (float)acch[1].y;     // j = g4
    float a1 = (g4==0) ? (float)acch[2].x : (g4==1) ? (float)acch[2].y
             : (g4==2) ? (float)acch[3].x : (float)acch[3].y;     // j = g4+4
    float a2 = (g4==0) ? (float)acch[4].x : (float)acch[4].y;     // j = g4+8 (g4<2 only)

    const _Float16* rp = rskip + (size_t)n*160 + cbase;
    float ov[3], rrv[3];
    float part = 0.f;
    #pragma unroll
    for (int jj = 0; jj < 3; ++jj){
      int j = g4 + 4*jj;
      float aj = (jj==0) ? a0 : (jj==1) ? a1 : a2;
      ov[jj] = 0.f; rrv[jj] = 0.f;
      if (j < 10){
        int c = cbase + j;
        float o = aj*inv + sw0*We[c] + sw1*We[160+c] + sw2*We[320+c] + sw3*We[480+c] + bterm*be[c];
        float r = (float)rp[j];
        ov[jj] = o; rrv[jj] = r;
        part += o*Wb[c] + r*Wb[160+c] + (o-r)*Wb[320+c];
      }
    }
    #pragma unroll
    for (int xm = 1; xm < 64; xm <<= 1) part += __shfl_xor(part, xm);
    float beta = 1.f/(1.f + __expf(-part));
    unsigned short* hp = hb + (size_t)n*JKW + loff + cbase;
    #pragma unroll
    for (int jj = 0; jj < 3; ++jj){
      int j = g4 + 4*jj;
      if (j < 10) hp[j] = f2bf(beta*rrv[jj] + (1.f-beta)*ov[jj]);
    }
  }
}

// ---------------- attention pooling with inline per-graph stats ----------------
__global__ __launch_bounds__(320) void k_pool(const unsigned short* __restrict__ hb, const float* __restrict__ gate,
                                              const int* __restrict__ batch, int N,
                                              float* __restrict__ pooled){
  __shared__ float sm[320];
  int g = blockIdx.x, part = blockIdx.y, j = threadIdx.x;
  int lo = lbound(batch, N, g), hi = lbound(batch, N, g+1);
  int len = hi - lo;
  if (len <= 0) return;
  float m = -INFINITY;
  for (int i = lo + j; i < hi; i += 320) m = fmaxf(m, gate[i]);
  sm[j] = m; __syncthreads();
  #pragma unroll
  for (int off = 256; off; off >>= 1){
    if (j < off && j + off < 320) sm[j] = fmaxf(sm[j], sm[j+off]);
    __syncthreads();
  }
  float gm = sm[0]; __syncthreads();
  float s = 0.f;
  for (int i = lo + j; i < hi; i += 320) s += __expf(gate[i] - gm);
  sm[j] = s; __syncthreads();
  #pragma unroll
  for (int off = 256; off; off >>= 1){
    if (j < off && j + off < 320) sm[j] += sm[j+off];
    __syncthreads();
  }
  float dg = sm[0];
  float invd = (dg > 0.f) ? 1.f/dg : 0.f;

  int chunk = (len + (int)gridDim.y - 1) / (int)gridDim.y;
  int a = lo + part*chunk;
  int bnd = a + chunk; if (bnd > hi) bnd = hi;
  if (a >= bnd) return;
  float acc = 0.f;
  for (int n = a; n < bnd; ++n){
    float at = __expf(gate[n] - gm);
    acc += at * bf2f(hb[(size_t)n*JKW + j]);
  }
  atomicAdd(&pooled[g*JKW + j], acc*invd);
}

__global__ __launch_bounds__(320) void k_head(const float* __restrict__ pooled, const float* __restrict__ Wh1,
                                              const float* __restrict__ bh1, const float* __restrict__ Wh2,
                                              const float* __restrict__ bh2, float* __restrict__ out){
  __shared__ float p[320];
  __shared__ float t[320];
  int g = blockIdx.x, tid = threadIdx.x;
  p[tid] = pooled[g*JKW + tid]; __syncthreads();
  float a = bh1[tid];
  for (int i = 0; i < 320; ++i) a += p[i]*Wh1[i*JKW + tid];
  t[tid] = fmaxf(a, 0.f); __syncthreads();
  if (tid < 6){
    float o = bh2[tid];
    for (int j = 0; j < 320; ++j) o += t[j]*Wh2[j*6 + tid];
    out[g*6 + tid] = o;
  }
}

extern "C" void kernel_launch(void* const* d_in, const int* in_sizes, int n_in,
                              void* d_out, int out_size, void* d_ws, size_t ws_size,
                              hipStream_t stream){
  (void)n_in; (void)out_size; (void)ws_size;
  const float* x        = (const float*)d_in[0];
  const int*   eidx     = (const int*)d_in[1];
  const float* edge_attr= (const float*)d_in[2];
  const int*   batch    = (const int*)d_in[3];
  const float* W_in     = (const float*)d_in[4];
  const float* b_in     = (const float*)d_in[5];
  const float* Wq       = (const float*)d_in[6];
  const float* bq       = (const float*)d_in[7];
  const float* Wk       = (const float*)d_in[8];
  const float* bk       = (const float*)d_in[9];
  const float* Wv       = (const float*)d_in[10];
  const float* bv       = (const float*)d_in[11];
  const float* We       = (const float*)d_in[12];
  const float* be       = (const float*)d_in[13];
  const float* Wsk      = (const float*)d_in[14];
  const float* bsk      = (const float*)d_in[15];
  const float* Wb       = (const float*)d_in[16];
  const float* Wg1      = (const float*)d_in[17];
  const float* bg1      = (const float*)d_in[18];
  const float* Wg2      = (const float*)d_in[19];
  const float* Wh1      = (const float*)d_in[21];
  const float* bh1      = (const float*)d_in[22];
  const float* Wh2      = (const float*)d_in[23];
  const float* bh2      = (const float*)d_in[24];

  const int N = in_sizes[0] / 5;
  const int E = in_sizes[1] / 2;
  float* out = (float*)d_out;

  char* w = (char*)d_ws;
  auto alloc = [&](size_t bytes)->char*{ char* p = w; w += (bytes + 255) & ~(size_t)255; return p; };
  unsigned short* hb = (unsigned short*)alloc((size_t)N*JKW*2);
  _Float16* qh  = (_Float16*)alloc((size_t)N*160*2);
  _Float16* kvh = (_Float16*)alloc((size_t)N*320*2);
  _Float16* rskip = (_Float16*)alloc((size_t)N*160*2);
  float* qwb    = (float*)alloc((size_t)N*20*4);
  unsigned short* Bth  = (unsigned short*)alloc((size_t)2*640*160*2);
  unsigned short* Btgh = (unsigned short*)alloc((size_t)160*320*2);
  float* bpack  = (float*)alloc((size_t)2*640*4);
  int*   cnt    = (int*)alloc((size_t)N*4);
  int*   esrc   = (int*)alloc((size_t)N*BCAP*4);
  uint2* eattr  = (uint2*)alloc((size_t)N*BCAP*8);
  float* gate   = (float*)alloc((size_t)N*4);
  float* pooled = (float*)alloc(NGRAPH*JKW*4);

  const int* srcI = eidx;
  const int* dstI = eidx + E;

  const int NL = (N*HIDW + 255)/256;
  const int NZ = (N + 255)/256;
  k_pre<<<NL + 1005 + NZ, 256, 0, stream>>>(x, W_in, b_in, hb,
                                            Wq, Wk, Wv, Wsk, bq, bk, bv, bsk, Wg1,
                                            Bth, bpack, Btgh, cnt, gate, pooled, N);

  const int eb = (E + 255)/256;
  k_fill<<<eb, 256, 0, stream>>>(dstI, srcI, edge_attr, E, cnt, esrc, eattr);

  const int MB128 = (N + 127)/128;
  for (int l = 0; l < 2; ++l){
    dim3 g1(5, MB128);
    k_mgemm<8,1><<<g1, 256, 0, stream>>>(hb, JKW, Bth + (size_t)l*102400, bpack + l*640,
                                         qh, kvh, rskip, nullptr, nullptr, N, HIDW);
    k_qprep<<<(N*4 + 255)/256, 256, 0, stream>>>(qh, We + l*640, be + l*160, qwb, N);
    k_attn<<<(N + 3)/4, 256, 0, stream>>>(qh, kvh, rskip, qwb, eattr, esrc, cnt,
                                          We + l*640, be + l*160, Wb + l*480, hb, l*HIDW, N);
  }

  k_mgemm<10,2><<<dim3(1, MB128), 256, 0, stream>>>(hb, JKW, Btgh, bg1, nullptr, nullptr, nullptr,
                                                    Wg2, gate, N, JKW);

  dim3 g3(NGRAPH, 8);
  k_pool<<<g3, 320, 0, stream>>>(hb, gate, batch, N, pooled);
  k_head<<<NGRAPH, 320, 0, stream>>>(pooled, Wh1, bh1, Wh2, bh2, out);
}

// Round 7
// 492.091 us; speedup vs baseline: 1.0483x; 1.0483x over previous
//
#include <hip/hip_runtime.h>
#include <math.h>
#include <stddef.h>

#define NHEAD 4
#define DHEAD 40
#define HIDW 160
#define JKW 320
#define NGRAPH 32
#define BCAP 64   // edge bucket capacity per node (deg ~ Poisson(10); P(>63) ~ 1e-31)

typedef __attribute__((ext_vector_type(8))) short short8;
typedef __attribute__((ext_vector_type(4))) float f32x4;
typedef __attribute__((ext_vector_type(2))) float f32x2;
typedef __fp16 h2 __attribute__((ext_vector_type(2)));
typedef int i32x4 __attribute__((ext_vector_type(4)));
typedef i32x4 i32x4_a4 __attribute__((aligned(4)));

__device__ inline unsigned short f2bf(float x){
  unsigned u = __float_as_uint(x);
  u += 0x7fff + ((u >> 16) & 1);
  return (unsigned short)(u >> 16);
}
__device__ inline float bf2f(unsigned short h){
  return __uint_as_float(((unsigned)h) << 16);
}
__device__ inline float fdot2(h2 a, h2 b, float c){
  return __builtin_amdgcn_fdot2(a, b, c, false);
}
__device__ inline h2 pk(float a, float b){
  return __builtin_amdgcn_cvt_pkrtz(a, b);
}
union HU { h2 h; int i; unsigned u; float f; };
__device__ inline h2 shfl_h2(h2 v, int xm){
  HU u; u.h = v; u.i = __shfl_xor(u.i, xm); return u.h;
}

#if __has_builtin(__builtin_amdgcn_cvt_pk_f16_fp8)
__device__ inline h2 cvt8(int s){ return __builtin_amdgcn_cvt_pk_f16_fp8((short)s); }
#else
__device__ inline h2 cvt8(int s){
  f32x2 t = __builtin_amdgcn_cvt_pk_f32_fp8(s, false);
  return pk(t.x, t.y);
}
#endif

__device__ inline int lbound(const int* __restrict__ b, int N, int g){
  int lo = 0, hi = N;
  while (lo < hi){ int mid = (lo + hi) >> 1; if (b[mid] < g) lo = mid + 1; else hi = mid; }
  return lo;
}

// ---------------- fused pre-pass: zero buffers + lin_in + weight pack ----------------
__global__ __launch_bounds__(256) void k_pre(const float* __restrict__ x, const float* __restrict__ W_in,
                                             const float* __restrict__ b_in, unsigned short* __restrict__ hb,
                                             const float* __restrict__ Wq, const float* __restrict__ Wk,
                                             const float* __restrict__ Wv, const float* __restrict__ Ws,
                                             const float* __restrict__ bq, const float* __restrict__ bk,
                                             const float* __restrict__ bv, const float* __restrict__ bs,
                                             const float* __restrict__ Wg1,
                                             unsigned short* __restrict__ Bth, float* __restrict__ bp,
                                             unsigned short* __restrict__ Btgh,
                                             int* __restrict__ cnt, float* __restrict__ gate,
                                             float* __restrict__ pooled, int N){
  int NL = (N*HIDW + 255)/256;
  int bid = blockIdx.x, tid = threadIdx.x;
  if (bid < NL){
    int idx = bid*256 + tid;
    if (idx >= N*HIDW) return;
    int n = idx / HIDW, j = idx % HIDW;
    const float* xr = x + n*5;
    float v = b_in[j];
    #pragma unroll
    for (int c = 0; c < 5; ++c) v += xr[c] * W_in[c*HIDW + j];
    hb[(size_t)n*JKW + j] = f2bf(v);
  } else if (bid < NL + 1005){
    int idx = (bid - NL)*256 + tid;
    if (idx < 204800){
      int l = idx / 102400, r = idx % 102400;
      int j = r / 160, i = r % 160;
      int sel = j / HIDW, jj = j % HIDW;
      const float* W = (sel==0) ? Wq : (sel==1) ? Wk : (sel==2) ? Wv : Ws;
      Bth[(size_t)l*102400 + (size_t)j*160 + i] = f2bf(W[(size_t)l*25600 + i*HIDW + jj]);
    } else if (idx < 256000){
      int r = idx - 204800;
      int j = r / 320, i = r % 320;
      Btgh[(size_t)j*320 + i] = f2bf(Wg1[(size_t)i*160 + j]);
    } else if (idx < 257280){
      int r = idx - 256000;
      int l = r / 640, j = r % 640;
      int sel = j / HIDW, jj = j % HIDW;
      const float* bb = (sel==0) ? bq : (sel==1) ? bk : (sel==2) ? bv : bs;
      bp[l*640 + j] = bb[l*160 + jj];
    }
  } else {
    int idx = (bid - NL - 1005)*256 + tid;
    if (idx < N){ cnt[idx] = 0; gate[idx] = 0.f; }
    if (idx < NGRAPH*JKW) pooled[idx] = 0.f;
  }
}

// ---------------- bucketed edge fill ----------------
__global__ __launch_bounds__(256) void k_fill(const int* __restrict__ dst, const int* __restrict__ src,
                                              const float* __restrict__ edge_attr, int E,
                                              int* __restrict__ cnt, int* __restrict__ esrc,
                                              uint2* __restrict__ eattr){
  int e = blockIdx.x*256 + threadIdx.x;
  if (e < E){
    int d = dst[e];
    int p = atomicAdd(&cnt[d], 1);
    if (p < BCAP){
      int slot = d*BCAP + p;
      esrc[slot] = src[e];
      float4 ea = *(const float4*)(edge_attr + (size_t)e*4);
      HU a, b; a.h = pk(ea.x, ea.y); b.h = pk(ea.z, ea.w);
      eattr[slot] = make_uint2(a.u, b.u);
    }
  }
}

// ---------------- bf16 MFMA GEMM v9: XCD-pinned row-blocks ----------------
// MODE 1 (QKV, K=160): whole B panel (128c x 160k = 41KB) staged ONCE ->
//   single barrier, barrier-free 5-step k-loop (was 10 barriers + dbuf).
//   sel 0 -> qh fp16 (scale folded); sel 3 -> rskip fp16;
//   sel 1/2 (k,v) -> fp8 kv8 (R6 lesson: fp16 KV doubled gather footprint
//   past L2 -> +12us; fp8 is the right representation).
// MODE 2 (gate, K=320): old 32-k double-buffered path (full stage = 104KB LDS).
#define BSTR 40
#define BSTR1 164   // full-K stage stride (shorts): 328B -> 16 distinct banks for l16 lanes
template<int NSUB, int MODE>
__global__ __launch_bounds__(256) void k_mgemm(const unsigned short* __restrict__ A, int lda,
                                               const unsigned short* __restrict__ Bh,
                                               const float* __restrict__ bias,
                                               _Float16* __restrict__ qh,
                                               unsigned char* __restrict__ kv8,
                                               _Float16* __restrict__ rskip,
                                               const float* __restrict__ Wg2,
                                               float* __restrict__ gate,
                                               int M, int K){
  __shared__ short sBh[(MODE==1) ? (16*NSUB*BSTR1) : (2*16*NSUB*BSTR)];
  int tid = threadIdx.x;
  int wv = tid >> 6, lane = tid & 63;
  int quad = lane >> 4, l16 = lane & 15;

  int P = gridDim.x, MBy = gridDim.y;
  int bid = blockIdx.y * P + blockIdx.x;       // dispatch-order linear id
  int fullRows = (MBy >> 3) << 3;
  int rowB, panel;
  if (bid < fullRows * P){
    int group = bid / (8*P), rem = bid % (8*P);
    rowB  = group*8 + (rem & 7);
    panel = rem >> 3;
  } else {
    int rem = bid - fullRows*P;
    int R = MBy - fullRows;                    // 1..7 tail rows
    panel = rem / R;
    rowB  = fullRows + rem % R;
  }
  int m0 = rowB*128 + wv*32;
  int col0 = panel * (16*NSUB);

  int ar0 = m0 + l16;      if (ar0 >= M) ar0 = M - 1;
  int ar1 = m0 + 16 + l16; if (ar1 >= M) ar1 = M - 1;
  const unsigned short* Ap0 = A + (size_t)ar0*lda + quad*8;
  const unsigned short* Ap1 = A + (size_t)ar1*lda + quad*8;

  f32x4 acc[2][NSUB];
  #pragma unroll
  for (int g = 0; g < 2; ++g)
    #pragma unroll
    for (int s = 0; s < NSUB; ++s) acc[g][s] = (f32x4){0.f,0.f,0.f,0.f};

  if constexpr (MODE == 1){
    // stage the full 128-col x 160-k panel once (20 short8 chunks per col)
    for (int u = tid; u < 16*NSUB*20; u += 256){
      int col = u / 20, q = u % 20;
      *(short8*)(&sBh[col*BSTR1 + q*8]) =
        *(const short8*)(Bh + (size_t)(col0 + col)*K + q*8);
    }
    __syncthreads();
    #pragma unroll
    for (int kk = 0; kk < 5; ++kk){
      int k0 = kk << 5;
      short8 ah0 = *(const short8*)(Ap0 + k0);
      short8 ah1 = *(const short8*)(Ap1 + k0);
      #pragma unroll
      for (int s = 0; s < NSUB; ++s){
        short8 bh = *(const short8*)(&sBh[(s*16 + l16)*BSTR1 + k0 + quad*8]);
        acc[0][s] = __builtin_amdgcn_mfma_f32_16x16x32_bf16(ah0, bh, acc[0][s], 0, 0, 0);
        acc[1][s] = __builtin_amdgcn_mfma_f32_16x16x32_bf16(ah1, bh, acc[1][s], 0, 0, 0);
      }
    }
  } else {
    const int CH = K >> 5;
    for (int u = tid; u < 16*NSUB*4; u += 256){
      int col = u >> 2, q4 = u & 3;
      *(short8*)(&sBh[col*BSTR + q4*8]) =
        *(const short8*)(Bh + (size_t)(col0 + col)*K + q4*8);
    }
    __syncthreads();
    int buf = 0;
    for (int kk = 0; kk < CH; ++kk){
      int k0 = kk << 5;
      if (kk + 1 < CH){
        int kn = k0 + 32;
        for (int u = tid; u < 16*NSUB*4; u += 256){
          int col = u >> 2, q4 = u & 3;
          *(short8*)(&sBh[(buf^1)*16*NSUB*BSTR + col*BSTR + q4*8]) =
            *(const short8*)(Bh + (size_t)(col0 + col)*K + kn + q4*8);
        }
      }
      short8 ah0 = *(const short8*)(Ap0 + k0);
      short8 ah1 = *(const short8*)(Ap1 + k0);
      #pragma unroll
      for (int s = 0; s < NSUB; ++s){
        short8 bh = *(const short8*)(&sBh[buf*16*NSUB*BSTR + (s*16 + l16)*BSTR + quad*8]);
        acc[0][s] = __builtin_amdgcn_mfma_f32_16x16x32_bf16(ah0, bh, acc[0][s], 0, 0, 0);
        acc[1][s] = __builtin_amdgcn_mfma_f32_16x16x32_bf16(ah1, bh, acc[1][s], 0, 0, 0);
      }
      __syncthreads();
      buf ^= 1;
    }
  }

  const float qscale = 0.15811388300841898f; // 1/sqrt(40)
  if (MODE == 1){
    #pragma unroll
    for (int g = 0; g < 2; ++g){
      #pragma unroll
      for (int s = 0; s < NSUB; ++s){
        int col = col0 + s*16 + l16;
        float bv = bias[col];
        int sel = col / 160, cc = col % 160;
        #pragma unroll
        for (int r = 0; r < 4; ++r){
          int row = m0 + g*16 + quad*4 + r;
          if (row >= M) continue;
          float v = acc[g][s][r] + bv;
          if (sel == 0)      qh[(size_t)row*160 + cc] = (_Float16)(v * qscale);
          else if (sel == 3) rskip[(size_t)row*160 + cc] = (_Float16)v;
          else {
            int slot = (cc/40)*4 + (cc%40)/10, j = cc%10;
            int e8 = __builtin_amdgcn_cvt_pk_fp8_f32(v, v, 0, false);
            kv8[(size_t)row*320 + slot*20 + (sel==2?10:0) + j] = (unsigned char)(e8 & 0xff);
          }
        }
      }
    }
  } else {
    float pg[2][4];
    #pragma unroll
    for (int g = 0; g < 2; ++g)
      #pragma unroll
      for (int r = 0; r < 4; ++r) pg[g][r] = 0.f;
    #pragma unroll
    for (int s = 0; s < NSUB; ++s){
      int col = col0 + s*16 + l16;
      float bv = bias[col], wg = Wg2[col];
      #pragma unroll
      for (int g = 0; g < 2; ++g)
        #pragma unroll
        for (int r = 0; r < 4; ++r)
          pg[g][r] += fmaxf(acc[g][s][r] + bv, 0.f) * wg;
    }
    #pragma unroll
    for (int g = 0; g < 2; ++g)
      #pragma unroll
      for (int r = 0; r < 4; ++r){
        float v = pg[g][r];
        v += __shfl_xor(v, 1); v += __shfl_xor(v, 2);
        v += __shfl_xor(v, 4); v += __shfl_xor(v, 8);
        int row = m0 + g*16 + quad*4 + r;
        if (l16 == 0 && row < M) atomicAdd(&gate[row], v);
      }
  }
}

// ---------------- per-node q-projection precompute ----------------
__global__ __launch_bounds__(256) void k_qprep(const _Float16* __restrict__ qh,
                                               const float* __restrict__ We, const float* __restrict__ be,
                                               float* __restrict__ qwb, int N){
  int idx = blockIdx.x*256 + threadIdx.x;
  if (idx >= N*4) return;
  int n = idx >> 2, h = idx & 3;
  const _Float16* qp = qh + (size_t)n*160 + h*40;
  float w0=0.f,w1=0.f,w2=0.f,w3=0.f,b=0.f;
  #pragma unroll
  for (int d = 0; d < 40; ++d){
    float q = (float)qp[d];
    int c = h*40 + d;
    w0 += q*We[c];     w1 += q*We[160+c];
    w2 += q*We[320+c]; w3 += q*We[480+c];
    b  += q*be[c];
  }
  float* o = qwb + (size_t)idx*5;
  o[0]=w0; o[1]=w1; o[2]=w2; o[3]=w3; o[4]=b;
}

// ---------------- fused edge attention + beta gate (fp8 kv, no-max softmax) ----------------
// scores are O(1) (0.05-scale weights) -> exp never overflows -> max-shift dropped (exact)
// v4 (measured best, 67.8us): fp8 kv (16MB table, L2-resident -- R6: fp16 FAILED,
//     +64MB HBM fetch), eattr +3 / kv +2 prefetch, __expf, distributed epilogue.
__global__ __launch_bounds__(256) void k_attn(const _Float16* __restrict__ qh,
                                              const unsigned char* __restrict__ kv8,
                                              const _Float16* __restrict__ rskip,
                                              const float* __restrict__ qwb,
                                              const uint2* __restrict__ eattr,
                                              const int* __restrict__ esrc,
                                              const int* __restrict__ cnt,
                                              const float* __restrict__ We, const float* __restrict__ be,
                                              const float* __restrict__ Wb,
                                              unsigned short* __restrict__ hb,
                                              int loff, int N){
  int n = blockIdx.x*4 + (threadIdx.x >> 6);
  if (n >= N) return;
  int lane = threadIdx.x & 63;
  int g4 = lane >> 4;
  int w  = lane & 15;
  int hh = w & 3, t = w >> 2;
  int cbase = DHEAD*hh + 10*t;
  int slot = hh*4 + t;

  h2 qh2[5];
  {
    const unsigned* qp = (const unsigned*)(qh + (size_t)n*160 + cbase);
    #pragma unroll
    for (int i = 0; i < 5; ++i){ HU u; u.u = qp[i]; qh2[i] = u.h; }
  }
  const float* qwp = qwb + ((size_t)n*4 + hh)*5;
  float qw0 = qwp[0], qw1 = qwp[1], qw2 = qwp[2], qw3 = qwp[3], qb = qwp[4];
  h2 qw01 = pk(qw0, qw1), qw23 = pk(qw2, qw3);

  float ssum = 0.f;
  h2 zh = pk(0.f, 0.f);
  h2 acch[5], sah[2];
  #pragma unroll
  for (int i = 0; i < 5; ++i) acch[i] = zh;
  sah[0] = zh; sah[1] = zh;

  int deg = cnt[n]; if (deg > BCAP) deg = BCAP;
  int st = n*BCAP, en = st + deg;
  int B = (deg + 3) >> 2;

  // pipeline state: A = processing, B = kv in flight, C = eattr arrived / kv issuing
  int snA=0, snB=0, snC=0; bool vA=false, vB=false, vC=false;
  h2 eaA0=zh, eaA1=zh, eaB0=zh, eaB1=zh, eaC0=zh, eaC1=zh;
  {
    int p0 = st + g4;       vA = (p0 < en);
    if (vA){ snA = esrc[p0]; uint2 e = eattr[p0]; HU a,b; a.u=e.x; b.u=e.y; eaA0=a.h; eaA1=b.h; }
    int p1 = st + 4 + g4;   vB = (p1 < en);
    if (vB){ snB = esrc[p1]; uint2 e = eattr[p1]; HU a,b; a.u=e.x; b.u=e.y; eaB0=a.h; eaB1=b.h; }
    int p2 = st + 8 + g4;   vC = (p2 < en);
    if (vC){ snC = esrc[p2]; uint2 e = eattr[p2]; HU a,b; a.u=e.x; b.u=e.y; eaC0=a.h; eaC1=b.h; }
  }
  i32x4 cA0 = {0,0,0,0}, cB0 = {0,0,0,0}; int cA4 = 0, cB4 = 0;
  if (vA){
    const unsigned char* kp = kv8 + (size_t)snA*320 + slot*20;
    cA0 = *(const i32x4_a4*)kp; cA4 = *(const int*)(kp+16);
  }
  if (vB){
    const unsigned char* kp = kv8 + (size_t)snB*320 + slot*20;
    cB0 = *(const i32x4_a4*)kp; cB4 = *(const int*)(kp+16);
  }

  for (int b = 0; b < B; ++b){
    // prefetch eattr/esrc for edge b+3
    int snD = 0; h2 eaD0 = zh, eaD1 = zh; bool vD;
    int p3 = st + (b+3)*4 + g4;
    vD = (p3 < en);
    if (vD){ snD = esrc[p3]; uint2 e = eattr[p3]; HU a,b2; a.u=e.x; b2.u=e.y; eaD0=a.h; eaD1=b2.h; }
    // prefetch kv for edge b+2 (snC arrived last iteration)
    i32x4 cC0 = {0,0,0,0}; int cC4 = 0;
    if (vC){
      const unsigned char* kp = kv8 + (size_t)snC*320 + slot*20;
      cC0 = *(const i32x4_a4*)kp; cC4 = *(const int*)(kp+16);
    }
    // compute on A (kv issued 2 iterations ago)
    float p = 0.f;
    if (vA){
      p = fdot2(qh2[0], cvt8(cA0.x), p);
      p = fdot2(qh2[1], cvt8(cA0.x >> 16), p);
      p = fdot2(qh2[2], cvt8(cA0.y), p);
      p = fdot2(qh2[3], cvt8(cA0.y >> 16), p);
      p = fdot2(qh2[4], cvt8(cA0.z), p);
    }
    p += __shfl_xor(p, 4);
    p += __shfl_xor(p, 8);
    p += qb;
    p = fdot2(eaA0, qw01, p);
    p = fdot2(eaA1, qw23, p);

    if (vA){
      float ex = __expf(p);
      ssum += ex;
      h2 eh = pk(ex, ex);
      acch[0] += cvt8(cA0.z >> 16)*eh;
      acch[1] += cvt8(cA0.w)*eh;
      acch[2] += cvt8(cA0.w >> 16)*eh;
      acch[3] += cvt8(cA4)*eh;
      acch[4] += cvt8(cA4 >> 16)*eh;
      sah[0] += eaA0*eh;
      sah[1] += eaA1*eh;
    }
    snA = snB; vA = vB; eaA0 = eaB0; eaA1 = eaB1; cA0 = cB0; cA4 = cB4;
    snB = snC; vB = vC; eaB0 = eaC0; eaB1 = eaC1; cB0 = cC0; cB4 = cC4;
    snC = snD; vC = vD; eaC0 = eaD0; eaC1 = eaD1;
  }

  // merge the 4 edge-slots: butterfly -> EVERY lane holds the full sums
  #pragma unroll
  for (int xm = 16; xm < 64; xm <<= 1){
    ssum += __shfl_xor(ssum, xm);
    #pragma unroll
    for (int i = 0; i < 5; ++i) acch[i] += shfl_h2(acch[i], xm);
    sah[0] += shfl_h2(sah[0], xm);
    sah[1] += shfl_h2(sah[1], xm);
  }

  // distributed epilogue: lane (g4, w) handles cols cbase + {g4, g4+4, g4+8}
  {
    float inv = (ssum > 0.f) ? 1.f/ssum : 0.f;
    float sw0 = (float)sah[0].x*inv, sw1 = (float)sah[0].y*inv;
    float sw2 = (float)sah[1].x*inv, sw3 = (float)sah[1].y*inv;
    float bterm = (ssum > 0.f) ? 1.f : 0.f;

    // accf[j] for j = g4 + 4*jj, selected without runtime register indexing
    float a0 = (g4==0) ? (float)acch[0].x : (g4==1) ? (float)acch[0].y
             : (g4==2) ? (float)acch[1].x : (float)acch[1].y;     // j = g4
    float a1 = (g4==0) ? (float)acch[2].x : (g4==1) ? (float)acch[2].y
             : (g4==2) ? (float)acch[3].x : (float)acch[3].y;     // j = g4+4
    float a2 = (g4==0) ? (float)acch[4].x : (float)acch[4].y;     // j = g4+8 (g4<2 only)

    const _Float16* rp = rskip + (size_t)n*160 + cbase;
    float ov[3], rrv[3];
    float part = 0.f;
    #pragma unroll
    for (int jj = 0; jj < 3; ++jj){
      int j = g4 + 4*jj;
      float aj = (jj==0) ? a0 : (jj==1) ? a1 : a2;
      ov[jj] = 0.f; rrv[jj] = 0.f;
      if (j < 10){
        int c = cbase + j;
        float o = aj*inv + sw0*We[c] + sw1*We[160+c] + sw2*We[320+c] + sw3*We[480+c] + bterm*be[c];
        float r = (float)rp[j];
        ov[jj] = o; rrv[jj] = r;
        part += o*Wb[c] + r*Wb[160+c] + (o-r)*Wb[320+c];
      }
    }
    #pragma unroll
    for (int xm = 1; xm < 64; xm <<= 1) part += __shfl_xor(part, xm);
    float beta = 1.f/(1.f + __expf(-part));
    unsigned short* hp = hb + (size_t)n*JKW + loff + cbase;
    #pragma unroll
    for (int jj = 0; jj < 3; ++jj){
      int j = g4 + 4*jj;
      if (j < 10) hp[j] = f2bf(beta*rrv[jj] + (1.f-beta)*ov[jj]);
    }
  }
}

// ---------------- attention pooling with inline per-graph stats ----------------
__global__ __launch_bounds__(320) void k_pool(const unsigned short* __restrict__ hb, const float* __restrict__ gate,
                                              const int* __restrict__ batch, int N,
                                              float* __restrict__ pooled){
  __shared__ float sm[320];
  int g = blockIdx.x, part = blockIdx.y, j = threadIdx.x;
  int lo = lbound(batch, N, g), hi = lbound(batch, N, g+1);
  int len = hi - lo;
  if (len <= 0) return;
  float m = -INFINITY;
  for (int i = lo + j; i < hi; i += 320) m = fmaxf(m, gate[i]);
  sm[j] = m; __syncthreads();
  #pragma unroll
  for (int off = 256; off; off >>= 1){
    if (j < off && j + off < 320) sm[j] = fmaxf(sm[j], sm[j+off]);
    __syncthreads();
  }
  float gm = sm[0]; __syncthreads();
  float s = 0.f;
  for (int i = lo + j; i < hi; i += 320) s += __expf(gate[i] - gm);
  sm[j] = s; __syncthreads();
  #pragma unroll
  for (int off = 256; off; off >>= 1){
    if (j < off && j + off < 320) sm[j] += sm[j+off];
    __syncthreads();
  }
  float dg = sm[0];
  float invd = (dg > 0.f) ? 1.f/dg : 0.f;

  int chunk = (len + (int)gridDim.y - 1) / (int)gridDim.y;
  int a = lo + part*chunk;
  int bnd = a + chunk; if (bnd > hi) bnd = hi;
  if (a >= bnd) return;
  float acc = 0.f;
  for (int n = a; n < bnd; ++n){
    float at = __expf(gate[n] - gm);
    acc += at * bf2f(hb[(size_t)n*JKW + j]);
  }
  atomicAdd(&pooled[g*JKW + j], acc*invd);
}

__global__ __launch_bounds__(320) void k_head(const float* __restrict__ pooled, const float* __restrict__ Wh1,
                                              const float* __restrict__ bh1, const float* __restrict__ Wh2,
                                              const float* __restrict__ bh2, float* __restrict__ out){
  __shared__ float p[320];
  __shared__ float t[320];
  int g = blockIdx.x, tid = threadIdx.x;
  p[tid] = pooled[g*JKW + tid]; __syncthreads();
  float a = bh1[tid];
  for (int i = 0; i < 320; ++i) a += p[i]*Wh1[i*JKW + tid];
  t[tid] = fmaxf(a, 0.f); __syncthreads();
  if (tid < 6){
    float o = bh2[tid];
    for (int j = 0; j < 320; ++j) o += t[j]*Wh2[j*6 + tid];
    out[g*6 + tid] = o;
  }
}

extern "C" void kernel_launch(void* const* d_in, const int* in_sizes, int n_in,
                              void* d_out, int out_size, void* d_ws, size_t ws_size,
                              hipStream_t stream){
  (void)n_in; (void)out_size; (void)ws_size;
  const float* x        = (const float*)d_in[0];
  const int*   eidx     = (const int*)d_in[1];
  const float* edge_attr= (const float*)d_in[2];
  const int*   batch    = (const int*)d_in[3];
  const float* W_in     = (const float*)d_in[4];
  const float* b_in     = (const float*)d_in[5];
  const float* Wq       = (const float*)d_in[6];
  const float* bq       = (const float*)d_in[7];
  const float* Wk       = (const float*)d_in[8];
  const float* bk       = (const float*)d_in[9];
  const float* Wv       = (const float*)d_in[10];
  const float* bv       = (const float*)d_in[11];
  const float* We       = (const float*)d_in[12];
  const float* be       = (const float*)d_in[13];
  const float* Wsk      = (const float*)d_in[14];
  const float* bsk      = (const float*)d_in[15];
  const float* Wb       = (const float*)d_in[16];
  const float* Wg1      = (const float*)d_in[17];
  const float* bg1      = (const float*)d_in[18];
  const float* Wg2      = (const float*)d_in[19];
  const float* Wh1      = (const float*)d_in[21];
  const float* bh1      = (const float*)d_in[22];
  const float* Wh2      = (const float*)d_in[23];
  const float* bh2      = (const float*)d_in[24];

  const int N = in_sizes[0] / 5;
  const int E = in_sizes[1] / 2;
  float* out = (float*)d_out;

  char* w = (char*)d_ws;
  auto alloc = [&](size_t bytes)->char*{ char* p = w; w += (bytes + 255) & ~(size_t)255; return p; };
  unsigned short* hb = (unsigned short*)alloc((size_t)N*JKW*2);
  _Float16* qh  = (_Float16*)alloc((size_t)N*160*2);
  unsigned char* kv8 = (unsigned char*)alloc((size_t)N*320);
  _Float16* rskip = (_Float16*)alloc((size_t)N*160*2);
  float* qwb    = (float*)alloc((size_t)N*20*4);
  unsigned short* Bth  = (unsigned short*)alloc((size_t)2*640*160*2);
  unsigned short* Btgh = (unsigned short*)alloc((size_t)160*320*2);
  float* bpack  = (float*)alloc((size_t)2*640*4);
  int*   cnt    = (int*)alloc((size_t)N*4);
  int*   esrc   = (int*)alloc((size_t)N*BCAP*4);
  uint2* eattr  = (uint2*)alloc((size_t)N*BCAP*8);
  float* gate   = (float*)alloc((size_t)N*4);
  float* pooled = (float*)alloc(NGRAPH*JKW*4);

  const int* srcI = eidx;
  const int* dstI = eidx + E;

  const int NL = (N*HIDW + 255)/256;
  const int NZ = (N + 255)/256;
  k_pre<<<NL + 1005 + NZ, 256, 0, stream>>>(x, W_in, b_in, hb,
                                            Wq, Wk, Wv, Wsk, bq, bk, bv, bsk, Wg1,
                                            Bth, bpack, Btgh, cnt, gate, pooled, N);

  const int eb = (E + 255)/256;
  k_fill<<<eb, 256, 0, stream>>>(dstI, srcI, edge_attr, E, cnt, esrc, eattr);

  const int MB128 = (N + 127)/128;
  for (int l = 0; l < 2; ++l){
    dim3 g1(5, MB128);
    k_mgemm<8,1><<<g1, 256, 0, stream>>>(hb, JKW, Bth + (size_t)l*102400, bpack + l*640,
                                         qh, kv8, rskip, nullptr, nullptr, N, HIDW);
    k_qprep<<<(N*4 + 255)/256, 256, 0, stream>>>(qh, We + l*640, be + l*160, qwb, N);
    k_attn<<<(N + 3)/4, 256, 0, stream>>>(qh, kv8, rskip, qwb, eattr, esrc, cnt,
                                          We + l*640, be + l*160, Wb + l*480, hb, l*HIDW, N);
  }

  k_mgemm<10,2><<<dim3(1, MB128), 256, 0, stream>>>(hb, JKW, Btgh, bg1, nullptr, nullptr, nullptr,
                                                    Wg2, gate, N, JKW);

  dim3 g3(NGRAPH, 8);
  k_pool<<<g3, 320, 0, stream>>>(hb, gate, batch, N, pooled);
  k_head<<<NGRAPH, 320, 0, stream>>>(pooled, Wh1, bh1, Wh2, bh2, out);
}

// Round 8
// 486.478 us; speedup vs baseline: 1.0604x; 1.0115x over previous
//
#include <hip/hip_runtime.h>
#include <math.h>
#include <stddef.h>

#define NHEAD 4
#define DHEAD 40
#define HIDW 160
#define JKW 320
#define NGRAPH 32
#define BCAP 64   // edge bucket capacity per node (deg ~ Poisson(10); P(>63) ~ 1e-31)

typedef __attribute__((ext_vector_type(8))) short short8;
typedef __attribute__((ext_vector_type(4))) float f32x4;
typedef __attribute__((ext_vector_type(2))) float f32x2;
typedef __fp16 h2 __attribute__((ext_vector_type(2)));
typedef int i32x4 __attribute__((ext_vector_type(4)));
typedef i32x4 i32x4_a4 __attribute__((aligned(4)));

__device__ inline unsigned short f2bf(float x){
  unsigned u = __float_as_uint(x);
  u += 0x7fff + ((u >> 16) & 1);
  return (unsigned short)(u >> 16);
}
__device__ inline float bf2f(unsigned short h){
  return __uint_as_float(((unsigned)h) << 16);
}
__device__ inline float fdot2(h2 a, h2 b, float c){
  return __builtin_amdgcn_fdot2(a, b, c, false);
}
__device__ inline h2 pk(float a, float b){
  return __builtin_amdgcn_cvt_pkrtz(a, b);
}
union HU { h2 h; int i; unsigned u; float f; };
__device__ inline h2 shfl_h2(h2 v, int xm){
  HU u; u.h = v; u.i = __shfl_xor(u.i, xm); return u.h;
}

#if __has_builtin(__builtin_amdgcn_cvt_pk_f16_fp8)
__device__ inline h2 cvt8(int s){ return __builtin_amdgcn_cvt_pk_f16_fp8((short)s); }
#else
__device__ inline h2 cvt8(int s){
  f32x2 t = __builtin_amdgcn_cvt_pk_f32_fp8(s, false);
  return pk(t.x, t.y);
}
#endif

__device__ inline int lbound(const int* __restrict__ b, int N, int g){
  int lo = 0, hi = N;
  while (lo < hi){ int mid = (lo + hi) >> 1; if (b[mid] < g) lo = mid + 1; else hi = mid; }
  return lo;
}

// ---------------- fused pre-pass: zero buffers + lin_in + weight pack ----------------
// v2: lin_in vectorized -- 8 outputs/thread, float4 W reads, short8 store
__global__ __launch_bounds__(256) void k_pre(const float* __restrict__ x, const float* __restrict__ W_in,
                                             const float* __restrict__ b_in, unsigned short* __restrict__ hb,
                                             const float* __restrict__ Wq, const float* __restrict__ Wk,
                                             const float* __restrict__ Wv, const float* __restrict__ Ws,
                                             const float* __restrict__ bq, const float* __restrict__ bk,
                                             const float* __restrict__ bv, const float* __restrict__ bs,
                                             const float* __restrict__ Wg1,
                                             unsigned short* __restrict__ Bth, float* __restrict__ bp,
                                             unsigned short* __restrict__ Btgh,
                                             int* __restrict__ cnt, float* __restrict__ gate,
                                             float* __restrict__ pooled, int N){
  int NL = (N*20 + 255)/256;
  int bid = blockIdx.x, tid = threadIdx.x;
  if (bid < NL){
    int idx = bid*256 + tid;
    if (idx >= N*20) return;
    int n = idx / 20, j8 = (idx % 20)*8;
    const float* xr = x + n*5;
    float x0 = xr[0], x1 = xr[1], x2 = xr[2], x3 = xr[3], x4 = xr[4];
    float v[8];
    #pragma unroll
    for (int u = 0; u < 8; ++u) v[u] = b_in[j8+u];
    #pragma unroll
    for (int c = 0; c < 5; ++c){
      float xc = (c==0)?x0:(c==1)?x1:(c==2)?x2:(c==3)?x3:x4;
      const float4 wa = *(const float4*)(W_in + c*HIDW + j8);
      const float4 wb = *(const float4*)(W_in + c*HIDW + j8 + 4);
      v[0] += xc*wa.x; v[1] += xc*wa.y; v[2] += xc*wa.z; v[3] += xc*wa.w;
      v[4] += xc*wb.x; v[5] += xc*wb.y; v[6] += xc*wb.z; v[7] += xc*wb.w;
    }
    short8 o;
    #pragma unroll
    for (int u = 0; u < 8; ++u) o[u] = (short)f2bf(v[u]);
    *(short8*)(hb + (size_t)n*JKW + j8) = o;
  } else if (bid < NL + 1005){
    int idx = (bid - NL)*256 + tid;
    if (idx < 204800){
      int l = idx / 102400, r = idx % 102400;
      int j = r / 160, i = r % 160;
      int sel = j / HIDW, jj = j % HIDW;
      const float* W = (sel==0) ? Wq : (sel==1) ? Wk : (sel==2) ? Wv : Ws;
      Bth[(size_t)l*102400 + (size_t)j*160 + i] = f2bf(W[(size_t)l*25600 + i*HIDW + jj]);
    } else if (idx < 256000){
      int r = idx - 204800;
      int j = r / 320, i = r % 320;
      Btgh[(size_t)j*320 + i] = f2bf(Wg1[(size_t)i*160 + j]);
    } else if (idx < 257280){
      int r = idx - 256000;
      int l = r / 640, j = r % 640;
      int sel = j / HIDW, jj = j % HIDW;
      const float* bb = (sel==0) ? bq : (sel==1) ? bk : (sel==2) ? bv : bs;
      bp[l*640 + j] = bb[l*160 + jj];
    }
  } else {
    int idx = (bid - NL - 1005)*256 + tid;
    if (idx < N){ cnt[idx] = 0; gate[idx] = 0.f; }
    if (idx < NGRAPH*JKW) pooled[idx] = 0.f;
  }
}

// ---------------- bucketed edge fill ----------------
__global__ __launch_bounds__(256) void k_fill(const int* __restrict__ dst, const int* __restrict__ src,
                                              const float* __restrict__ edge_attr, int E,
                                              int* __restrict__ cnt, int* __restrict__ esrc,
                                              uint2* __restrict__ eattr){
  int e = blockIdx.x*256 + threadIdx.x;
  if (e < E){
    int d = dst[e];
    int p = atomicAdd(&cnt[d], 1);
    if (p < BCAP){
      int slot = d*BCAP + p;
      esrc[slot] = src[e];
      float4 ea = *(const float4*)(edge_attr + (size_t)e*4);
      HU a, b; a.h = pk(ea.x, ea.y); b.h = pk(ea.z, ea.w);
      eattr[slot] = make_uint2(a.u, b.u);
    }
  }
}

// ---------------- bf16 MFMA GEMM v9: XCD-pinned row-blocks ----------------
// MODE 1 (QKV, K=160): whole B panel staged once, barrier-free 5-step k-loop.
// MODE 2 (gate, K=320): 32-k double-buffered path.
#define BSTR 40
#define BSTR1 164
template<int NSUB, int MODE>
__global__ __launch_bounds__(256) void k_mgemm(const unsigned short* __restrict__ A, int lda,
                                               const unsigned short* __restrict__ Bh,
                                               const float* __restrict__ bias,
                                               _Float16* __restrict__ qh,
                                               unsigned char* __restrict__ kv8,
                                               _Float16* __restrict__ rskip,
                                               const float* __restrict__ Wg2,
                                               float* __restrict__ gate,
                                               int M, int K){
  __shared__ short sBh[(MODE==1) ? (16*NSUB*BSTR1) : (2*16*NSUB*BSTR)];
  int tid = threadIdx.x;
  int wv = tid >> 6, lane = tid & 63;
  int quad = lane >> 4, l16 = lane & 15;

  int P = gridDim.x, MBy = gridDim.y;
  int bid = blockIdx.y * P + blockIdx.x;       // dispatch-order linear id
  int fullRows = (MBy >> 3) << 3;
  int rowB, panel;
  if (bid < fullRows * P){
    int group = bid / (8*P), rem = bid % (8*P);
    rowB  = group*8 + (rem & 7);
    panel = rem >> 3;
  } else {
    int rem = bid - fullRows*P;
    int R = MBy - fullRows;                    // 1..7 tail rows
    panel = rem / R;
    rowB  = fullRows + rem % R;
  }
  int m0 = rowB*128 + wv*32;
  int col0 = panel * (16*NSUB);

  int ar0 = m0 + l16;      if (ar0 >= M) ar0 = M - 1;
  int ar1 = m0 + 16 + l16; if (ar1 >= M) ar1 = M - 1;
  const unsigned short* Ap0 = A + (size_t)ar0*lda + quad*8;
  const unsigned short* Ap1 = A + (size_t)ar1*lda + quad*8;

  f32x4 acc[2][NSUB];
  #pragma unroll
  for (int g = 0; g < 2; ++g)
    #pragma unroll
    for (int s = 0; s < NSUB; ++s) acc[g][s] = (f32x4){0.f,0.f,0.f,0.f};

  if constexpr (MODE == 1){
    for (int u = tid; u < 16*NSUB*20; u += 256){
      int col = u / 20, q = u % 20;
      *(short8*)(&sBh[col*BSTR1 + q*8]) =
        *(const short8*)(Bh + (size_t)(col0 + col)*K + q*8);
    }
    __syncthreads();
    #pragma unroll
    for (int kk = 0; kk < 5; ++kk){
      int k0 = kk << 5;
      short8 ah0 = *(const short8*)(Ap0 + k0);
      short8 ah1 = *(const short8*)(Ap1 + k0);
      #pragma unroll
      for (int s = 0; s < NSUB; ++s){
        short8 bh = *(const short8*)(&sBh[(s*16 + l16)*BSTR1 + k0 + quad*8]);
        acc[0][s] = __builtin_amdgcn_mfma_f32_16x16x32_bf16(ah0, bh, acc[0][s], 0, 0, 0);
        acc[1][s] = __builtin_amdgcn_mfma_f32_16x16x32_bf16(ah1, bh, acc[1][s], 0, 0, 0);
      }
    }
  } else {
    const int CH = K >> 5;
    for (int u = tid; u < 16*NSUB*4; u += 256){
      int col = u >> 2, q4 = u & 3;
      *(short8*)(&sBh[col*BSTR + q4*8]) =
        *(const short8*)(Bh + (size_t)(col0 + col)*K + q4*8);
    }
    __syncthreads();
    int buf = 0;
    for (int kk = 0; kk < CH; ++kk){
      int k0 = kk << 5;
      if (kk + 1 < CH){
        int kn = k0 + 32;
        for (int u = tid; u < 16*NSUB*4; u += 256){
          int col = u >> 2, q4 = u & 3;
          *(short8*)(&sBh[(buf^1)*16*NSUB*BSTR + col*BSTR + q4*8]) =
            *(const short8*)(Bh + (size_t)(col0 + col)*K + kn + q4*8);
        }
      }
      short8 ah0 = *(const short8*)(Ap0 + k0);
      short8 ah1 = *(const short8*)(Ap1 + k0);
      #pragma unroll
      for (int s = 0; s < NSUB; ++s){
        short8 bh = *(const short8*)(&sBh[buf*16*NSUB*BSTR + (s*16 + l16)*BSTR + quad*8]);
        acc[0][s] = __builtin_amdgcn_mfma_f32_16x16x32_bf16(ah0, bh, acc[0][s], 0, 0, 0);
        acc[1][s] = __builtin_amdgcn_mfma_f32_16x16x32_bf16(ah1, bh, acc[1][s], 0, 0, 0);
      }
      __syncthreads();
      buf ^= 1;
    }
  }

  const float qscale = 0.15811388300841898f; // 1/sqrt(40)
  if (MODE == 1){
    #pragma unroll
    for (int g = 0; g < 2; ++g){
      #pragma unroll
      for (int s = 0; s < NSUB; ++s){
        int col = col0 + s*16 + l16;
        float bv = bias[col];
        int sel = col / 160, cc = col % 160;
        #pragma unroll
        for (int r = 0; r < 4; ++r){
          int row = m0 + g*16 + quad*4 + r;
          if (row >= M) continue;
          float v = acc[g][s][r] + bv;
          if (sel == 0)      qh[(size_t)row*160 + cc] = (_Float16)(v * qscale);
          else if (sel == 3) rskip[(size_t)row*160 + cc] = (_Float16)v;
          else {
            int slot = (cc/40)*4 + (cc%40)/10, j = cc%10;
            int e8 = __builtin_amdgcn_cvt_pk_fp8_f32(v, v, 0, false);
            kv8[(size_t)row*320 + slot*20 + (sel==2?10:0) + j] = (unsigned char)(e8 & 0xff);
          }
        }
      }
    }
  } else {
    float pg[2][4];
    #pragma unroll
    for (int g = 0; g < 2; ++g)
      #pragma unroll
      for (int r = 0; r < 4; ++r) pg[g][r] = 0.f;
    #pragma unroll
    for (int s = 0; s < NSUB; ++s){
      int col = col0 + s*16 + l16;
      float bv = bias[col], wg = Wg2[col];
      #pragma unroll
      for (int g = 0; g < 2; ++g)
        #pragma unroll
        for (int r = 0; r < 4; ++r)
          pg[g][r] += fmaxf(acc[g][s][r] + bv, 0.f) * wg;
    }
    #pragma unroll
    for (int g = 0; g < 2; ++g)
      #pragma unroll
      for (int r = 0; r < 4; ++r){
        float v = pg[g][r];
        v += __shfl_xor(v, 1); v += __shfl_xor(v, 2);
        v += __shfl_xor(v, 4); v += __shfl_xor(v, 8);
        int row = m0 + g*16 + quad*4 + r;
        if (l16 == 0 && row < M) atomicAdd(&gate[row], v);
      }
  }
}

// ---------------- per-node q-projection precompute ----------------
// v2: dword (h2) loads of qh -- 20 loads instead of 40 scalar fp16
__global__ __launch_bounds__(256) void k_qprep(const _Float16* __restrict__ qh,
                                               const float* __restrict__ We, const float* __restrict__ be,
                                               float* __restrict__ qwb, int N){
  int idx = blockIdx.x*256 + threadIdx.x;
  if (idx >= N*4) return;
  int n = idx >> 2, h = idx & 3;
  const unsigned* qp = (const unsigned*)(qh + (size_t)n*160 + h*40);
  float w0=0.f,w1=0.f,w2=0.f,w3=0.f,b=0.f;
  #pragma unroll
  for (int i = 0; i < 20; ++i){
    HU u; u.u = qp[i];
    float qa = (float)u.h.x, qb = (float)u.h.y;
    int c = h*40 + 2*i;
    w0 += qa*We[c]       + qb*We[c+1];
    w1 += qa*We[160+c]   + qb*We[161+c];
    w2 += qa*We[320+c]   + qb*We[321+c];
    w3 += qa*We[480+c]   + qb*We[481+c];
    b  += qa*be[c]       + qb*be[c+1];
  }
  float* o = qwb + (size_t)idx*5;
  o[0]=w0; o[1]=w1; o[2]=w2; o[3]=w3; o[4]=b;
}

// ---------------- fused edge attention + beta gate (fp8 kv, no-max softmax) ----------------
// v6: 512-thread blocks (8 nodes) -- full occupancy needs only 4 WGs/CU (was 8);
//     better latency-hiding for the random kv gather. Loop body unchanged from
//     measured-best v4 (fp8 kv, +3/+2 prefetch, __expf, distributed epilogue).
__global__ __launch_bounds__(512) void k_attn(const _Float16* __restrict__ qh,
                                              const unsigned char* __restrict__ kv8,
                                              const _Float16* __restrict__ rskip,
                                              const float* __restrict__ qwb,
                                              const uint2* __restrict__ eattr,
                                              const int* __restrict__ esrc,
                                              const int* __restrict__ cnt,
                                              const float* __restrict__ We, const float* __restrict__ be,
                                              const float* __restrict__ Wb,
                                              unsigned short* __restrict__ hb,
                                              int loff, int N){
  int n = blockIdx.x*8 + (threadIdx.x >> 6);
  if (n >= N) return;
  int lane = threadIdx.x & 63;
  int g4 = lane >> 4;
  int w  = lane & 15;
  int hh = w & 3, t = w >> 2;
  int cbase = DHEAD*hh + 10*t;
  int slot = hh*4 + t;

  h2 qh2[5];
  {
    const unsigned* qp = (const unsigned*)(qh + (size_t)n*160 + cbase);
    #pragma unroll
    for (int i = 0; i < 5; ++i){ HU u; u.u = qp[i]; qh2[i] = u.h; }
  }
  const float* qwp = qwb + ((size_t)n*4 + hh)*5;
  float qw0 = qwp[0], qw1 = qwp[1], qw2 = qwp[2], qw3 = qwp[3], qb = qwp[4];
  h2 qw01 = pk(qw0, qw1), qw23 = pk(qw2, qw3);

  float ssum = 0.f;
  h2 zh = pk(0.f, 0.f);
  h2 acch[5], sah[2];
  #pragma unroll
  for (int i = 0; i < 5; ++i) acch[i] = zh;
  sah[0] = zh; sah[1] = zh;

  int deg = cnt[n]; if (deg > BCAP) deg = BCAP;
  int st = n*BCAP, en = st + deg;
  int B = (deg + 3) >> 2;

  // pipeline state: A = processing, B = kv in flight, C = eattr arrived / kv issuing
  int snA=0, snB=0, snC=0; bool vA=false, vB=false, vC=false;
  h2 eaA0=zh, eaA1=zh, eaB0=zh, eaB1=zh, eaC0=zh, eaC1=zh;
  {
    int p0 = st + g4;       vA = (p0 < en);
    if (vA){ snA = esrc[p0]; uint2 e = eattr[p0]; HU a,b; a.u=e.x; b.u=e.y; eaA0=a.h; eaA1=b.h; }
    int p1 = st + 4 + g4;   vB = (p1 < en);
    if (vB){ snB = esrc[p1]; uint2 e = eattr[p1]; HU a,b; a.u=e.x; b.u=e.y; eaB0=a.h; eaB1=b.h; }
    int p2 = st + 8 + g4;   vC = (p2 < en);
    if (vC){ snC = esrc[p2]; uint2 e = eattr[p2]; HU a,b; a.u=e.x; b.u=e.y; eaC0=a.h; eaC1=b.h; }
  }
  i32x4 cA0 = {0,0,0,0}, cB0 = {0,0,0,0}; int cA4 = 0, cB4 = 0;
  if (vA){
    const unsigned char* kp = kv8 + (size_t)snA*320 + slot*20;
    cA0 = *(const i32x4_a4*)kp; cA4 = *(const int*)(kp+16);
  }
  if (vB){
    const unsigned char* kp = kv8 + (size_t)snB*320 + slot*20;
    cB0 = *(const i32x4_a4*)kp; cB4 = *(const int*)(kp+16);
  }

  for (int b = 0; b < B; ++b){
    // prefetch eattr/esrc for edge b+3
    int snD = 0; h2 eaD0 = zh, eaD1 = zh; bool vD;
    int p3 = st + (b+3)*4 + g4;
    vD = (p3 < en);
    if (vD){ snD = esrc[p3]; uint2 e = eattr[p3]; HU a,b2; a.u=e.x; b2.u=e.y; eaD0=a.h; eaD1=b2.h; }
    // prefetch kv for edge b+2 (snC arrived last iteration)
    i32x4 cC0 = {0,0,0,0}; int cC4 = 0;
    if (vC){
      const unsigned char* kp = kv8 + (size_t)snC*320 + slot*20;
      cC0 = *(const i32x4_a4*)kp; cC4 = *(const int*)(kp+16);
    }
    // compute on A (kv issued 2 iterations ago)
    float p = 0.f;
    if (vA){
      p = fdot2(qh2[0], cvt8(cA0.x), p);
      p = fdot2(qh2[1], cvt8(cA0.x >> 16), p);
      p = fdot2(qh2[2], cvt8(cA0.y), p);
      p = fdot2(qh2[3], cvt8(cA0.y >> 16), p);
      p = fdot2(qh2[4], cvt8(cA0.z), p);
    }
    p += __shfl_xor(p, 4);
    p += __shfl_xor(p, 8);
    p += qb;
    p = fdot2(eaA0, qw01, p);
    p = fdot2(eaA1, qw23, p);

    if (vA){
      float ex = __expf(p);
      ssum += ex;
      h2 eh = pk(ex, ex);
      acch[0] += cvt8(cA0.z >> 16)*eh;
      acch[1] += cvt8(cA0.w)*eh;
      acch[2] += cvt8(cA0.w >> 16)*eh;
      acch[3] += cvt8(cA4)*eh;
      acch[4] += cvt8(cA4 >> 16)*eh;
      sah[0] += eaA0*eh;
      sah[1] += eaA1*eh;
    }
    snA = snB; vA = vB; eaA0 = eaB0; eaA1 = eaB1; cA0 = cB0; cA4 = cB4;
    snB = snC; vB = vC; eaB0 = eaC0; eaB1 = eaC1; cB0 = cC0; cB4 = cC4;
    snC = snD; vC = vD; eaC0 = eaD0; eaC1 = eaD1;
  }

  // merge the 4 edge-slots: butterfly -> EVERY lane holds the full sums
  #pragma unroll
  for (int xm = 16; xm < 64; xm <<= 1){
    ssum += __shfl_xor(ssum, xm);
    #pragma unroll
    for (int i = 0; i < 5; ++i) acch[i] += shfl_h2(acch[i], xm);
    sah[0] += shfl_h2(sah[0], xm);
    sah[1] += shfl_h2(sah[1], xm);
  }

  // distributed epilogue: lane (g4, w) handles cols cbase + {g4, g4+4, g4+8}
  {
    float inv = (ssum > 0.f) ? 1.f/ssum : 0.f;
    float sw0 = (float)sah[0].x*inv, sw1 = (float)sah[0].y*inv;
    float sw2 = (float)sah[1].x*inv, sw3 = (float)sah[1].y*inv;
    float bterm = (ssum > 0.f) ? 1.f : 0.f;

    float a0 = (g4==0) ? (float)acch[0].x : (g4==1) ? (float)acch[0].y
             : (g4==2) ? (float)acch[1].x : (float)acch[1].y;     // j = g4
    float a1 = (g4==0) ? (float)acch[2].x : (g4==1) ? (float)acch[2].y
             : (g4==2) ? (float)acch[3].x : (float)acch[3].y;     // j = g4+4
    float a2 = (g4==0) ? (float)acch[4].x : (float)acch[4].y;     // j = g4+8 (g4<2 only)

    const _Float16* rp = rskip + (size_t)n*160 + cbase;
    float ov[3], rrv[3];
    float part = 0.f;
    #pragma unroll
    for (int jj = 0; jj < 3; ++jj){
      int j = g4 + 4*jj;
      float aj = (jj==0) ? a0 : (jj==1) ? a1 : a2;
      ov[jj] = 0.f; rrv[jj] = 0.f;
      if (j < 10){
        int c = cbase + j;
        float o = aj*inv + sw0*We[c] + sw1*We[160+c] + sw2*We[320+c] + sw3*We[480+c] + bterm*be[c];
        float r = (float)rp[j];
        ov[jj] = o; rrv[jj] = r;
        part += o*Wb[c] + r*Wb[160+c] + (o-r)*Wb[320+c];
      }
    }
    #pragma unroll
    for (int xm = 1; xm < 64; xm <<= 1) part += __shfl_xor(part, xm);
    float beta = 1.f/(1.f + __expf(-part));
    unsigned short* hp = hb + (size_t)n*JKW + loff + cbase;
    #pragma unroll
    for (int jj = 0; jj < 3; ++jj){
      int j = g4 + 4*jj;
      if (j < 10) hp[j] = f2bf(beta*rrv[jj] + (1.f-beta)*ov[jj]);
    }
  }
}

// ---------------- attention pooling with inline per-graph stats ----------------
__global__ __launch_bounds__(320) void k_pool(const unsigned short* __restrict__ hb, const float* __restrict__ gate,
                                              const int* __restrict__ batch, int N,
                                              float* __restrict__ pooled){
  __shared__ float sm[320];
  int g = blockIdx.x, part = blockIdx.y, j = threadIdx.x;
  int lo = lbound(batch, N, g), hi = lbound(batch, N, g+1);
  int len = hi - lo;
  if (len <= 0) return;
  float m = -INFINITY;
  for (int i = lo + j; i < hi; i += 320) m = fmaxf(m, gate[i]);
  sm[j] = m; __syncthreads();
  #pragma unroll
  for (int off = 256; off; off >>= 1){
    if (j < off && j + off < 320) sm[j] = fmaxf(sm[j], sm[j+off]);
    __syncthreads();
  }
  float gm = sm[0]; __syncthreads();
  float s = 0.f;
  for (int i = lo + j; i < hi; i += 320) s += __expf(gate[i] - gm);
  sm[j] = s; __syncthreads();
  #pragma unroll
  for (int off = 256; off; off >>= 1){
    if (j < off && j + off < 320) sm[j] += sm[j+off];
    __syncthreads();
  }
  float dg = sm[0];
  float invd = (dg > 0.f) ? 1.f/dg : 0.f;

  int chunk = (len + (int)gridDim.y - 1) / (int)gridDim.y;
  int a = lo + part*chunk;
  int bnd = a + chunk; if (bnd > hi) bnd = hi;
  if (a >= bnd) return;
  float acc = 0.f;
  for (int n = a; n < bnd; ++n){
    float at = __expf(gate[n] - gm);
    acc += at * bf2f(hb[(size_t)n*JKW + j]);
  }
  atomicAdd(&pooled[g*JKW + j], acc*invd);
}

__global__ __launch_bounds__(320) void k_head(const float* __restrict__ pooled, const float* __restrict__ Wh1,
                                              const float* __restrict__ bh1, const float* __restrict__ Wh2,
                                              const float* __restrict__ bh2, float* __restrict__ out){
  __shared__ float p[320];
  __shared__ float t[320];
  int g = blockIdx.x, tid = threadIdx.x;
  p[tid] = pooled[g*JKW + tid]; __syncthreads();
  float a = bh1[tid];
  for (int i = 0; i < 320; ++i) a += p[i]*Wh1[i*JKW + tid];
  t[tid] = fmaxf(a, 0.f); __syncthreads();
  if (tid < 6){
    float o = bh2[tid];
    for (int j = 0; j < 320; ++j) o += t[j]*Wh2[j*6 + tid];
    out[g*6 + tid] = o;
  }
}

extern "C" void kernel_launch(void* const* d_in, const int* in_sizes, int n_in,
                              void* d_out, int out_size, void* d_ws, size_t ws_size,
                              hipStream_t stream){
  (void)n_in; (void)out_size; (void)ws_size;
  const float* x        = (const float*)d_in[0];
  const int*   eidx     = (const int*)d_in[1];
  const float* edge_attr= (const float*)d_in[2];
  const int*   batch    = (const int*)d_in[3];
  const float* W_in     = (const float*)d_in[4];
  const float* b_in     = (const float*)d_in[5];
  const float* Wq       = (const float*)d_in[6];
  const float* bq       = (const float*)d_in[7];
  const float* Wk       = (const float*)d_in[8];
  const float* bk       = (const float*)d_in[9];
  const float* Wv       = (const float*)d_in[10];
  const float* bv       = (const float*)d_in[11];
  const float* We       = (const float*)d_in[12];
  const float* be       = (const float*)d_in[13];
  const float* Wsk      = (const float*)d_in[14];
  const float* bsk      = (const float*)d_in[15];
  const float* Wb       = (const float*)d_in[16];
  const float* Wg1      = (const float*)d_in[17];
  const float* bg1      = (const float*)d_in[18];
  const float* Wg2      = (const float*)d_in[19];
  const float* Wh1      = (const float*)d_in[21];
  const float* bh1      = (const float*)d_in[22];
  const float* Wh2      = (const float*)d_in[23];
  const float* bh2      = (const float*)d_in[24];

  const int N = in_sizes[0] / 5;
  const int E = in_sizes[1] / 2;
  float* out = (float*)d_out;

  char* w = (char*)d_ws;
  auto alloc = [&](size_t bytes)->char*{ char* p = w; w += (bytes + 255) & ~(size_t)255; return p; };
  unsigned short* hb = (unsigned short*)alloc((size_t)N*JKW*2);
  _Float16* qh  = (_Float16*)alloc((size_t)N*160*2);
  unsigned char* kv8 = (unsigned char*)alloc((size_t)N*320);
  _Float16* rskip = (_Float16*)alloc((size_t)N*160*2);
  float* qwb    = (float*)alloc((size_t)N*20*4);
  unsigned short* Bth  = (unsigned short*)alloc((size_t)2*640*160*2);
  unsigned short* Btgh = (unsigned short*)alloc((size_t)160*320*2);
  float* bpack  = (float*)alloc((size_t)2*640*4);
  int*   cnt    = (int*)alloc((size_t)N*4);
  int*   esrc   = (int*)alloc((size_t)N*BCAP*4);
  uint2* eattr  = (uint2*)alloc((size_t)N*BCAP*8);
  float* gate   = (float*)alloc((size_t)N*4);
  float* pooled = (float*)alloc(NGRAPH*JKW*4);

  const int* srcI = eidx;
  const int* dstI = eidx + E;

  const int NL = (N*20 + 255)/256;
  const int NZ = (N + 255)/256;
  k_pre<<<NL + 1005 + NZ, 256, 0, stream>>>(x, W_in, b_in, hb,
                                            Wq, Wk, Wv, Wsk, bq, bk, bv, bsk, Wg1,
                                            Bth, bpack, Btgh, cnt, gate, pooled, N);

  const int eb = (E + 255)/256;
  k_fill<<<eb, 256, 0, stream>>>(dstI, srcI, edge_attr, E, cnt, esrc, eattr);

  const int MB128 = (N + 127)/128;
  for (int l = 0; l < 2; ++l){
    dim3 g1(5, MB128);
    k_mgemm<8,1><<<g1, 256, 0, stream>>>(hb, JKW, Bth + (size_t)l*102400, bpack + l*640,
                                         qh, kv8, rskip, nullptr, nullptr, N, HIDW);
    k_qprep<<<(N*4 + 255)/256, 256, 0, stream>>>(qh, We + l*640, be + l*160, qwb, N);
    k_attn<<<(N + 7)/8, 512, 0, stream>>>(qh, kv8, rskip, qwb, eattr, esrc, cnt,
                                          We + l*640, be + l*160, Wb + l*480, hb, l*HIDW, N);
  }

  k_mgemm<10,2><<<dim3(1, MB128), 256, 0, stream>>>(hb, JKW, Btgh, bg1, nullptr, nullptr, nullptr,
                                                    Wg2, gate, N, JKW);

  dim3 g3(NGRAPH, 8);
  k_pool<<<g3, 320, 0, stream>>>(hb, gate, batch, N, pooled);
  k_head<<<NGRAPH, 320, 0, stream>>>(pooled, Wh1, bh1, Wh2, bh2, out);
}

// Round 9
// 481.183 us; speedup vs baseline: 1.0721x; 1.0110x over previous
//
#include <hip/hip_runtime.h>
#include <math.h>
#include <stddef.h>

#define NHEAD 4
#define DHEAD 40
#define HIDW 160
#define JKW 320
#define NGRAPH 32
#define BCAP 64   // edge bucket capacity per node (deg ~ Poisson(10); P(>63) ~ 1e-31)

typedef __attribute__((ext_vector_type(8))) short short8;
typedef __attribute__((ext_vector_type(4))) float f32x4;
typedef __attribute__((ext_vector_type(2))) float f32x2;
typedef __fp16 h2 __attribute__((ext_vector_type(2)));
typedef int i32x4 __attribute__((ext_vector_type(4)));
typedef i32x4 i32x4_a4 __attribute__((aligned(4)));

__device__ inline unsigned short f2bf(float x){
  unsigned u = __float_as_uint(x);
  u += 0x7fff + ((u >> 16) & 1);
  return (unsigned short)(u >> 16);
}
__device__ inline float bf2f(unsigned short h){
  return __uint_as_float(((unsigned)h) << 16);
}
__device__ inline float fdot2(h2 a, h2 b, float c){
  return __builtin_amdgcn_fdot2(a, b, c, false);
}
__device__ inline h2 pk(float a, float b){
  return __builtin_amdgcn_cvt_pkrtz(a, b);
}
union HU { h2 h; int i; unsigned u; float f; };
__device__ inline h2 shfl_h2(h2 v, int xm){
  HU u; u.h = v; u.i = __shfl_xor(u.i, xm); return u.h;
}
__device__ inline h2 asH2(unsigned i){ HU u; u.u = i; return u.h; }

#if __has_builtin(__builtin_amdgcn_cvt_pk_f16_fp8)
__device__ inline h2 cvt8(int s){ return __builtin_amdgcn_cvt_pk_f16_fp8((short)s); }
#else
__device__ inline h2 cvt8(int s){
  f32x2 t = __builtin_amdgcn_cvt_pk_f32_fp8(s, false);
  return pk(t.x, t.y);
}
#endif

__device__ inline int lbound(const int* __restrict__ b, int N, int g){
  int lo = 0, hi = N;
  while (lo < hi){ int mid = (lo + hi) >> 1; if (b[mid] < g) lo = mid + 1; else hi = mid; }
  return lo;
}

// ---------------- fused pre-pass: zero buffers + lin_in + weight pack ----------------
// v3: lin_in vectorized (8 out/thread); Bth pack reads coalesced (consecutive
//     tid -> consecutive jj), scattered writes into 410KB L2-resident Bth.
__global__ __launch_bounds__(256) void k_pre(const float* __restrict__ x, const float* __restrict__ W_in,
                                             const float* __restrict__ b_in, unsigned short* __restrict__ hb,
                                             const float* __restrict__ Wq, const float* __restrict__ Wk,
                                             const float* __restrict__ Wv, const float* __restrict__ Ws,
                                             const float* __restrict__ bq, const float* __restrict__ bk,
                                             const float* __restrict__ bv, const float* __restrict__ bs,
                                             const float* __restrict__ Wg1,
                                             unsigned short* __restrict__ Bth, float* __restrict__ bp,
                                             unsigned short* __restrict__ Btgh,
                                             int* __restrict__ cnt, float* __restrict__ gate,
                                             float* __restrict__ pooled, int N){
  int NL = (N*20 + 255)/256;
  int bid = blockIdx.x, tid = threadIdx.x;
  if (bid < NL){
    int idx = bid*256 + tid;
    if (idx >= N*20) return;
    int n = idx / 20, j8 = (idx % 20)*8;
    const float* xr = x + n*5;
    float x0 = xr[0], x1 = xr[1], x2 = xr[2], x3 = xr[3], x4 = xr[4];
    float v[8];
    #pragma unroll
    for (int u = 0; u < 8; ++u) v[u] = b_in[j8+u];
    #pragma unroll
    for (int c = 0; c < 5; ++c){
      float xc = (c==0)?x0:(c==1)?x1:(c==2)?x2:(c==3)?x3:x4;
      const float4 wa = *(const float4*)(W_in + c*HIDW + j8);
      const float4 wb = *(const float4*)(W_in + c*HIDW + j8 + 4);
      v[0] += xc*wa.x; v[1] += xc*wa.y; v[2] += xc*wa.z; v[3] += xc*wa.w;
      v[4] += xc*wb.x; v[5] += xc*wb.y; v[6] += xc*wb.z; v[7] += xc*wb.w;
    }
    short8 o;
    #pragma unroll
    for (int u = 0; u < 8; ++u) o[u] = (short)f2bf(v[u]);
    *(short8*)(hb + (size_t)n*JKW + j8) = o;
  } else if (bid < NL + 1005){
    int idx = (bid - NL)*256 + tid;
    if (idx < 204800){
      int l = idx / 102400, r = idx % 102400;
      int i = r / 640, j = r % 640;            // consecutive tid -> consecutive jj (coalesced W reads)
      int sel = j / HIDW, jj = j % HIDW;
      const float* W = (sel==0) ? Wq : (sel==1) ? Wk : (sel==2) ? Wv : Ws;
      Bth[(size_t)l*102400 + (size_t)j*160 + i] = f2bf(W[(size_t)l*25600 + i*HIDW + jj]);
    } else if (idx < 256000){
      int r = idx - 204800;
      int j = r / 320, i = r % 320;
      Btgh[(size_t)j*320 + i] = f2bf(Wg1[(size_t)i*160 + j]);
    } else if (idx < 257280){
      int r = idx - 256000;
      int l = r / 640, j = r % 640;
      int sel = j / HIDW, jj = j % HIDW;
      const float* bb = (sel==0) ? bq : (sel==1) ? bk : (sel==2) ? bv : bs;
      bp[l*640 + j] = bb[l*160 + jj];
    }
  } else {
    int idx = (bid - NL - 1005)*256 + tid;
    if (idx < N){ cnt[idx] = 0; gate[idx] = 0.f; }
    if (idx < NGRAPH*JKW) pooled[idx] = 0.f;
  }
}

// ---------------- bucketed edge fill ----------------
// v2: single 16B record {src, ea01, ea23, pad} -- one scattered store per edge
//     (was 4B + 8B into two arrays = 2 cache-line allocations per edge).
__global__ __launch_bounds__(256) void k_fill(const int* __restrict__ dst, const int* __restrict__ src,
                                              const float* __restrict__ edge_attr, int E,
                                              int* __restrict__ cnt, uint4* __restrict__ edges){
  int e = blockIdx.x*256 + threadIdx.x;
  if (e < E){
    int d = dst[e];
    int p = atomicAdd(&cnt[d], 1);
    if (p < BCAP){
      float4 ea = *(const float4*)(edge_attr + (size_t)e*4);
      HU a, b; a.h = pk(ea.x, ea.y); b.h = pk(ea.z, ea.w);
      edges[(size_t)d*BCAP + p] = make_uint4((unsigned)src[e], a.u, b.u, 0u);
    }
  }
}

// ---------------- bf16 MFMA GEMM v9: XCD-pinned row-blocks ----------------
// MODE 1 (QKV, K=160): whole B panel staged once, barrier-free 5-step k-loop.
// MODE 2 (gate, K=320): 32-k double-buffered path.
#define BSTR 40
#define BSTR1 164
template<int NSUB, int MODE>
__global__ __launch_bounds__(256) void k_mgemm(const unsigned short* __restrict__ A, int lda,
                                               const unsigned short* __restrict__ Bh,
                                               const float* __restrict__ bias,
                                               _Float16* __restrict__ qh,
                                               unsigned char* __restrict__ kv8,
                                               _Float16* __restrict__ rskip,
                                               const float* __restrict__ Wg2,
                                               float* __restrict__ gate,
                                               int M, int K){
  __shared__ short sBh[(MODE==1) ? (16*NSUB*BSTR1) : (2*16*NSUB*BSTR)];
  int tid = threadIdx.x;
  int wv = tid >> 6, lane = tid & 63;
  int quad = lane >> 4, l16 = lane & 15;

  int P = gridDim.x, MBy = gridDim.y;
  int bid = blockIdx.y * P + blockIdx.x;       // dispatch-order linear id
  int fullRows = (MBy >> 3) << 3;
  int rowB, panel;
  if (bid < fullRows * P){
    int group = bid / (8*P), rem = bid % (8*P);
    rowB  = group*8 + (rem & 7);
    panel = rem >> 3;
  } else {
    int rem = bid - fullRows*P;
    int R = MBy - fullRows;                    // 1..7 tail rows
    panel = rem / R;
    rowB  = fullRows + rem % R;
  }
  int m0 = rowB*128 + wv*32;
  int col0 = panel * (16*NSUB);

  int ar0 = m0 + l16;      if (ar0 >= M) ar0 = M - 1;
  int ar1 = m0 + 16 + l16; if (ar1 >= M) ar1 = M - 1;
  const unsigned short* Ap0 = A + (size_t)ar0*lda + quad*8;
  const unsigned short* Ap1 = A + (size_t)ar1*lda + quad*8;

  f32x4 acc[2][NSUB];
  #pragma unroll
  for (int g = 0; g < 2; ++g)
    #pragma unroll
    for (int s = 0; s < NSUB; ++s) acc[g][s] = (f32x4){0.f,0.f,0.f,0.f};

  if constexpr (MODE == 1){
    for (int u = tid; u < 16*NSUB*20; u += 256){
      int col = u / 20, q = u % 20;
      *(short8*)(&sBh[col*BSTR1 + q*8]) =
        *(const short8*)(Bh + (size_t)(col0 + col)*K + q*8);
    }
    __syncthreads();
    #pragma unroll
    for (int kk = 0; kk < 5; ++kk){
      int k0 = kk << 5;
      short8 ah0 = *(const short8*)(Ap0 + k0);
      short8 ah1 = *(const short8*)(Ap1 + k0);
      #pragma unroll
      for (int s = 0; s < NSUB; ++s){
        short8 bh = *(const short8*)(&sBh[(s*16 + l16)*BSTR1 + k0 + quad*8]);
        acc[0][s] = __builtin_amdgcn_mfma_f32_16x16x32_bf16(ah0, bh, acc[0][s], 0, 0, 0);
        acc[1][s] = __builtin_amdgcn_mfma_f32_16x16x32_bf16(ah1, bh, acc[1][s], 0, 0, 0);
      }
    }
  } else {
    const int CH = K >> 5;
    for (int u = tid; u < 16*NSUB*4; u += 256){
      int col = u >> 2, q4 = u & 3;
      *(short8*)(&sBh[col*BSTR + q4*8]) =
        *(const short8*)(Bh + (size_t)(col0 + col)*K + q4*8);
    }
    __syncthreads();
    int buf = 0;
    for (int kk = 0; kk < CH; ++kk){
      int k0 = kk << 5;
      if (kk + 1 < CH){
        int kn = k0 + 32;
        for (int u = tid; u < 16*NSUB*4; u += 256){
          int col = u >> 2, q4 = u & 3;
          *(short8*)(&sBh[(buf^1)*16*NSUB*BSTR + col*BSTR + q4*8]) =
            *(const short8*)(Bh + (size_t)(col0 + col)*K + kn + q4*8);
        }
      }
      short8 ah0 = *(const short8*)(Ap0 + k0);
      short8 ah1 = *(const short8*)(Ap1 + k0);
      #pragma unroll
      for (int s = 0; s < NSUB; ++s){
        short8 bh = *(const short8*)(&sBh[buf*16*NSUB*BSTR + (s*16 + l16)*BSTR + quad*8]);
        acc[0][s] = __builtin_amdgcn_mfma_f32_16x16x32_bf16(ah0, bh, acc[0][s], 0, 0, 0);
        acc[1][s] = __builtin_amdgcn_mfma_f32_16x16x32_bf16(ah1, bh, acc[1][s], 0, 0, 0);
      }
      __syncthreads();
      buf ^= 1;
    }
  }

  const float qscale = 0.15811388300841898f; // 1/sqrt(40)
  if (MODE == 1){
    #pragma unroll
    for (int g = 0; g < 2; ++g){
      #pragma unroll
      for (int s = 0; s < NSUB; ++s){
        int col = col0 + s*16 + l16;
        float bv = bias[col];
        int sel = col / 160, cc = col % 160;
        #pragma unroll
        for (int r = 0; r < 4; ++r){
          int row = m0 + g*16 + quad*4 + r;
          if (row >= M) continue;
          float v = acc[g][s][r] + bv;
          if (sel == 0)      qh[(size_t)row*160 + cc] = (_Float16)(v * qscale);
          else if (sel == 3) rskip[(size_t)row*160 + cc] = (_Float16)v;
          else {
            int slot = (cc/40)*4 + (cc%40)/10, j = cc%10;
            int e8 = __builtin_amdgcn_cvt_pk_fp8_f32(v, v, 0, false);
            kv8[(size_t)row*320 + slot*20 + (sel==2?10:0) + j] = (unsigned char)(e8 & 0xff);
          }
        }
      }
    }
  } else {
    float pg[2][4];
    #pragma unroll
    for (int g = 0; g < 2; ++g)
      #pragma unroll
      for (int r = 0; r < 4; ++r) pg[g][r] = 0.f;
    #pragma unroll
    for (int s = 0; s < NSUB; ++s){
      int col = col0 + s*16 + l16;
      float bv = bias[col], wg = Wg2[col];
      #pragma unroll
      for (int g = 0; g < 2; ++g)
        #pragma unroll
        for (int r = 0; r < 4; ++r)
          pg[g][r] += fmaxf(acc[g][s][r] + bv, 0.f) * wg;
    }
    #pragma unroll
    for (int g = 0; g < 2; ++g)
      #pragma unroll
      for (int r = 0; r < 4; ++r){
        float v = pg[g][r];
        v += __shfl_xor(v, 1); v += __shfl_xor(v, 2);
        v += __shfl_xor(v, 4); v += __shfl_xor(v, 8);
        int row = m0 + g*16 + quad*4 + r;
        if (l16 == 0 && row < M) atomicAdd(&gate[row], v);
      }
  }
}

// ---------------- per-node q-projection precompute ----------------
// v2: dword (h2) loads of qh
__global__ __launch_bounds__(256) void k_qprep(const _Float16* __restrict__ qh,
                                               const float* __restrict__ We, const float* __restrict__ be,
                                               float* __restrict__ qwb, int N){
  int idx = blockIdx.x*256 + threadIdx.x;
  if (idx >= N*4) return;
  int n = idx >> 2, h = idx & 3;
  const unsigned* qp = (const unsigned*)(qh + (size_t)n*160 + h*40);
  float w0=0.f,w1=0.f,w2=0.f,w3=0.f,b=0.f;
  #pragma unroll
  for (int i = 0; i < 20; ++i){
    HU u; u.u = qp[i];
    float qa = (float)u.h.x, qb = (float)u.h.y;
    int c = h*40 + 2*i;
    w0 += qa*We[c]       + qb*We[c+1];
    w1 += qa*We[160+c]   + qb*We[161+c];
    w2 += qa*We[320+c]   + qb*We[321+c];
    w3 += qa*We[480+c]   + qb*We[481+c];
    b  += qa*be[c]       + qb*be[c+1];
  }
  float* o = qwb + (size_t)idx*5;
  o[0]=w0; o[1]=w1; o[2]=w2; o[3]=w3; o[4]=b;
}

// ---------------- fused edge attention + beta gate (fp8 kv, no-max softmax) ----------------
// v7: 256-thread blocks (R8: 512 lowered occupancy 70->64.7, +1.9us);
//     single 16B edge-record load (was esrc 4B + eattr 8B);
//     body otherwise measured-best v4 (fp8 kv, +3/+2 prefetch, __expf, dist epilogue).
__global__ __launch_bounds__(256) void k_attn(const _Float16* __restrict__ qh,
                                              const unsigned char* __restrict__ kv8,
                                              const _Float16* __restrict__ rskip,
                                              const float* __restrict__ qwb,
                                              const uint4* __restrict__ edges,
                                              const int* __restrict__ cnt,
                                              const float* __restrict__ We, const float* __restrict__ be,
                                              const float* __restrict__ Wb,
                                              unsigned short* __restrict__ hb,
                                              int loff, int N){
  int n = blockIdx.x*4 + (threadIdx.x >> 6);
  if (n >= N) return;
  int lane = threadIdx.x & 63;
  int g4 = lane >> 4;
  int w  = lane & 15;
  int hh = w & 3, t = w >> 2;
  int cbase = DHEAD*hh + 10*t;
  int slot = hh*4 + t;

  h2 qh2[5];
  {
    const unsigned* qp = (const unsigned*)(qh + (size_t)n*160 + cbase);
    #pragma unroll
    for (int i = 0; i < 5; ++i){ HU u; u.u = qp[i]; qh2[i] = u.h; }
  }
  const float* qwp = qwb + ((size_t)n*4 + hh)*5;
  float qw0 = qwp[0], qw1 = qwp[1], qw2 = qwp[2], qw3 = qwp[3], qb = qwp[4];
  h2 qw01 = pk(qw0, qw1), qw23 = pk(qw2, qw3);

  float ssum = 0.f;
  h2 zh = pk(0.f, 0.f);
  h2 acch[5], sah[2];
  #pragma unroll
  for (int i = 0; i < 5; ++i) acch[i] = zh;
  sah[0] = zh; sah[1] = zh;

  int deg = cnt[n]; if (deg > BCAP) deg = BCAP;
  int st = n*BCAP, en = st + deg;
  int B = (deg + 3) >> 2;

  // pipeline: A = processing, B = kv in flight, C = edge rec arrived / kv issuing
  int snA=0, snB=0, snC=0; bool vA=false, vB=false, vC=false;
  h2 eaA0=zh, eaA1=zh, eaB0=zh, eaB1=zh, eaC0=zh, eaC1=zh;
  {
    int p0 = st + g4;       vA = (p0 < en);
    if (vA){ uint4 e = edges[p0]; snA = (int)e.x; eaA0 = asH2(e.y); eaA1 = asH2(e.z); }
    int p1 = st + 4 + g4;   vB = (p1 < en);
    if (vB){ uint4 e = edges[p1]; snB = (int)e.x; eaB0 = asH2(e.y); eaB1 = asH2(e.z); }
    int p2 = st + 8 + g4;   vC = (p2 < en);
    if (vC){ uint4 e = edges[p2]; snC = (int)e.x; eaC0 = asH2(e.y); eaC1 = asH2(e.z); }
  }
  i32x4 cA0 = {0,0,0,0}, cB0 = {0,0,0,0}; int cA4 = 0, cB4 = 0;
  if (vA){
    const unsigned char* kp = kv8 + (size_t)snA*320 + slot*20;
    cA0 = *(const i32x4_a4*)kp; cA4 = *(const int*)(kp+16);
  }
  if (vB){
    const unsigned char* kp = kv8 + (size_t)snB*320 + slot*20;
    cB0 = *(const i32x4_a4*)kp; cB4 = *(const int*)(kp+16);
  }

  for (int b = 0; b < B; ++b){
    // prefetch edge record for edge b+3
    int snD = 0; h2 eaD0 = zh, eaD1 = zh; bool vD;
    int p3 = st + (b+3)*4 + g4;
    vD = (p3 < en);
    if (vD){ uint4 e = edges[p3]; snD = (int)e.x; eaD0 = asH2(e.y); eaD1 = asH2(e.z); }
    // prefetch kv for edge b+2 (snC arrived last iteration)
    i32x4 cC0 = {0,0,0,0}; int cC4 = 0;
    if (vC){
      const unsigned char* kp = kv8 + (size_t)snC*320 + slot*20;
      cC0 = *(const i32x4_a4*)kp; cC4 = *(const int*)(kp+16);
    }
    // compute on A (kv issued 2 iterations ago)
    float p = 0.f;
    if (vA){
      p = fdot2(qh2[0], cvt8(cA0.x), p);
      p = fdot2(qh2[1], cvt8(cA0.x >> 16), p);
      p = fdot2(qh2[2], cvt8(cA0.y), p);
      p = fdot2(qh2[3], cvt8(cA0.y >> 16), p);
      p = fdot2(qh2[4], cvt8(cA0.z), p);
    }
    p += __shfl_xor(p, 4);
    p += __shfl_xor(p, 8);
    p += qb;
    p = fdot2(eaA0, qw01, p);
    p = fdot2(eaA1, qw23, p);

    if (vA){
      float ex = __expf(p);
      ssum += ex;
      h2 eh = pk(ex, ex);
      acch[0] += cvt8(cA0.z >> 16)*eh;
      acch[1] += cvt8(cA0.w)*eh;
      acch[2] += cvt8(cA0.w >> 16)*eh;
      acch[3] += cvt8(cA4)*eh;
      acch[4] += cvt8(cA4 >> 16)*eh;
      sah[0] += eaA0*eh;
      sah[1] += eaA1*eh;
    }
    snA = snB; vA = vB; eaA0 = eaB0; eaA1 = eaB1; cA0 = cB0; cA4 = cB4;
    snB = snC; vB = vC; eaB0 = eaC0; eaB1 = eaC1; cB0 = cC0; cB4 = cC4;
    snC = snD; vC = vD; eaC0 = eaD0; eaC1 = eaD1;
  }

  // merge the 4 edge-slots: butterfly -> EVERY lane holds the full sums
  #pragma unroll
  for (int xm = 16; xm < 64; xm <<= 1){
    ssum += __shfl_xor(ssum, xm);
    #pragma unroll
    for (int i = 0; i < 5; ++i) acch[i] += shfl_h2(acch[i], xm);
    sah[0] += shfl_h2(sah[0], xm);
    sah[1] += shfl_h2(sah[1], xm);
  }

  // distributed epilogue: lane (g4, w) handles cols cbase + {g4, g4+4, g4+8}
  {
    float inv = (ssum > 0.f) ? 1.f/ssum : 0.f;
    float sw0 = (float)sah[0].x*inv, sw1 = (float)sah[0].y*inv;
    float sw2 = (float)sah[1].x*inv, sw3 = (float)sah[1].y*inv;
    float bterm = (ssum > 0.f) ? 1.f : 0.f;

    float a0 = (g4==0) ? (float)acch[0].x : (g4==1) ? (float)acch[0].y
             : (g4==2) ? (float)acch[1].x : (float)acch[1].y;     // j = g4
    float a1 = (g4==0) ? (float)acch[2].x : (g4==1) ? (float)acch[2].y
             : (g4==2) ? (float)acch[3].x : (float)acch[3].y;     // j = g4+4
    float a2 = (g4==0) ? (float)acch[4].x : (float)acch[4].y;     // j = g4+8 (g4<2 only)

    const _Float16* rp = rskip + (size_t)n*160 + cbase;
    float ov[3], rrv[3];
    float part = 0.f;
    #pragma unroll
    for (int jj = 0; jj < 3; ++jj){
      int j = g4 + 4*jj;
      float aj = (jj==0) ? a0 : (jj==1) ? a1 : a2;
      ov[jj] = 0.f; rrv[jj] = 0.f;
      if (j < 10){
        int c = cbase + j;
        float o = aj*inv + sw0*We[c] + sw1*We[160+c] + sw2*We[320+c] + sw3*We[480+c] + bterm*be[c];
        float r = (float)rp[j];
        ov[jj] = o; rrv[jj] = r;
        part += o*Wb[c] + r*Wb[160+c] + (o-r)*Wb[320+c];
      }
    }
    #pragma unroll
    for (int xm = 1; xm < 64; xm <<= 1) part += __shfl_xor(part, xm);
    float beta = 1.f/(1.f + __expf(-part));
    unsigned short* hp = hb + (size_t)n*JKW + loff + cbase;
    #pragma unroll
    for (int jj = 0; jj < 3; ++jj){
      int j = g4 + 4*jj;
      if (j < 10) hp[j] = f2bf(beta*rrv[jj] + (1.f-beta)*ov[jj]);
    }
  }
}

// ---------------- attention pooling with inline per-graph stats ----------------
__global__ __launch_bounds__(320) void k_pool(const unsigned short* __restrict__ hb, const float* __restrict__ gate,
                                              const int* __restrict__ batch, int N,
                                              float* __restrict__ pooled){
  __shared__ float sm[320];
  int g = blockIdx.x, part = blockIdx.y, j = threadIdx.x;
  int lo = lbound(batch, N, g), hi = lbound(batch, N, g+1);
  int len = hi - lo;
  if (len <= 0) return;
  float m = -INFINITY;
  for (int i = lo + j; i < hi; i += 320) m = fmaxf(m, gate[i]);
  sm[j] = m; __syncthreads();
  #pragma unroll
  for (int off = 256; off; off >>= 1){
    if (j < off && j + off < 320) sm[j] = fmaxf(sm[j], sm[j+off]);
    __syncthreads();
  }
  float gm = sm[0]; __syncthreads();
  float s = 0.f;
  for (int i = lo + j; i < hi; i += 320) s += __expf(gate[i] - gm);
  sm[j] = s; __syncthreads();
  #pragma unroll
  for (int off = 256; off; off >>= 1){
    if (j < off && j + off < 320) sm[j] += sm[j+off];
    __syncthreads();
  }
  float dg = sm[0];
  float invd = (dg > 0.f) ? 1.f/dg : 0.f;

  int chunk = (len + (int)gridDim.y - 1) / (int)gridDim.y;
  int a = lo + part*chunk;
  int bnd = a + chunk; if (bnd > hi) bnd = hi;
  if (a >= bnd) return;
  float acc = 0.f;
  for (int n = a; n < bnd; ++n){
    float at = __expf(gate[n] - gm);
    acc += at * bf2f(hb[(size_t)n*JKW + j]);
  }
  atomicAdd(&pooled[g*JKW + j], acc*invd);
}

__global__ __launch_bounds__(320) void k_head(const float* __restrict__ pooled, const float* __restrict__ Wh1,
                                              const float* __restrict__ bh1, const float* __restrict__ Wh2,
                                              const float* __restrict__ bh2, float* __restrict__ out){
  __shared__ float p[320];
  __shared__ float t[320];
  int g = blockIdx.x, tid = threadIdx.x;
  p[tid] = pooled[g*JKW + tid]; __syncthreads();
  float a = bh1[tid];
  for (int i = 0; i < 320; ++i) a += p[i]*Wh1[i*JKW + tid];
  t[tid] = fmaxf(a, 0.f); __syncthreads();
  if (tid < 6){
    float o = bh2[tid];
    for (int j = 0; j < 320; ++j) o += t[j]*Wh2[j*6 + tid];
    out[g*6 + tid] = o;
  }
}

extern "C" void kernel_launch(void* const* d_in, const int* in_sizes, int n_in,
                              void* d_out, int out_size, void* d_ws, size_t ws_size,
                              hipStream_t stream){
  (void)n_in; (void)out_size; (void)ws_size;
  const float* x        = (const float*)d_in[0];
  const int*   eidx     = (const int*)d_in[1];
  const float* edge_attr= (const float*)d_in[2];
  const int*   batch    = (const int*)d_in[3];
  const float* W_in     = (const float*)d_in[4];
  const float* b_in     = (const float*)d_in[5];
  const float* Wq       = (const float*)d_in[6];
  const float* bq       = (const float*)d_in[7];
  const float* Wk       = (const float*)d_in[8];
  const float* bk       = (const float*)d_in[9];
  const float* Wv       = (const float*)d_in[10];
  const float* bv       = (const float*)d_in[11];
  const float* We       = (const float*)d_in[12];
  const float* be       = (const float*)d_in[13];
  const float* Wsk      = (const float*)d_in[14];
  const float* bsk      = (const float*)d_in[15];
  const float* Wb       = (const float*)d_in[16];
  const float* Wg1      = (const float*)d_in[17];
  const float* bg1      = (const float*)d_in[18];
  const float* Wg2      = (const float*)d_in[19];
  const float* Wh1      = (const float*)d_in[21];
  const float* bh1      = (const float*)d_in[22];
  const float* Wh2      = (const float*)d_in[23];
  const float* bh2      = (const float*)d_in[24];

  const int N = in_sizes[0] / 5;
  const int E = in_sizes[1] / 2;
  float* out = (float*)d_out;

  char* w = (char*)d_ws;
  auto alloc = [&](size_t bytes)->char*{ char* p = w; w += (bytes + 255) & ~(size_t)255; return p; };
  unsigned short* hb = (unsigned short*)alloc((size_t)N*JKW*2);
  _Float16* qh  = (_Float16*)alloc((size_t)N*160*2);
  unsigned char* kv8 = (unsigned char*)alloc((size_t)N*320);
  _Float16* rskip = (_Float16*)alloc((size_t)N*160*2);
  float* qwb    = (float*)alloc((size_t)N*20*4);
  unsigned short* Bth  = (unsigned short*)alloc((size_t)2*640*160*2);
  unsigned short* Btgh = (unsigned short*)alloc((size_t)160*320*2);
  float* bpack  = (float*)alloc((size_t)2*640*4);
  int*   cnt    = (int*)alloc((size_t)N*4);
  uint4* edges  = (uint4*)alloc((size_t)N*BCAP*16);
  float* gate   = (float*)alloc((size_t)N*4);
  float* pooled = (float*)alloc(NGRAPH*JKW*4);

  const int* srcI = eidx;
  const int* dstI = eidx + E;

  const int NL = (N*20 + 255)/256;
  const int NZ = (N + 255)/256;
  k_pre<<<NL + 1005 + NZ, 256, 0, stream>>>(x, W_in, b_in, hb,
                                            Wq, Wk, Wv, Wsk, bq, bk, bv, bsk, Wg1,
                                            Bth, bpack, Btgh, cnt, gate, pooled, N);

  const int eb = (E + 255)/256;
  k_fill<<<eb, 256, 0, stream>>>(dstI, srcI, edge_attr, E, cnt, edges);

  const int MB128 = (N + 127)/128;
  for (int l = 0; l < 2; ++l){
    dim3 g1(5, MB128);
    k_mgemm<8,1><<<g1, 256, 0, stream>>>(hb, JKW, Bth + (size_t)l*102400, bpack + l*640,
                                         qh, kv8, rskip, nullptr, nullptr, N, HIDW);
    k_qprep<<<(N*4 + 255)/256, 256, 0, stream>>>(qh, We + l*640, be + l*160, qwb, N);
    k_attn<<<(N + 3)/4, 256, 0, stream>>>(qh, kv8, rskip, qwb, edges, cnt,
                                          We + l*640, be + l*160, Wb + l*480, hb, l*HIDW, N);
  }

  k_mgemm<10,2><<<dim3(1, MB128), 256, 0, stream>>>(hb, JKW, Btgh, bg1, nullptr, nullptr, nullptr,
                                                    Wg2, gate, N, JKW);

  dim3 g3(NGRAPH, 8);
  k_pool<<<g3, 320, 0, stream>>>(hb, gate, batch, N, pooled);
  k_head<<<NGRAPH, 320, 0, stream>>>(pooled, Wh1, bh1, Wh2, bh2, out);
}

// Round 10
// 456.819 us; speedup vs baseline: 1.1293x; 1.0533x over previous
//
#include <hip/hip_runtime.h>
#include <math.h>
#include <stddef.h>

#define NHEAD 4
#define DHEAD 40
#define HIDW 160
#define JKW 320
#define NGRAPH 32
#define BCAP 64   // edge bucket capacity per node (deg ~ Poisson(10); P(>63) ~ 1e-31)

typedef __attribute__((ext_vector_type(8))) short short8;
typedef __attribute__((ext_vector_type(4))) float f32x4;
typedef __attribute__((ext_vector_type(2))) float f32x2;
typedef __fp16 h2 __attribute__((ext_vector_type(2)));
typedef int i32x4 __attribute__((ext_vector_type(4)));
typedef i32x4 i32x4_a4 __attribute__((aligned(4)));

__device__ inline unsigned short f2bf(float x){
  unsigned u = __float_as_uint(x);
  u += 0x7fff + ((u >> 16) & 1);
  return (unsigned short)(u >> 16);
}
__device__ inline float bf2f(unsigned short h){
  return __uint_as_float(((unsigned)h) << 16);
}
__device__ inline float fdot2(h2 a, h2 b, float c){
  return __builtin_amdgcn_fdot2(a, b, c, false);
}
__device__ inline h2 pk(float a, float b){
  return __builtin_amdgcn_cvt_pkrtz(a, b);
}
union HU { h2 h; int i; unsigned u; float f; };
__device__ inline h2 shfl_h2(h2 v, int xm){
  HU u; u.h = v; u.i = __shfl_xor(u.i, xm); return u.h;
}
__device__ inline h2 asH2(unsigned i){ HU u; u.u = i; return u.h; }

#if __has_builtin(__builtin_amdgcn_cvt_pk_f16_fp8)
__device__ inline h2 cvt8(int s){ return __builtin_amdgcn_cvt_pk_f16_fp8((short)s); }
#else
__device__ inline h2 cvt8(int s){
  f32x2 t = __builtin_amdgcn_cvt_pk_f32_fp8(s, false);
  return pk(t.x, t.y);
}
#endif

__device__ inline int lbound(const int* __restrict__ b, int N, int g){
  int lo = 0, hi = N;
  while (lo < hi){ int mid = (lo + hi) >> 1; if (b[mid] < g) lo = mid + 1; else hi = mid; }
  return lo;
}

// ---------------- fused pre-pass: zero buffers + lin_in + weight pack ----------------
// v3: lin_in vectorized (8 out/thread); Bth pack reads coalesced.
__global__ __launch_bounds__(256) void k_pre(const float* __restrict__ x, const float* __restrict__ W_in,
                                             const float* __restrict__ b_in, unsigned short* __restrict__ hb,
                                             const float* __restrict__ Wq, const float* __restrict__ Wk,
                                             const float* __restrict__ Wv, const float* __restrict__ Ws,
                                             const float* __restrict__ bq, const float* __restrict__ bk,
                                             const float* __restrict__ bv, const float* __restrict__ bs,
                                             const float* __restrict__ Wg1,
                                             unsigned short* __restrict__ Bth, float* __restrict__ bp,
                                             unsigned short* __restrict__ Btgh,
                                             int* __restrict__ cnt, float* __restrict__ gate,
                                             float* __restrict__ pooled, int N){
  int NL = (N*20 + 255)/256;
  int bid = blockIdx.x, tid = threadIdx.x;
  if (bid < NL){
    int idx = bid*256 + tid;
    if (idx >= N*20) return;
    int n = idx / 20, j8 = (idx % 20)*8;
    const float* xr = x + n*5;
    float x0 = xr[0], x1 = xr[1], x2 = xr[2], x3 = xr[3], x4 = xr[4];
    float v[8];
    #pragma unroll
    for (int u = 0; u < 8; ++u) v[u] = b_in[j8+u];
    #pragma unroll
    for (int c = 0; c < 5; ++c){
      float xc = (c==0)?x0:(c==1)?x1:(c==2)?x2:(c==3)?x3:x4;
      const float4 wa = *(const float4*)(W_in + c*HIDW + j8);
      const float4 wb = *(const float4*)(W_in + c*HIDW + j8 + 4);
      v[0] += xc*wa.x; v[1] += xc*wa.y; v[2] += xc*wa.z; v[3] += xc*wa.w;
      v[4] += xc*wb.x; v[5] += xc*wb.y; v[6] += xc*wb.z; v[7] += xc*wb.w;
    }
    short8 o;
    #pragma unroll
    for (int u = 0; u < 8; ++u) o[u] = (short)f2bf(v[u]);
    *(short8*)(hb + (size_t)n*JKW + j8) = o;
  } else if (bid < NL + 1005){
    int idx = (bid - NL)*256 + tid;
    if (idx < 204800){
      int l = idx / 102400, r = idx % 102400;
      int i = r / 640, j = r % 640;            // consecutive tid -> consecutive jj (coalesced W reads)
      int sel = j / HIDW, jj = j % HIDW;
      const float* W = (sel==0) ? Wq : (sel==1) ? Wk : (sel==2) ? Wv : Ws;
      Bth[(size_t)l*102400 + (size_t)j*160 + i] = f2bf(W[(size_t)l*25600 + i*HIDW + jj]);
    } else if (idx < 256000){
      int r = idx - 204800;
      int j = r / 320, i = r % 320;
      Btgh[(size_t)j*320 + i] = f2bf(Wg1[(size_t)i*160 + j]);
    } else if (idx < 257280){
      int r = idx - 256000;
      int l = r / 640, j = r % 640;
      int sel = j / HIDW, jj = j % HIDW;
      const float* bb = (sel==0) ? bq : (sel==1) ? bk : (sel==2) ? bv : bs;
      bp[l*640 + j] = bb[l*160 + jj];
    }
  } else {
    int idx = (bid - NL - 1005)*256 + tid;
    if (idx < N){ cnt[idx] = 0; gate[idx] = 0.f; }
    if (idx < NGRAPH*JKW) pooled[idx] = 0.f;
  }
}

// ---------------- bucketed edge fill ----------------
// v2: single 16B record {src, ea01, ea23, pad} -- one scattered store per edge.
__global__ __launch_bounds__(256) void k_fill(const int* __restrict__ dst, const int* __restrict__ src,
                                              const float* __restrict__ edge_attr, int E,
                                              int* __restrict__ cnt, uint4* __restrict__ edges){
  int e = blockIdx.x*256 + threadIdx.x;
  if (e < E){
    int d = dst[e];
    int p = atomicAdd(&cnt[d], 1);
    if (p < BCAP){
      float4 ea = *(const float4*)(edge_attr + (size_t)e*4);
      HU a, b; a.h = pk(ea.x, ea.y); b.h = pk(ea.z, ea.w);
      edges[(size_t)d*BCAP + p] = make_uint4((unsigned)src[e], a.u, b.u, 0u);
    }
  }
}

// ---------------- bf16 MFMA GEMM v9: XCD-pinned row-blocks ----------------
// MODE 1 (QKV, K=160): whole B panel staged once, barrier-free 5-step k-loop.
// MODE 2 (gate, K=320): 32-k double-buffered path.
#define BSTR 40
#define BSTR1 164
template<int NSUB, int MODE>
__global__ __launch_bounds__(256) void k_mgemm(const unsigned short* __restrict__ A, int lda,
                                               const unsigned short* __restrict__ Bh,
                                               const float* __restrict__ bias,
                                               _Float16* __restrict__ qh,
                                               unsigned char* __restrict__ kv8,
                                               _Float16* __restrict__ rskip,
                                               const float* __restrict__ Wg2,
                                               float* __restrict__ gate,
                                               int M, int K){
  __shared__ short sBh[(MODE==1) ? (16*NSUB*BSTR1) : (2*16*NSUB*BSTR)];
  int tid = threadIdx.x;
  int wv = tid >> 6, lane = tid & 63;
  int quad = lane >> 4, l16 = lane & 15;

  int P = gridDim.x, MBy = gridDim.y;
  int bid = blockIdx.y * P + blockIdx.x;       // dispatch-order linear id
  int fullRows = (MBy >> 3) << 3;
  int rowB, panel;
  if (bid < fullRows * P){
    int group = bid / (8*P), rem = bid % (8*P);
    rowB  = group*8 + (rem & 7);
    panel = rem >> 3;
  } else {
    int rem = bid - fullRows*P;
    int R = MBy - fullRows;                    // 1..7 tail rows
    panel = rem / R;
    rowB  = fullRows + rem % R;
  }
  int m0 = rowB*128 + wv*32;
  int col0 = panel * (16*NSUB);

  int ar0 = m0 + l16;      if (ar0 >= M) ar0 = M - 1;
  int ar1 = m0 + 16 + l16; if (ar1 >= M) ar1 = M - 1;
  const unsigned short* Ap0 = A + (size_t)ar0*lda + quad*8;
  const unsigned short* Ap1 = A + (size_t)ar1*lda + quad*8;

  f32x4 acc[2][NSUB];
  #pragma unroll
  for (int g = 0; g < 2; ++g)
    #pragma unroll
    for (int s = 0; s < NSUB; ++s) acc[g][s] = (f32x4){0.f,0.f,0.f,0.f};

  if constexpr (MODE == 1){
    for (int u = tid; u < 16*NSUB*20; u += 256){
      int col = u / 20, q = u % 20;
      *(short8*)(&sBh[col*BSTR1 + q*8]) =
        *(const short8*)(Bh + (size_t)(col0 + col)*K + q*8);
    }
    __syncthreads();
    #pragma unroll
    for (int kk = 0; kk < 5; ++kk){
      int k0 = kk << 5;
      short8 ah0 = *(const short8*)(Ap0 + k0);
      short8 ah1 = *(const short8*)(Ap1 + k0);
      #pragma unroll
      for (int s = 0; s < NSUB; ++s){
        short8 bh = *(const short8*)(&sBh[(s*16 + l16)*BSTR1 + k0 + quad*8]);
        acc[0][s] = __builtin_amdgcn_mfma_f32_16x16x32_bf16(ah0, bh, acc[0][s], 0, 0, 0);
        acc[1][s] = __builtin_amdgcn_mfma_f32_16x16x32_bf16(ah1, bh, acc[1][s], 0, 0, 0);
      }
    }
  } else {
    const int CH = K >> 5;
    for (int u = tid; u < 16*NSUB*4; u += 256){
      int col = u >> 2, q4 = u & 3;
      *(short8*)(&sBh[col*BSTR + q4*8]) =
        *(const short8*)(Bh + (size_t)(col0 + col)*K + q4*8);
    }
    __syncthreads();
    int buf = 0;
    for (int kk = 0; kk < CH; ++kk){
      int k0 = kk << 5;
      if (kk + 1 < CH){
        int kn = k0 + 32;
        for (int u = tid; u < 16*NSUB*4; u += 256){
          int col = u >> 2, q4 = u & 3;
          *(short8*)(&sBh[(buf^1)*16*NSUB*BSTR + col*BSTR + q4*8]) =
            *(const short8*)(Bh + (size_t)(col0 + col)*K + kn + q4*8);
        }
      }
      short8 ah0 = *(const short8*)(Ap0 + k0);
      short8 ah1 = *(const short8*)(Ap1 + k0);
      #pragma unroll
      for (int s = 0; s < NSUB; ++s){
        short8 bh = *(const short8*)(&sBh[buf*16*NSUB*BSTR + (s*16 + l16)*BSTR + quad*8]);
        acc[0][s] = __builtin_amdgcn_mfma_f32_16x16x32_bf16(ah0, bh, acc[0][s], 0, 0, 0);
        acc[1][s] = __builtin_amdgcn_mfma_f32_16x16x32_bf16(ah1, bh, acc[1][s], 0, 0, 0);
      }
      __syncthreads();
      buf ^= 1;
    }
  }

  const float qscale = 0.15811388300841898f; // 1/sqrt(40)
  if (MODE == 1){
    #pragma unroll
    for (int g = 0; g < 2; ++g){
      #pragma unroll
      for (int s = 0; s < NSUB; ++s){
        int col = col0 + s*16 + l16;
        float bv = bias[col];
        int sel = col / 160, cc = col % 160;
        #pragma unroll
        for (int r = 0; r < 4; ++r){
          int row = m0 + g*16 + quad*4 + r;
          if (row >= M) continue;
          float v = acc[g][s][r] + bv;
          if (sel == 0)      qh[(size_t)row*160 + cc] = (_Float16)(v * qscale);
          else if (sel == 3) rskip[(size_t)row*160 + cc] = (_Float16)v;
          else {
            int slot = (cc/40)*4 + (cc%40)/10, j = cc%10;
            int e8 = __builtin_amdgcn_cvt_pk_fp8_f32(v, v, 0, false);
            kv8[(size_t)row*320 + slot*20 + (sel==2?10:0) + j] = (unsigned char)(e8 & 0xff);
          }
        }
      }
    }
  } else {
    float pg[2][4];
    #pragma unroll
    for (int g = 0; g < 2; ++g)
      #pragma unroll
      for (int r = 0; r < 4; ++r) pg[g][r] = 0.f;
    #pragma unroll
    for (int s = 0; s < NSUB; ++s){
      int col = col0 + s*16 + l16;
      float bv = bias[col], wg = Wg2[col];
      #pragma unroll
      for (int g = 0; g < 2; ++g)
        #pragma unroll
        for (int r = 0; r < 4; ++r)
          pg[g][r] += fmaxf(acc[g][s][r] + bv, 0.f) * wg;
    }
    #pragma unroll
    for (int g = 0; g < 2; ++g)
      #pragma unroll
      for (int r = 0; r < 4; ++r){
        float v = pg[g][r];
        v += __shfl_xor(v, 1); v += __shfl_xor(v, 2);
        v += __shfl_xor(v, 4); v += __shfl_xor(v, 8);
        int row = m0 + g*16 + quad*4 + r;
        if (l16 == 0 && row < M) atomicAdd(&gate[row], v);
      }
  }
}

// ---------------- per-node q-projection precompute ----------------
__global__ __launch_bounds__(256) void k_qprep(const _Float16* __restrict__ qh,
                                               const float* __restrict__ We, const float* __restrict__ be,
                                               float* __restrict__ qwb, int N){
  int idx = blockIdx.x*256 + threadIdx.x;
  if (idx >= N*4) return;
  int n = idx >> 2, h = idx & 3;
  const unsigned* qp = (const unsigned*)(qh + (size_t)n*160 + h*40);
  float w0=0.f,w1=0.f,w2=0.f,w3=0.f,b=0.f;
  #pragma unroll
  for (int i = 0; i < 20; ++i){
    HU u; u.u = qp[i];
    float qa = (float)u.h.x, qb = (float)u.h.y;
    int c = h*40 + 2*i;
    w0 += qa*We[c]       + qb*We[c+1];
    w1 += qa*We[160+c]   + qb*We[161+c];
    w2 += qa*We[320+c]   + qb*We[321+c];
    w3 += qa*We[480+c]   + qb*We[481+c];
    b  += qa*be[c]       + qb*be[c+1];
  }
  float* o = qwb + (size_t)idx*5;
  o[0]=w0; o[1]=w1; o[2]=w2; o[3]=w3; o[4]=b;
}

// ---------------- fused edge attention + beta gate (fp8 kv, no-max softmax) ----------------
// v8: ONE NODE PER 16-LANE GROUP (4 nodes/wave, 16/block). Each group walks its
// node's edges serially -> the 3-stage xm=16/32 butterfly merge (27 shfls/node,
// the dominant per-node tail at deg~10) is eliminated; epilogue has each lane
// owning 10 contiguous cols (no g4-select, packed dword hb stores).
// Cost: wave runs max(deg of 4 nodes) iters (~+13% loop util) -- net win.
__global__ __launch_bounds__(256) void k_attn(const _Float16* __restrict__ qh,
                                              const unsigned char* __restrict__ kv8,
                                              const _Float16* __restrict__ rskip,
                                              const float* __restrict__ qwb,
                                              const uint4* __restrict__ edges,
                                              const int* __restrict__ cnt,
                                              const float* __restrict__ We, const float* __restrict__ be,
                                              const float* __restrict__ Wb,
                                              unsigned short* __restrict__ hb,
                                              int loff, int N){
  int tid = threadIdx.x;
  int grp = tid >> 4;                 // 16 groups per block
  int n = blockIdx.x*16 + grp;
  bool valid = (n < N);
  int nn = valid ? n : (N-1);
  int w = tid & 15;
  int hh = w & 3, t = w >> 2;
  int cbase = DHEAD*hh + 10*t;
  int slot = hh*4 + t;

  h2 qh2[5];
  {
    const unsigned* qp = (const unsigned*)(qh + (size_t)nn*160 + cbase);
    #pragma unroll
    for (int i = 0; i < 5; ++i) qh2[i] = asH2(qp[i]);
  }
  const float* qwp = qwb + ((size_t)nn*4 + hh)*5;
  float qw0 = qwp[0], qw1 = qwp[1], qw2 = qwp[2], qw3 = qwp[3], qb = qwp[4];
  h2 qw01 = pk(qw0, qw1), qw23 = pk(qw2, qw3);

  float ssum = 0.f;
  h2 zh = pk(0.f, 0.f);
  h2 acch[5], sah[2];
  #pragma unroll
  for (int i = 0; i < 5; ++i) acch[i] = zh;
  sah[0] = zh; sah[1] = zh;

  int deg = 0;
  if (valid){ deg = cnt[nn]; if (deg > BCAP) deg = BCAP; }
  int st = nn*BCAP;

  // serial pipeline: compute edge e; kv for e+1 in flight; record e+2 arrived
  uint4 recA = make_uint4(0,0,0,0), recB = make_uint4(0,0,0,0);
  i32x4 cA0 = {0,0,0,0}; int cA4 = 0;
  if (deg > 0) recA = edges[st];
  if (deg > 1) recB = edges[st+1];
  if (deg > 0){
    const unsigned char* kp = kv8 + (size_t)recA.x*320 + slot*20;
    cA0 = *(const i32x4_a4*)kp; cA4 = *(const int*)(kp+16);
  }

  for (int e = 0; e < deg; ++e){
    uint4 recC = make_uint4(0,0,0,0);
    if (e + 2 < deg) recC = edges[st + e + 2];
    i32x4 cB0 = {0,0,0,0}; int cB4 = 0;
    if (e + 1 < deg){
      const unsigned char* kp = kv8 + (size_t)recB.x*320 + slot*20;
      cB0 = *(const i32x4_a4*)kp; cB4 = *(const int*)(kp+16);
    }
    h2 ea0 = asH2(recA.y), ea1 = asH2(recA.z);
    float p = 0.f;
    p = fdot2(qh2[0], cvt8(cA0.x), p);
    p = fdot2(qh2[1], cvt8(cA0.x >> 16), p);
    p = fdot2(qh2[2], cvt8(cA0.y), p);
    p = fdot2(qh2[3], cvt8(cA0.y >> 16), p);
    p = fdot2(qh2[4], cvt8(cA0.z), p);
    p += __shfl_xor(p, 4);          // sum over t within the head (within 16-lane group)
    p += __shfl_xor(p, 8);
    p += qb;
    p = fdot2(ea0, qw01, p);
    p = fdot2(ea1, qw23, p);

    float ex = __expf(p);
    ssum += ex;
    h2 eh = pk(ex, ex);
    acch[0] += cvt8(cA0.z >> 16)*eh;
    acch[1] += cvt8(cA0.w)*eh;
    acch[2] += cvt8(cA0.w >> 16)*eh;
    acch[3] += cvt8(cA4)*eh;
    acch[4] += cvt8(cA4 >> 16)*eh;
    sah[0] += ea0*eh;
    sah[1] += ea1*eh;

    recA = recB; recB = recC; cA0 = cB0; cA4 = cB4;
  }

  // epilogue: no cross-slot merge needed -- each lane owns cols cbase..cbase+9
  {
    float inv = (ssum > 0.f) ? 1.f/ssum : 0.f;
    float sw0 = (float)sah[0].x*inv, sw1 = (float)sah[0].y*inv;
    float sw2 = (float)sah[1].x*inv, sw3 = (float)sah[1].y*inv;
    float bterm = (ssum > 0.f) ? 1.f : 0.f;

    const unsigned* rpu = (const unsigned*)(rskip + (size_t)nn*160 + cbase);
    float o[10];
    float part = 0.f;
    #pragma unroll
    for (int i = 0; i < 5; ++i){
      int c = cbase + 2*i;
      float o0 = (float)acch[i].x*inv + sw0*We[c]   + sw1*We[160+c] + sw2*We[320+c] + sw3*We[480+c] + bterm*be[c];
      float o1 = (float)acch[i].y*inv + sw0*We[c+1] + sw1*We[161+c] + sw2*We[321+c] + sw3*We[481+c] + bterm*be[c+1];
      HU u; u.u = rpu[i];
      float r0 = (float)u.h.x, r1 = (float)u.h.y;
      part += o0*Wb[c]   + r0*Wb[160+c] + (o0-r0)*Wb[320+c];
      part += o1*Wb[c+1] + r1*Wb[161+c] + (o1-r1)*Wb[321+c];
      o[2*i] = o0; o[2*i+1] = o1;
    }
    part += __shfl_xor(part, 1); part += __shfl_xor(part, 2);
    part += __shfl_xor(part, 4); part += __shfl_xor(part, 8);
    float beta = 1.f/(1.f + __expf(-part));
    if (valid){
      unsigned* hp32 = (unsigned*)(hb + (size_t)nn*JKW + loff);
      #pragma unroll
      for (int i = 0; i < 5; ++i){
        HU u; u.u = rpu[i];
        float r0 = (float)u.h.x, r1 = (float)u.h.y;
        unsigned lo = f2bf(beta*r0 + (1.f-beta)*o[2*i]);
        unsigned hi = f2bf(beta*r1 + (1.f-beta)*o[2*i+1]);
        hp32[cbase/2 + i] = lo | (hi << 16);
      }
    }
  }
}

// ---------------- attention pooling with inline per-graph stats ----------------
__global__ __launch_bounds__(320) void k_pool(const unsigned short* __restrict__ hb, const float* __restrict__ gate,
                                              const int* __restrict__ batch, int N,
                                              float* __restrict__ pooled){
  __shared__ float sm[320];
  int g = blockIdx.x, part = blockIdx.y, j = threadIdx.x;
  int lo = lbound(batch, N, g), hi = lbound(batch, N, g+1);
  int len = hi - lo;
  if (len <= 0) return;
  float m = -INFINITY;
  for (int i = lo + j; i < hi; i += 320) m = fmaxf(m, gate[i]);
  sm[j] = m; __syncthreads();
  #pragma unroll
  for (int off = 256; off; off >>= 1){
    if (j < off && j + off < 320) sm[j] = fmaxf(sm[j], sm[j+off]);
    __syncthreads();
  }
  float gm = sm[0]; __syncthreads();
  float s = 0.f;
  for (int i = lo + j; i < hi; i += 320) s += __expf(gate[i] - gm);
  sm[j] = s; __syncthreads();
  #pragma unroll
  for (int off = 256; off; off >>= 1){
    if (j < off && j + off < 320) sm[j] += sm[j+off];
    __syncthreads();
  }
  float dg = sm[0];
  float invd = (dg > 0.f) ? 1.f/dg : 0.f;

  int chunk = (len + (int)gridDim.y - 1) / (int)gridDim.y;
  int a = lo + part*chunk;
  int bnd = a + chunk; if (bnd > hi) bnd = hi;
  if (a >= bnd) return;
  float acc = 0.f;
  for (int n = a; n < bnd; ++n){
    float at = __expf(gate[n] - gm);
    acc += at * bf2f(hb[(size_t)n*JKW + j]);
  }
  atomicAdd(&pooled[g*JKW + j], acc*invd);
}

__global__ __launch_bounds__(320) void k_head(const float* __restrict__ pooled, const float* __restrict__ Wh1,
                                              const float* __restrict__ bh1, const float* __restrict__ Wh2,
                                              const float* __restrict__ bh2, float* __restrict__ out){
  __shared__ float p[320];
  __shared__ float t[320];
  int g = blockIdx.x, tid = threadIdx.x;
  p[tid] = pooled[g*JKW + tid]; __syncthreads();
  float a = bh1[tid];
  for (int i = 0; i < 320; ++i) a += p[i]*Wh1[i*JKW + tid];
  t[tid] = fmaxf(a, 0.f); __syncthreads();
  if (tid < 6){
    float o = bh2[tid];
    for (int j = 0; j < 320; ++j) o += t[j]*Wh2[j*6 + tid];
    out[g*6 + tid] = o;
  }
}

extern "C" void kernel_launch(void* const* d_in, const int* in_sizes, int n_in,
                              void* d_out, int out_size, void* d_ws, size_t ws_size,
                              hipStream_t stream){
  (void)n_in; (void)out_size; (void)ws_size;
  const float* x        = (const float*)d_in[0];
  const int*   eidx     = (const int*)d_in[1];
  const float* edge_attr= (const float*)d_in[2];
  const int*   batch    = (const int*)d_in[3];
  const float* W_in     = (const float*)d_in[4];
  const float* b_in     = (const float*)d_in[5];
  const float* Wq       = (const float*)d_in[6];
  const float* bq       = (const float*)d_in[7];
  const float* Wk       = (const float*)d_in[8];
  const float* bk       = (const float*)d_in[9];
  const float* Wv       = (const float*)d_in[10];
  const float* bv       = (const float*)d_in[11];
  const float* We       = (const float*)d_in[12];
  const float* be       = (const float*)d_in[13];
  const float* Wsk      = (const float*)d_in[14];
  const float* bsk      = (const float*)d_in[15];
  const float* Wb       = (const float*)d_in[16];
  const float* Wg1      = (const float*)d_in[17];
  const float* bg1      = (const float*)d_in[18];
  const float* Wg2      = (const float*)d_in[19];
  const float* Wh1      = (const float*)d_in[21];
  const float* bh1      = (const float*)d_in[22];
  const float* Wh2      = (const float*)d_in[23];
  const float* bh2      = (const float*)d_in[24];

  const int N = in_sizes[0] / 5;
  const int E = in_sizes[1] / 2;
  float* out = (float*)d_out;

  char* w = (char*)d_ws;
  auto alloc = [&](size_t bytes)->char*{ char* p = w; w += (bytes + 255) & ~(size_t)255; return p; };
  unsigned short* hb = (unsigned short*)alloc((size_t)N*JKW*2);
  _Float16* qh  = (_Float16*)alloc((size_t)N*160*2);
  unsigned char* kv8 = (unsigned char*)alloc((size_t)N*320);
  _Float16* rskip = (_Float16*)alloc((size_t)N*160*2);
  float* qwb    = (float*)alloc((size_t)N*20*4);
  unsigned short* Bth  = (unsigned short*)alloc((size_t)2*640*160*2);
  unsigned short* Btgh = (unsigned short*)alloc((size_t)160*320*2);
  float* bpack  = (float*)alloc((size_t)2*640*4);
  int*   cnt    = (int*)alloc((size_t)N*4);
  uint4* edges  = (uint4*)alloc((size_t)N*BCAP*16);
  float* gate   = (float*)alloc((size_t)N*4);
  float* pooled = (float*)alloc(NGRAPH*JKW*4);

  const int* srcI = eidx;
  const int* dstI = eidx + E;

  const int NL = (N*20 + 255)/256;
  const int NZ = (N + 255)/256;
  k_pre<<<NL + 1005 + NZ, 256, 0, stream>>>(x, W_in, b_in, hb,
                                            Wq, Wk, Wv, Wsk, bq, bk, bv, bsk, Wg1,
                                            Bth, bpack, Btgh, cnt, gate, pooled, N);

  const int eb = (E + 255)/256;
  k_fill<<<eb, 256, 0, stream>>>(dstI, srcI, edge_attr, E, cnt, edges);

  const int MB128 = (N + 127)/128;
  for (int l = 0; l < 2; ++l){
    dim3 g1(5, MB128);
    k_mgemm<8,1><<<g1, 256, 0, stream>>>(hb, JKW, Bth + (size_t)l*102400, bpack + l*640,
                                         qh, kv8, rskip, nullptr, nullptr, N, HIDW);
    k_qprep<<<(N*4 + 255)/256, 256, 0, stream>>>(qh, We + l*640, be + l*160, qwb, N);
    k_attn<<<(N + 15)/16, 256, 0, stream>>>(qh, kv8, rskip, qwb, edges, cnt,
                                            We + l*640, be + l*160, Wb + l*480, hb, l*HIDW, N);
  }

  k_mgemm<10,2><<<dim3(1, MB128), 256, 0, stream>>>(hb, JKW, Btgh, bg1, nullptr, nullptr, nullptr,
                                                    Wg2, gate, N, JKW);

  dim3 g3(NGRAPH, 8);
  k_pool<<<g3, 320, 0, stream>>>(hb, gate, batch, N, pooled);
  k_head<<<NGRAPH, 320, 0, stream>>>(pooled, Wh1, bh1, Wh2, bh2, out);
}

// Round 11
// 429.015 us; speedup vs baseline: 1.2025x; 1.0648x over previous
//
#include <hip/hip_runtime.h>
#include <math.h>
#include <stddef.h>

#define NHEAD 4
#define DHEAD 40
#define HIDW 160
#define JKW 320
#define NGRAPH 32
#define BCAP 64   // edge bucket capacity per node (deg ~ Poisson(10); P(>63) ~ 1e-31)

typedef __attribute__((ext_vector_type(8))) short short8;
typedef __attribute__((ext_vector_type(4))) float f32x4;
typedef __attribute__((ext_vector_type(2))) float f32x2;
typedef __fp16 h2 __attribute__((ext_vector_type(2)));
typedef int i32x4 __attribute__((ext_vector_type(4)));
typedef i32x4 i32x4_a4 __attribute__((aligned(4)));

__device__ inline unsigned short f2bf(float x){
  unsigned u = __float_as_uint(x);
  u += 0x7fff + ((u >> 16) & 1);
  return (unsigned short)(u >> 16);
}
__device__ inline float bf2f(unsigned short h){
  return __uint_as_float(((unsigned)h) << 16);
}
__device__ inline float fdot2(h2 a, h2 b, float c){
  return __builtin_amdgcn_fdot2(a, b, c, false);
}
__device__ inline h2 pk(float a, float b){
  return __builtin_amdgcn_cvt_pkrtz(a, b);
}
union HU { h2 h; int i; unsigned u; float f; };
__device__ inline h2 shfl_h2(h2 v, int xm){
  HU u; u.h = v; u.i = __shfl_xor(u.i, xm); return u.h;
}
__device__ inline h2 asH2(unsigned i){ HU u; u.u = i; return u.h; }

#if __has_builtin(__builtin_amdgcn_cvt_pk_f16_fp8)
__device__ inline h2 cvt8(int s){ return __builtin_amdgcn_cvt_pk_f16_fp8((short)s); }
#else
__device__ inline h2 cvt8(int s){
  f32x2 t = __builtin_amdgcn_cvt_pk_f32_fp8(s, false);
  return pk(t.x, t.y);
}
#endif

__device__ inline int lbound(const int* __restrict__ b, int N, int g){
  int lo = 0, hi = N;
  while (lo < hi){ int mid = (lo + hi) >> 1; if (b[mid] < g) lo = mid + 1; else hi = mid; }
  return lo;
}

// ---------------- fused pre-pass: zero buffers + lin_in + weight pack ----------------
// v3: lin_in vectorized (8 out/thread); Bth pack reads coalesced.
__global__ __launch_bounds__(256) void k_pre(const float* __restrict__ x, const float* __restrict__ W_in,
                                             const float* __restrict__ b_in, unsigned short* __restrict__ hb,
                                             const float* __restrict__ Wq, const float* __restrict__ Wk,
                                             const float* __restrict__ Wv, const float* __restrict__ Ws,
                                             const float* __restrict__ bq, const float* __restrict__ bk,
                                             const float* __restrict__ bv, const float* __restrict__ bs,
                                             const float* __restrict__ Wg1,
                                             unsigned short* __restrict__ Bth, float* __restrict__ bp,
                                             unsigned short* __restrict__ Btgh,
                                             int* __restrict__ cnt, float* __restrict__ gate,
                                             float* __restrict__ pooled, int N){
  int NL = (N*20 + 255)/256;
  int bid = blockIdx.x, tid = threadIdx.x;
  if (bid < NL){
    int idx = bid*256 + tid;
    if (idx >= N*20) return;
    int n = idx / 20, j8 = (idx % 20)*8;
    const float* xr = x + n*5;
    float x0 = xr[0], x1 = xr[1], x2 = xr[2], x3 = xr[3], x4 = xr[4];
    float v[8];
    #pragma unroll
    for (int u = 0; u < 8; ++u) v[u] = b_in[j8+u];
    #pragma unroll
    for (int c = 0; c < 5; ++c){
      float xc = (c==0)?x0:(c==1)?x1:(c==2)?x2:(c==3)?x3:x4;
      const float4 wa = *(const float4*)(W_in + c*HIDW + j8);
      const float4 wb = *(const float4*)(W_in + c*HIDW + j8 + 4);
      v[0] += xc*wa.x; v[1] += xc*wa.y; v[2] += xc*wa.z; v[3] += xc*wa.w;
      v[4] += xc*wb.x; v[5] += xc*wb.y; v[6] += xc*wb.z; v[7] += xc*wb.w;
    }
    short8 o;
    #pragma unroll
    for (int u = 0; u < 8; ++u) o[u] = (short)f2bf(v[u]);
    *(short8*)(hb + (size_t)n*JKW + j8) = o;
  } else if (bid < NL + 1005){
    int idx = (bid - NL)*256 + tid;
    if (idx < 204800){
      int l = idx / 102400, r = idx % 102400;
      int i = r / 640, j = r % 640;            // consecutive tid -> consecutive jj (coalesced W reads)
      int sel = j / HIDW, jj = j % HIDW;
      const float* W = (sel==0) ? Wq : (sel==1) ? Wk : (sel==2) ? Wv : Ws;
      Bth[(size_t)l*102400 + (size_t)j*160 + i] = f2bf(W[(size_t)l*25600 + i*HIDW + jj]);
    } else if (idx < 256000){
      int r = idx - 204800;
      int j = r / 320, i = r % 320;
      Btgh[(size_t)j*320 + i] = f2bf(Wg1[(size_t)i*160 + j]);
    } else if (idx < 257280){
      int r = idx - 256000;
      int l = r / 640, j = r % 640;
      int sel = j / HIDW, jj = j % HIDW;
      const float* bb = (sel==0) ? bq : (sel==1) ? bk : (sel==2) ? bv : bs;
      bp[l*640 + j] = bb[l*160 + jj];
    }
  } else {
    int idx = (bid - NL - 1005)*256 + tid;
    if (idx < N){ cnt[idx] = 0; gate[idx] = 0.f; }
    if (idx < NGRAPH*JKW) pooled[idx] = 0.f;
  }
}

// ---------------- bucketed edge fill ----------------
// v2: single 16B record {src, ea01, ea23, pad} -- one scattered store per edge.
__global__ __launch_bounds__(256) void k_fill(const int* __restrict__ dst, const int* __restrict__ src,
                                              const float* __restrict__ edge_attr, int E,
                                              int* __restrict__ cnt, uint4* __restrict__ edges){
  int e = blockIdx.x*256 + threadIdx.x;
  if (e < E){
    int d = dst[e];
    int p = atomicAdd(&cnt[d], 1);
    if (p < BCAP){
      float4 ea = *(const float4*)(edge_attr + (size_t)e*4);
      HU a, b; a.h = pk(ea.x, ea.y); b.h = pk(ea.z, ea.w);
      edges[(size_t)d*BCAP + p] = make_uint4((unsigned)src[e], a.u, b.u, 0u);
    }
  }
}

// ---------------- bf16 MFMA GEMM v9: XCD-pinned row-blocks ----------------
// MODE 1 (QKV, K=160): whole B panel staged once, barrier-free 5-step k-loop.
// MODE 2 (gate, K=320): 32-k double-buffered path.
#define BSTR 40
#define BSTR1 164
template<int NSUB, int MODE>
__global__ __launch_bounds__(256) void k_mgemm(const unsigned short* __restrict__ A, int lda,
                                               const unsigned short* __restrict__ Bh,
                                               const float* __restrict__ bias,
                                               _Float16* __restrict__ qh,
                                               unsigned char* __restrict__ kv8,
                                               _Float16* __restrict__ rskip,
                                               const float* __restrict__ Wg2,
                                               float* __restrict__ gate,
                                               int M, int K){
  __shared__ short sBh[(MODE==1) ? (16*NSUB*BSTR1) : (2*16*NSUB*BSTR)];
  int tid = threadIdx.x;
  int wv = tid >> 6, lane = tid & 63;
  int quad = lane >> 4, l16 = lane & 15;

  int P = gridDim.x, MBy = gridDim.y;
  int bid = blockIdx.y * P + blockIdx.x;       // dispatch-order linear id
  int fullRows = (MBy >> 3) << 3;
  int rowB, panel;
  if (bid < fullRows * P){
    int group = bid / (8*P), rem = bid % (8*P);
    rowB  = group*8 + (rem & 7);
    panel = rem >> 3;
  } else {
    int rem = bid - fullRows*P;
    int R = MBy - fullRows;                    // 1..7 tail rows
    panel = rem / R;
    rowB  = fullRows + rem % R;
  }
  int m0 = rowB*128 + wv*32;
  int col0 = panel * (16*NSUB);

  int ar0 = m0 + l16;      if (ar0 >= M) ar0 = M - 1;
  int ar1 = m0 + 16 + l16; if (ar1 >= M) ar1 = M - 1;
  const unsigned short* Ap0 = A + (size_t)ar0*lda + quad*8;
  const unsigned short* Ap1 = A + (size_t)ar1*lda + quad*8;

  f32x4 acc[2][NSUB];
  #pragma unroll
  for (int g = 0; g < 2; ++g)
    #pragma unroll
    for (int s = 0; s < NSUB; ++s) acc[g][s] = (f32x4){0.f,0.f,0.f,0.f};

  if constexpr (MODE == 1){
    for (int u = tid; u < 16*NSUB*20; u += 256){
      int col = u / 20, q = u % 20;
      *(short8*)(&sBh[col*BSTR1 + q*8]) =
        *(const short8*)(Bh + (size_t)(col0 + col)*K + q*8);
    }
    __syncthreads();
    #pragma unroll
    for (int kk = 0; kk < 5; ++kk){
      int k0 = kk << 5;
      short8 ah0 = *(const short8*)(Ap0 + k0);
      short8 ah1 = *(const short8*)(Ap1 + k0);
      #pragma unroll
      for (int s = 0; s < NSUB; ++s){
        short8 bh = *(const short8*)(&sBh[(s*16 + l16)*BSTR1 + k0 + quad*8]);
        acc[0][s] = __builtin_amdgcn_mfma_f32_16x16x32_bf16(ah0, bh, acc[0][s], 0, 0, 0);
        acc[1][s] = __builtin_amdgcn_mfma_f32_16x16x32_bf16(ah1, bh, acc[1][s], 0, 0, 0);
      }
    }
  } else {
    const int CH = K >> 5;
    for (int u = tid; u < 16*NSUB*4; u += 256){
      int col = u >> 2, q4 = u & 3;
      *(short8*)(&sBh[col*BSTR + q4*8]) =
        *(const short8*)(Bh + (size_t)(col0 + col)*K + q4*8);
    }
    __syncthreads();
    int buf = 0;
    for (int kk = 0; kk < CH; ++kk){
      int k0 = kk << 5;
      if (kk + 1 < CH){
        int kn = k0 + 32;
        for (int u = tid; u < 16*NSUB*4; u += 256){
          int col = u >> 2, q4 = u & 3;
          *(short8*)(&sBh[(buf^1)*16*NSUB*BSTR + col*BSTR + q4*8]) =
            *(const short8*)(Bh + (size_t)(col0 + col)*K + kn + q4*8);
        }
      }
      short8 ah0 = *(const short8*)(Ap0 + k0);
      short8 ah1 = *(const short8*)(Ap1 + k0);
      #pragma unroll
      for (int s = 0; s < NSUB; ++s){
        short8 bh = *(const short8*)(&sBh[buf*16*NSUB*BSTR + (s*16 + l16)*BSTR + quad*8]);
        acc[0][s] = __builtin_amdgcn_mfma_f32_16x16x32_bf16(ah0, bh, acc[0][s], 0, 0, 0);
        acc[1][s] = __builtin_amdgcn_mfma_f32_16x16x32_bf16(ah1, bh, acc[1][s], 0, 0, 0);
      }
      __syncthreads();
      buf ^= 1;
    }
  }

  const float qscale = 0.15811388300841898f; // 1/sqrt(40)
  if (MODE == 1){
    #pragma unroll
    for (int g = 0; g < 2; ++g){
      #pragma unroll
      for (int s = 0; s < NSUB; ++s){
        int col = col0 + s*16 + l16;
        float bv = bias[col];
        int sel = col / 160, cc = col % 160;
        #pragma unroll
        for (int r = 0; r < 4; ++r){
          int row = m0 + g*16 + quad*4 + r;
          if (row >= M) continue;
          float v = acc[g][s][r] + bv;
          if (sel == 0)      qh[(size_t)row*160 + cc] = (_Float16)(v * qscale);
          else if (sel == 3) rskip[(size_t)row*160 + cc] = (_Float16)v;
          else {
            int slot = (cc/40)*4 + (cc%40)/10, j = cc%10;
            int e8 = __builtin_amdgcn_cvt_pk_fp8_f32(v, v, 0, false);
            kv8[(size_t)row*320 + slot*20 + (sel==2?10:0) + j] = (unsigned char)(e8 & 0xff);
          }
        }
      }
    }
  } else {
    float pg[2][4];
    #pragma unroll
    for (int g = 0; g < 2; ++g)
      #pragma unroll
      for (int r = 0; r < 4; ++r) pg[g][r] = 0.f;
    #pragma unroll
    for (int s = 0; s < NSUB; ++s){
      int col = col0 + s*16 + l16;
      float bv = bias[col], wg = Wg2[col];
      #pragma unroll
      for (int g = 0; g < 2; ++g)
        #pragma unroll
        for (int r = 0; r < 4; ++r)
          pg[g][r] += fmaxf(acc[g][s][r] + bv, 0.f) * wg;
    }
    #pragma unroll
    for (int g = 0; g < 2; ++g)
      #pragma unroll
      for (int r = 0; r < 4; ++r){
        float v = pg[g][r];
        v += __shfl_xor(v, 1); v += __shfl_xor(v, 2);
        v += __shfl_xor(v, 4); v += __shfl_xor(v, 8);
        int row = m0 + g*16 + quad*4 + r;
        if (l16 == 0 && row < M) atomicAdd(&gate[row], v);
      }
  }
}

// ---------------- per-node q-projection precompute ----------------
__global__ __launch_bounds__(256) void k_qprep(const _Float16* __restrict__ qh,
                                               const float* __restrict__ We, const float* __restrict__ be,
                                               float* __restrict__ qwb, int N){
  int idx = blockIdx.x*256 + threadIdx.x;
  if (idx >= N*4) return;
  int n = idx >> 2, h = idx & 3;
  const unsigned* qp = (const unsigned*)(qh + (size_t)n*160 + h*40);
  float w0=0.f,w1=0.f,w2=0.f,w3=0.f,b=0.f;
  #pragma unroll
  for (int i = 0; i < 20; ++i){
    HU u; u.u = qp[i];
    float qa = (float)u.h.x, qb = (float)u.h.y;
    int c = h*40 + 2*i;
    w0 += qa*We[c]       + qb*We[c+1];
    w1 += qa*We[160+c]   + qb*We[161+c];
    w2 += qa*We[320+c]   + qb*We[321+c];
    w3 += qa*We[480+c]   + qb*We[481+c];
    b  += qa*be[c]       + qb*be[c+1];
  }
  float* o = qwb + (size_t)idx*5;
  o[0]=w0; o[1]=w1; o[2]=w2; o[3]=w3; o[4]=b;
}

// ---------------- fused edge attention + beta gate (fp8 kv, no-max softmax) ----------------
// v8: one node per 16-lane group (measured best, R10).
__global__ __launch_bounds__(256) void k_attn(const _Float16* __restrict__ qh,
                                              const unsigned char* __restrict__ kv8,
                                              const _Float16* __restrict__ rskip,
                                              const float* __restrict__ qwb,
                                              const uint4* __restrict__ edges,
                                              const int* __restrict__ cnt,
                                              const float* __restrict__ We, const float* __restrict__ be,
                                              const float* __restrict__ Wb,
                                              unsigned short* __restrict__ hb,
                                              int loff, int N){
  int tid = threadIdx.x;
  int grp = tid >> 4;                 // 16 groups per block
  int n = blockIdx.x*16 + grp;
  bool valid = (n < N);
  int nn = valid ? n : (N-1);
  int w = tid & 15;
  int hh = w & 3, t = w >> 2;
  int cbase = DHEAD*hh + 10*t;
  int slot = hh*4 + t;

  h2 qh2[5];
  {
    const unsigned* qp = (const unsigned*)(qh + (size_t)nn*160 + cbase);
    #pragma unroll
    for (int i = 0; i < 5; ++i) qh2[i] = asH2(qp[i]);
  }
  const float* qwp = qwb + ((size_t)nn*4 + hh)*5;
  float qw0 = qwp[0], qw1 = qwp[1], qw2 = qwp[2], qw3 = qwp[3], qb = qwp[4];
  h2 qw01 = pk(qw0, qw1), qw23 = pk(qw2, qw3);

  float ssum = 0.f;
  h2 zh = pk(0.f, 0.f);
  h2 acch[5], sah[2];
  #pragma unroll
  for (int i = 0; i < 5; ++i) acch[i] = zh;
  sah[0] = zh; sah[1] = zh;

  int deg = 0;
  if (valid){ deg = cnt[nn]; if (deg > BCAP) deg = BCAP; }
  int st = nn*BCAP;

  // serial pipeline: compute edge e; kv for e+1 in flight; record e+2 arrived
  uint4 recA = make_uint4(0,0,0,0), recB = make_uint4(0,0,0,0);
  i32x4 cA0 = {0,0,0,0}; int cA4 = 0;
  if (deg > 0) recA = edges[st];
  if (deg > 1) recB = edges[st+1];
  if (deg > 0){
    const unsigned char* kp = kv8 + (size_t)recA.x*320 + slot*20;
    cA0 = *(const i32x4_a4*)kp; cA4 = *(const int*)(kp+16);
  }

  for (int e = 0; e < deg; ++e){
    uint4 recC = make_uint4(0,0,0,0);
    if (e + 2 < deg) recC = edges[st + e + 2];
    i32x4 cB0 = {0,0,0,0}; int cB4 = 0;
    if (e + 1 < deg){
      const unsigned char* kp = kv8 + (size_t)recB.x*320 + slot*20;
      cB0 = *(const i32x4_a4*)kp; cB4 = *(const int*)(kp+16);
    }
    h2 ea0 = asH2(recA.y), ea1 = asH2(recA.z);
    float p = 0.f;
    p = fdot2(qh2[0], cvt8(cA0.x), p);
    p = fdot2(qh2[1], cvt8(cA0.x >> 16), p);
    p = fdot2(qh2[2], cvt8(cA0.y), p);
    p = fdot2(qh2[3], cvt8(cA0.y >> 16), p);
    p = fdot2(qh2[4], cvt8(cA0.z), p);
    p += __shfl_xor(p, 4);          // sum over t within the head (within 16-lane group)
    p += __shfl_xor(p, 8);
    p += qb;
    p = fdot2(ea0, qw01, p);
    p = fdot2(ea1, qw23, p);

    float ex = __expf(p);
    ssum += ex;
    h2 eh = pk(ex, ex);
    acch[0] += cvt8(cA0.z >> 16)*eh;
    acch[1] += cvt8(cA0.w)*eh;
    acch[2] += cvt8(cA0.w >> 16)*eh;
    acch[3] += cvt8(cA4)*eh;
    acch[4] += cvt8(cA4 >> 16)*eh;
    sah[0] += ea0*eh;
    sah[1] += ea1*eh;

    recA = recB; recB = recC; cA0 = cB0; cA4 = cB4;
  }

  // epilogue: each lane owns cols cbase..cbase+9
  {
    float inv = (ssum > 0.f) ? 1.f/ssum : 0.f;
    float sw0 = (float)sah[0].x*inv, sw1 = (float)sah[0].y*inv;
    float sw2 = (float)sah[1].x*inv, sw3 = (float)sah[1].y*inv;
    float bterm = (ssum > 0.f) ? 1.f : 0.f;

    const unsigned* rpu = (const unsigned*)(rskip + (size_t)nn*160 + cbase);
    float o[10];
    float part = 0.f;
    #pragma unroll
    for (int i = 0; i < 5; ++i){
      int c = cbase + 2*i;
      float o0 = (float)acch[i].x*inv + sw0*We[c]   + sw1*We[160+c] + sw2*We[320+c] + sw3*We[480+c] + bterm*be[c];
      float o1 = (float)acch[i].y*inv + sw0*We[c+1] + sw1*We[161+c] + sw2*We[321+c] + sw3*We[481+c] + bterm*be[c+1];
      HU u; u.u = rpu[i];
      float r0 = (float)u.h.x, r1 = (float)u.h.y;
      part += o0*Wb[c]   + r0*Wb[160+c] + (o0-r0)*Wb[320+c];
      part += o1*Wb[c+1] + r1*Wb[161+c] + (o1-r1)*Wb[321+c];
      o[2*i] = o0; o[2*i+1] = o1;
    }
    part += __shfl_xor(part, 1); part += __shfl_xor(part, 2);
    part += __shfl_xor(part, 4); part += __shfl_xor(part, 8);
    float beta = 1.f/(1.f + __expf(-part));
    if (valid){
      unsigned* hp32 = (unsigned*)(hb + (size_t)nn*JKW + loff);
      #pragma unroll
      for (int i = 0; i < 5; ++i){
        HU u; u.u = rpu[i];
        float r0 = (float)u.h.x, r1 = (float)u.h.y;
        unsigned lo = f2bf(beta*r0 + (1.f-beta)*o[2*i]);
        unsigned hi = f2bf(beta*r1 + (1.f-beta)*o[2*i+1]);
        hp32[cbase/2 + i] = lo | (hi << 16);
      }
    }
  }
}

// ---------------- per-graph gate stats + in-place att normalization ----------------
// R10: k_pool was 59us at 4.7% VALU / 12% occupancy -- each of 8 part-blocks
// redundantly rescanned its whole segment for max+denom (18 barriers), and all
// 320 threads recomputed the same expf per node. Split: this kernel (32 blocks)
// computes stats once and overwrites gate[n] with att[n]=exp(gate-gm)/denom
// (segments are block-exclusive -> in-place safe).
__global__ __launch_bounds__(256) void k_gatt(float* __restrict__ gate, const int* __restrict__ batch, int N){
  __shared__ float sm[256];
  int g = blockIdx.x, j = threadIdx.x;
  int lo = lbound(batch, N, g), hi = lbound(batch, N, g+1);
  if (hi <= lo) return;
  float m = -INFINITY;
  for (int i = lo + j; i < hi; i += 256) m = fmaxf(m, gate[i]);
  sm[j] = m; __syncthreads();
  #pragma unroll
  for (int off = 128; off; off >>= 1){
    if (j < off) sm[j] = fmaxf(sm[j], sm[j+off]);
    __syncthreads();
  }
  float gm = sm[0]; __syncthreads();
  float s = 0.f;
  for (int i = lo + j; i < hi; i += 256) s += __expf(gate[i] - gm);
  sm[j] = s; __syncthreads();
  #pragma unroll
  for (int off = 128; off; off >>= 1){
    if (j < off) sm[j] += sm[j+off];
    __syncthreads();
  }
  float dg = sm[0];
  float invd = (dg > 0.f) ? 1.f/dg : 0.f;
  for (int i = lo + j; i < hi; i += 256) gate[i] = __expf(gate[i] - gm) * invd;
}

// ---------------- attention pooling: pure weighted accumulation ----------------
// v2: gate already holds att[n]; grid (NGRAPH, 32 parts) = 1024 blocks; no
// barriers, no stats, no exp -- broadcast att load + coalesced hb row + fma.
__global__ __launch_bounds__(320) void k_pool(const unsigned short* __restrict__ hb, const float* __restrict__ gate,
                                              const int* __restrict__ batch, int N,
                                              float* __restrict__ pooled){
  int g = blockIdx.x, part = blockIdx.y, j = threadIdx.x;
  int lo = lbound(batch, N, g), hi = lbound(batch, N, g+1);
  int len = hi - lo;
  if (len <= 0) return;
  int chunk = (len + (int)gridDim.y - 1) / (int)gridDim.y;
  int a = lo + part*chunk;
  int bnd = a + chunk; if (bnd > hi) bnd = hi;
  if (a >= bnd) return;
  float acc = 0.f;
  #pragma unroll 2
  for (int n = a; n < bnd; ++n){
    acc += gate[n] * bf2f(hb[(size_t)n*JKW + j]);
  }
  atomicAdd(&pooled[g*JKW + j], acc);
}

__global__ __launch_bounds__(320) void k_head(const float* __restrict__ pooled, const float* __restrict__ Wh1,
                                              const float* __restrict__ bh1, const float* __restrict__ Wh2,
                                              const float* __restrict__ bh2, float* __restrict__ out){
  __shared__ float p[320];
  __shared__ float t[320];
  int g = blockIdx.x, tid = threadIdx.x;
  p[tid] = pooled[g*JKW + tid]; __syncthreads();
  float a = bh1[tid];
  for (int i = 0; i < 320; ++i) a += p[i]*Wh1[i*JKW + tid];
  t[tid] = fmaxf(a, 0.f); __syncthreads();
  if (tid < 6){
    float o = bh2[tid];
    for (int j = 0; j < 320; ++j) o += t[j]*Wh2[j*6 + tid];
    out[g*6 + tid] = o;
  }
}

extern "C" void kernel_launch(void* const* d_in, const int* in_sizes, int n_in,
                              void* d_out, int out_size, void* d_ws, size_t ws_size,
                              hipStream_t stream){
  (void)n_in; (void)out_size; (void)ws_size;
  const float* x        = (const float*)d_in[0];
  const int*   eidx     = (const int*)d_in[1];
  const float* edge_attr= (const float*)d_in[2];
  const int*   batch    = (const int*)d_in[3];
  const float* W_in     = (const float*)d_in[4];
  const float* b_in     = (const float*)d_in[5];
  const float* Wq       = (const float*)d_in[6];
  const float* bq       = (const float*)d_in[7];
  const float* Wk       = (const float*)d_in[8];
  const float* bk       = (const float*)d_in[9];
  const float* Wv       = (const float*)d_in[10];
  const float* bv       = (const float*)d_in[11];
  const float* We       = (const float*)d_in[12];
  const float* be       = (const float*)d_in[13];
  const float* Wsk      = (const float*)d_in[14];
  const float* bsk      = (const float*)d_in[15];
  const float* Wb       = (const float*)d_in[16];
  const float* Wg1      = (const float*)d_in[17];
  const float* bg1      = (const float*)d_in[18];
  const float* Wg2      = (const float*)d_in[19];
  const float* Wh1      = (const float*)d_in[21];
  const float* bh1      = (const float*)d_in[22];
  const float* Wh2      = (const float*)d_in[23];
  const float* bh2      = (const float*)d_in[24];

  const int N = in_sizes[0] / 5;
  const int E = in_sizes[1] / 2;
  float* out = (float*)d_out;

  char* w = (char*)d_ws;
  auto alloc = [&](size_t bytes)->char*{ char* p = w; w += (bytes + 255) & ~(size_t)255; return p; };
  unsigned short* hb = (unsigned short*)alloc((size_t)N*JKW*2);
  _Float16* qh  = (_Float16*)alloc((size_t)N*160*2);
  unsigned char* kv8 = (unsigned char*)alloc((size_t)N*320);
  _Float16* rskip = (_Float16*)alloc((size_t)N*160*2);
  float* qwb    = (float*)alloc((size_t)N*20*4);
  unsigned short* Bth  = (unsigned short*)alloc((size_t)2*640*160*2);
  unsigned short* Btgh = (unsigned short*)alloc((size_t)160*320*2);
  float* bpack  = (float*)alloc((size_t)2*640*4);
  int*   cnt    = (int*)alloc((size_t)N*4);
  uint4* edges  = (uint4*)alloc((size_t)N*BCAP*16);
  float* gate   = (float*)alloc((size_t)N*4);
  float* pooled = (float*)alloc(NGRAPH*JKW*4);

  const int* srcI = eidx;
  const int* dstI = eidx + E;

  const int NL = (N*20 + 255)/256;
  const int NZ = (N + 255)/256;
  k_pre<<<NL + 1005 + NZ, 256, 0, stream>>>(x, W_in, b_in, hb,
                                            Wq, Wk, Wv, Wsk, bq, bk, bv, bsk, Wg1,
                                            Bth, bpack, Btgh, cnt, gate, pooled, N);

  const int eb = (E + 255)/256;
  k_fill<<<eb, 256, 0, stream>>>(dstI, srcI, edge_attr, E, cnt, edges);

  const int MB128 = (N + 127)/128;
  for (int l = 0; l < 2; ++l){
    dim3 g1(5, MB128);
    k_mgemm<8,1><<<g1, 256, 0, stream>>>(hb, JKW, Bth + (size_t)l*102400, bpack + l*640,
                                         qh, kv8, rskip, nullptr, nullptr, N, HIDW);
    k_qprep<<<(N*4 + 255)/256, 256, 0, stream>>>(qh, We + l*640, be + l*160, qwb, N);
    k_attn<<<(N + 15)/16, 256, 0, stream>>>(qh, kv8, rskip, qwb, edges, cnt,
                                            We + l*640, be + l*160, Wb + l*480, hb, l*HIDW, N);
  }

  k_mgemm<10,2><<<dim3(1, MB128), 256, 0, stream>>>(hb, JKW, Btgh, bg1, nullptr, nullptr, nullptr,
                                                    Wg2, gate, N, JKW);

  k_gatt<<<NGRAPH, 256, 0, stream>>>(gate, batch, N);
  dim3 g3(NGRAPH, 32);
  k_pool<<<g3, 320, 0, stream>>>(hb, gate, batch, N, pooled);
  k_head<<<NGRAPH, 320, 0, stream>>>(pooled, Wh1, bh1, Wh2, bh2, out);
}

// Round 12
// 421.629 us; speedup vs baseline: 1.2235x; 1.0175x over previous
//
#include <hip/hip_runtime.h>
#include <math.h>
#include <stddef.h>

#define NHEAD 4
#define DHEAD 40
#define HIDW 160
#define JKW 320
#define NGRAPH 32
#define BCAP 64   // edge bucket capacity per node (deg ~ Poisson(10); P(>63) ~ 1e-31)

typedef __attribute__((ext_vector_type(8))) short short8;
typedef __attribute__((ext_vector_type(4))) float f32x4;
typedef __attribute__((ext_vector_type(2))) float f32x2;
typedef __fp16 h2 __attribute__((ext_vector_type(2)));
typedef int i32x4 __attribute__((ext_vector_type(4)));
typedef i32x4 i32x4_a4 __attribute__((aligned(4)));

__device__ inline unsigned short f2bf(float x){
  unsigned u = __float_as_uint(x);
  u += 0x7fff + ((u >> 16) & 1);
  return (unsigned short)(u >> 16);
}
__device__ inline float bf2f(unsigned short h){
  return __uint_as_float(((unsigned)h) << 16);
}
__device__ inline float fdot2(h2 a, h2 b, float c){
  return __builtin_amdgcn_fdot2(a, b, c, false);
}
__device__ inline h2 pk(float a, float b){
  return __builtin_amdgcn_cvt_pkrtz(a, b);
}
union HU { h2 h; int i; unsigned u; float f; };
__device__ inline h2 shfl_h2(h2 v, int xm){
  HU u; u.h = v; u.i = __shfl_xor(u.i, xm); return u.h;
}
__device__ inline h2 asH2(unsigned i){ HU u; u.u = i; return u.h; }

#if __has_builtin(__builtin_amdgcn_cvt_pk_f16_fp8)
__device__ inline h2 cvt8(int s){ return __builtin_amdgcn_cvt_pk_f16_fp8((short)s); }
#else
__device__ inline h2 cvt8(int s){
  f32x2 t = __builtin_amdgcn_cvt_pk_f32_fp8(s, false);
  return pk(t.x, t.y);
}
#endif

__device__ inline int lbound(const int* __restrict__ b, int N, int g){
  int lo = 0, hi = N;
  while (lo < hi){ int mid = (lo + hi) >> 1; if (b[mid] < g) lo = mid + 1; else hi = mid; }
  return lo;
}

// ---------------- fused pre-pass: zero buffers + lin_in + weight pack ----------------
// v3: lin_in vectorized (8 out/thread); Bth pack reads coalesced.
__global__ __launch_bounds__(256) void k_pre(const float* __restrict__ x, const float* __restrict__ W_in,
                                             const float* __restrict__ b_in, unsigned short* __restrict__ hb,
                                             const float* __restrict__ Wq, const float* __restrict__ Wk,
                                             const float* __restrict__ Wv, const float* __restrict__ Ws,
                                             const float* __restrict__ bq, const float* __restrict__ bk,
                                             const float* __restrict__ bv, const float* __restrict__ bs,
                                             const float* __restrict__ Wg1,
                                             unsigned short* __restrict__ Bth, float* __restrict__ bp,
                                             unsigned short* __restrict__ Btgh,
                                             int* __restrict__ cnt, float* __restrict__ gate,
                                             float* __restrict__ pooled, int N){
  int NL = (N*20 + 255)/256;
  int bid = blockIdx.x, tid = threadIdx.x;
  if (bid < NL){
    int idx = bid*256 + tid;
    if (idx >= N*20) return;
    int n = idx / 20, j8 = (idx % 20)*8;
    const float* xr = x + n*5;
    float x0 = xr[0], x1 = xr[1], x2 = xr[2], x3 = xr[3], x4 = xr[4];
    float v[8];
    #pragma unroll
    for (int u = 0; u < 8; ++u) v[u] = b_in[j8+u];
    #pragma unroll
    for (int c = 0; c < 5; ++c){
      float xc = (c==0)?x0:(c==1)?x1:(c==2)?x2:(c==3)?x3:x4;
      const float4 wa = *(const float4*)(W_in + c*HIDW + j8);
      const float4 wb = *(const float4*)(W_in + c*HIDW + j8 + 4);
      v[0] += xc*wa.x; v[1] += xc*wa.y; v[2] += xc*wa.z; v[3] += xc*wa.w;
      v[4] += xc*wb.x; v[5] += xc*wb.y; v[6] += xc*wb.z; v[7] += xc*wb.w;
    }
    short8 o;
    #pragma unroll
    for (int u = 0; u < 8; ++u) o[u] = (short)f2bf(v[u]);
    *(short8*)(hb + (size_t)n*JKW + j8) = o;
  } else if (bid < NL + 1005){
    int idx = (bid - NL)*256 + tid;
    if (idx < 204800){
      int l = idx / 102400, r = idx % 102400;
      int i = r / 640, j = r % 640;            // consecutive tid -> consecutive jj (coalesced W reads)
      int sel = j / HIDW, jj = j % HIDW;
      const float* W = (sel==0) ? Wq : (sel==1) ? Wk : (sel==2) ? Wv : Ws;
      Bth[(size_t)l*102400 + (size_t)j*160 + i] = f2bf(W[(size_t)l*25600 + i*HIDW + jj]);
    } else if (idx < 256000){
      int r = idx - 204800;
      int j = r / 320, i = r % 320;
      Btgh[(size_t)j*320 + i] = f2bf(Wg1[(size_t)i*160 + j]);
    } else if (idx < 257280){
      int r = idx - 256000;
      int l = r / 640, j = r % 640;
      int sel = j / HIDW, jj = j % HIDW;
      const float* bb = (sel==0) ? bq : (sel==1) ? bk : (sel==2) ? bv : bs;
      bp[l*640 + j] = bb[l*160 + jj];
    }
  } else {
    int idx = (bid - NL - 1005)*256 + tid;
    if (idx < N){ cnt[idx] = 0; gate[idx] = 0.f; }
    if (idx < NGRAPH*JKW) pooled[idx] = 0.f;
  }
}

// ---------------- bucketed edge fill ----------------
// v2: single 16B record {src, ea01, ea23, pad} -- one scattered store per edge.
__global__ __launch_bounds__(256) void k_fill(const int* __restrict__ dst, const int* __restrict__ src,
                                              const float* __restrict__ edge_attr, int E,
                                              int* __restrict__ cnt, uint4* __restrict__ edges){
  int e = blockIdx.x*256 + threadIdx.x;
  if (e < E){
    int d = dst[e];
    int p = atomicAdd(&cnt[d], 1);
    if (p < BCAP){
      float4 ea = *(const float4*)(edge_attr + (size_t)e*4);
      HU a, b; a.h = pk(ea.x, ea.y); b.h = pk(ea.z, ea.w);
      edges[(size_t)d*BCAP + p] = make_uint4((unsigned)src[e], a.u, b.u, 0u);
    }
  }
}

// ---------------- bf16 MFMA GEMM v9: XCD-pinned row-blocks ----------------
// MODE 1 (QKV, K=160): whole B panel staged once, barrier-free 5-step k-loop.
// MODE 2 (gate, K=320): 32-k double-buffered path.
#define BSTR 40
#define BSTR1 164
template<int NSUB, int MODE>
__global__ __launch_bounds__(256) void k_mgemm(const unsigned short* __restrict__ A, int lda,
                                               const unsigned short* __restrict__ Bh,
                                               const float* __restrict__ bias,
                                               _Float16* __restrict__ qh,
                                               unsigned char* __restrict__ kv8,
                                               _Float16* __restrict__ rskip,
                                               const float* __restrict__ Wg2,
                                               float* __restrict__ gate,
                                               int M, int K){
  __shared__ short sBh[(MODE==1) ? (16*NSUB*BSTR1) : (2*16*NSUB*BSTR)];
  int tid = threadIdx.x;
  int wv = tid >> 6, lane = tid & 63;
  int quad = lane >> 4, l16 = lane & 15;

  int P = gridDim.x, MBy = gridDim.y;
  int bid = blockIdx.y * P + blockIdx.x;       // dispatch-order linear id
  int fullRows = (MBy >> 3) << 3;
  int rowB, panel;
  if (bid < fullRows * P){
    int group = bid / (8*P), rem = bid % (8*P);
    rowB  = group*8 + (rem & 7);
    panel = rem >> 3;
  } else {
    int rem = bid - fullRows*P;
    int R = MBy - fullRows;                    // 1..7 tail rows
    panel = rem / R;
    rowB  = fullRows + rem % R;
  }
  int m0 = rowB*128 + wv*32;
  int col0 = panel * (16*NSUB);

  int ar0 = m0 + l16;      if (ar0 >= M) ar0 = M - 1;
  int ar1 = m0 + 16 + l16; if (ar1 >= M) ar1 = M - 1;
  const unsigned short* Ap0 = A + (size_t)ar0*lda + quad*8;
  const unsigned short* Ap1 = A + (size_t)ar1*lda + quad*8;

  f32x4 acc[2][NSUB];
  #pragma unroll
  for (int g = 0; g < 2; ++g)
    #pragma unroll
    for (int s = 0; s < NSUB; ++s) acc[g][s] = (f32x4){0.f,0.f,0.f,0.f};

  if constexpr (MODE == 1){
    for (int u = tid; u < 16*NSUB*20; u += 256){
      int col = u / 20, q = u % 20;
      *(short8*)(&sBh[col*BSTR1 + q*8]) =
        *(const short8*)(Bh + (size_t)(col0 + col)*K + q*8);
    }
    __syncthreads();
    #pragma unroll
    for (int kk = 0; kk < 5; ++kk){
      int k0 = kk << 5;
      short8 ah0 = *(const short8*)(Ap0 + k0);
      short8 ah1 = *(const short8*)(Ap1 + k0);
      #pragma unroll
      for (int s = 0; s < NSUB; ++s){
        short8 bh = *(const short8*)(&sBh[(s*16 + l16)*BSTR1 + k0 + quad*8]);
        acc[0][s] = __builtin_amdgcn_mfma_f32_16x16x32_bf16(ah0, bh, acc[0][s], 0, 0, 0);
        acc[1][s] = __builtin_amdgcn_mfma_f32_16x16x32_bf16(ah1, bh, acc[1][s], 0, 0, 0);
      }
    }
  } else {
    const int CH = K >> 5;
    for (int u = tid; u < 16*NSUB*4; u += 256){
      int col = u >> 2, q4 = u & 3;
      *(short8*)(&sBh[col*BSTR + q4*8]) =
        *(const short8*)(Bh + (size_t)(col0 + col)*K + q4*8);
    }
    __syncthreads();
    int buf = 0;
    for (int kk = 0; kk < CH; ++kk){
      int k0 = kk << 5;
      if (kk + 1 < CH){
        int kn = k0 + 32;
        for (int u = tid; u < 16*NSUB*4; u += 256){
          int col = u >> 2, q4 = u & 3;
          *(short8*)(&sBh[(buf^1)*16*NSUB*BSTR + col*BSTR + q4*8]) =
            *(const short8*)(Bh + (size_t)(col0 + col)*K + kn + q4*8);
        }
      }
      short8 ah0 = *(const short8*)(Ap0 + k0);
      short8 ah1 = *(const short8*)(Ap1 + k0);
      #pragma unroll
      for (int s = 0; s < NSUB; ++s){
        short8 bh = *(const short8*)(&sBh[buf*16*NSUB*BSTR + (s*16 + l16)*BSTR + quad*8]);
        acc[0][s] = __builtin_amdgcn_mfma_f32_16x16x32_bf16(ah0, bh, acc[0][s], 0, 0, 0);
        acc[1][s] = __builtin_amdgcn_mfma_f32_16x16x32_bf16(ah1, bh, acc[1][s], 0, 0, 0);
      }
      __syncthreads();
      buf ^= 1;
    }
  }

  const float qscale = 0.15811388300841898f; // 1/sqrt(40)
  if (MODE == 1){
    #pragma unroll
    for (int g = 0; g < 2; ++g){
      #pragma unroll
      for (int s = 0; s < NSUB; ++s){
        int col = col0 + s*16 + l16;
        float bv = bias[col];
        int sel = col / 160, cc = col % 160;
        #pragma unroll
        for (int r = 0; r < 4; ++r){
          int row = m0 + g*16 + quad*4 + r;
          if (row >= M) continue;
          float v = acc[g][s][r] + bv;
          if (sel == 0)      qh[(size_t)row*160 + cc] = (_Float16)(v * qscale);
          else if (sel == 3) rskip[(size_t)row*160 + cc] = (_Float16)v;
          else {
            int slot = (cc/40)*4 + (cc%40)/10, j = cc%10;
            int e8 = __builtin_amdgcn_cvt_pk_fp8_f32(v, v, 0, false);
            kv8[(size_t)row*320 + slot*20 + (sel==2?10:0) + j] = (unsigned char)(e8 & 0xff);
          }
        }
      }
    }
  } else {
    float pg[2][4];
    #pragma unroll
    for (int g = 0; g < 2; ++g)
      #pragma unroll
      for (int r = 0; r < 4; ++r) pg[g][r] = 0.f;
    #pragma unroll
    for (int s = 0; s < NSUB; ++s){
      int col = col0 + s*16 + l16;
      float bv = bias[col], wg = Wg2[col];
      #pragma unroll
      for (int g = 0; g < 2; ++g)
        #pragma unroll
        for (int r = 0; r < 4; ++r)
          pg[g][r] += fmaxf(acc[g][s][r] + bv, 0.f) * wg;
    }
    #pragma unroll
    for (int g = 0; g < 2; ++g)
      #pragma unroll
      for (int r = 0; r < 4; ++r){
        float v = pg[g][r];
        v += __shfl_xor(v, 1); v += __shfl_xor(v, 2);
        v += __shfl_xor(v, 4); v += __shfl_xor(v, 8);
        int row = m0 + g*16 + quad*4 + r;
        if (l16 == 0 && row < M) atomicAdd(&gate[row], v);
      }
  }
}

// ---------------- per-node q-projection precompute ----------------
__global__ __launch_bounds__(256) void k_qprep(const _Float16* __restrict__ qh,
                                               const float* __restrict__ We, const float* __restrict__ be,
                                               float* __restrict__ qwb, int N){
  int idx = blockIdx.x*256 + threadIdx.x;
  if (idx >= N*4) return;
  int n = idx >> 2, h = idx & 3;
  const unsigned* qp = (const unsigned*)(qh + (size_t)n*160 + h*40);
  float w0=0.f,w1=0.f,w2=0.f,w3=0.f,b=0.f;
  #pragma unroll
  for (int i = 0; i < 20; ++i){
    HU u; u.u = qp[i];
    float qa = (float)u.h.x, qb = (float)u.h.y;
    int c = h*40 + 2*i;
    w0 += qa*We[c]       + qb*We[c+1];
    w1 += qa*We[160+c]   + qb*We[161+c];
    w2 += qa*We[320+c]   + qb*We[321+c];
    w3 += qa*We[480+c]   + qb*We[481+c];
    b  += qa*be[c]       + qb*be[c+1];
  }
  float* o = qwb + (size_t)idx*5;
  o[0]=w0; o[1]=w1; o[2]=w2; o[3]=w3; o[4]=b;
}

// ---------------- fused edge attention + beta gate (fp8 kv, no-max softmax) ----------------
// v9: 2-WIDE edge pipeline. R11 counters (VALU 45%, occ 56%): stall = the
// serial per-edge chain (5 fdot2 -> 2 LDS-pipe shfls -> exp -> fmas), not
// memory. Two independent score chains per iteration hide each other's
// shfl/exp latency. Records prefetched to e+5, kv to e+3. Accum order kept
// sequential (e then e+1).
__global__ __launch_bounds__(256) void k_attn(const _Float16* __restrict__ qh,
                                              const unsigned char* __restrict__ kv8,
                                              const _Float16* __restrict__ rskip,
                                              const float* __restrict__ qwb,
                                              const uint4* __restrict__ edges,
                                              const int* __restrict__ cnt,
                                              const float* __restrict__ We, const float* __restrict__ be,
                                              const float* __restrict__ Wb,
                                              unsigned short* __restrict__ hb,
                                              int loff, int N){
  int tid = threadIdx.x;
  int grp = tid >> 4;                 // 16 groups per block
  int n = blockIdx.x*16 + grp;
  bool valid = (n < N);
  int nn = valid ? n : (N-1);
  int w = tid & 15;
  int hh = w & 3, t = w >> 2;
  int cbase = DHEAD*hh + 10*t;
  int slot = hh*4 + t;

  h2 qh2[5];
  {
    const unsigned* qp = (const unsigned*)(qh + (size_t)nn*160 + cbase);
    #pragma unroll
    for (int i = 0; i < 5; ++i) qh2[i] = asH2(qp[i]);
  }
  const float* qwp = qwb + ((size_t)nn*4 + hh)*5;
  float qw0 = qwp[0], qw1 = qwp[1], qw2 = qwp[2], qw3 = qwp[3], qb = qwp[4];
  h2 qw01 = pk(qw0, qw1), qw23 = pk(qw2, qw3);

  float ssum = 0.f;
  h2 zh = pk(0.f, 0.f);
  h2 acch[5], sah[2];
  #pragma unroll
  for (int i = 0; i < 5; ++i) acch[i] = zh;
  sah[0] = zh; sah[1] = zh;

  int deg = 0;
  if (valid){ deg = cnt[nn]; if (deg > BCAP) deg = BCAP; }
  int st = nn*BCAP;

  // pipeline: records r0..r3 for edges e..e+3; kv for e, e+1 in registers
  uint4 r0 = make_uint4(0,0,0,0), r1 = make_uint4(0,0,0,0);
  uint4 r2 = make_uint4(0,0,0,0), r3 = make_uint4(0,0,0,0);
  i32x4 k0v = {0,0,0,0}, k1v = {0,0,0,0}; int k0e = 0, k1e = 0;
  if (deg > 0) r0 = edges[st];
  if (deg > 1) r1 = edges[st+1];
  if (deg > 2) r2 = edges[st+2];
  if (deg > 3) r3 = edges[st+3];
  if (deg > 0){
    const unsigned char* kp = kv8 + (size_t)r0.x*320 + slot*20;
    k0v = *(const i32x4_a4*)kp; k0e = *(const int*)(kp+16);
  }
  if (deg > 1){
    const unsigned char* kp = kv8 + (size_t)r1.x*320 + slot*20;
    k1v = *(const i32x4_a4*)kp; k1e = *(const int*)(kp+16);
  }

  for (int e = 0; e < deg; e += 2){
    // prefetch records e+4, e+5
    uint4 n0 = make_uint4(0,0,0,0), n1 = make_uint4(0,0,0,0);
    if (e + 4 < deg) n0 = edges[st + e + 4];
    if (e + 5 < deg) n1 = edges[st + e + 5];
    // prefetch kv e+2, e+3 (records arrived last iteration)
    i32x4 k2v = {0,0,0,0}, k3v = {0,0,0,0}; int k2e = 0, k3e = 0;
    if (e + 2 < deg){
      const unsigned char* kp = kv8 + (size_t)r2.x*320 + slot*20;
      k2v = *(const i32x4_a4*)kp; k2e = *(const int*)(kp+16);
    }
    if (e + 3 < deg){
      const unsigned char* kp = kv8 + (size_t)r3.x*320 + slot*20;
      k3v = *(const i32x4_a4*)kp; k3e = *(const int*)(kp+16);
    }
    // two independent score chains (edge e, edge e+1)
    bool v1 = (e + 1 < deg);
    h2 ea00 = asH2(r0.y), ea01 = asH2(r0.z);
    h2 ea10 = asH2(r1.y), ea11 = asH2(r1.z);
    float p0 = 0.f, p1 = 0.f;
    p0 = fdot2(qh2[0], cvt8(k0v.x), p0);       p1 = fdot2(qh2[0], cvt8(k1v.x), p1);
    p0 = fdot2(qh2[1], cvt8(k0v.x >> 16), p0); p1 = fdot2(qh2[1], cvt8(k1v.x >> 16), p1);
    p0 = fdot2(qh2[2], cvt8(k0v.y), p0);       p1 = fdot2(qh2[2], cvt8(k1v.y), p1);
    p0 = fdot2(qh2[3], cvt8(k0v.y >> 16), p0); p1 = fdot2(qh2[3], cvt8(k1v.y >> 16), p1);
    p0 = fdot2(qh2[4], cvt8(k0v.z), p0);       p1 = fdot2(qh2[4], cvt8(k1v.z), p1);
    p0 += __shfl_xor(p0, 4);                   p1 += __shfl_xor(p1, 4);
    p0 += __shfl_xor(p0, 8);                   p1 += __shfl_xor(p1, 8);
    p0 += qb;                                  p1 += qb;
    p0 = fdot2(ea00, qw01, p0);                p1 = fdot2(ea10, qw01, p1);
    p0 = fdot2(ea01, qw23, p0);                p1 = fdot2(ea11, qw23, p1);

    float ex0 = __expf(p0);
    float ex1 = v1 ? __expf(p1) : 0.f;
    ssum += ex0;
    ssum += ex1;
    h2 eh0 = pk(ex0, ex0), eh1 = pk(ex1, ex1);
    acch[0] += cvt8(k0v.z >> 16)*eh0;  acch[0] += cvt8(k1v.z >> 16)*eh1;
    acch[1] += cvt8(k0v.w)*eh0;        acch[1] += cvt8(k1v.w)*eh1;
    acch[2] += cvt8(k0v.w >> 16)*eh0;  acch[2] += cvt8(k1v.w >> 16)*eh1;
    acch[3] += cvt8(k0e)*eh0;          acch[3] += cvt8(k1e)*eh1;
    acch[4] += cvt8(k0e >> 16)*eh0;    acch[4] += cvt8(k1e >> 16)*eh1;
    sah[0] += ea00*eh0;                sah[0] += ea10*eh1;
    sah[1] += ea01*eh0;                sah[1] += ea11*eh1;

    r0 = r2; r1 = r3; r2 = n0; r3 = n1;
    k0v = k2v; k0e = k2e; k1v = k3v; k1e = k3e;
  }

  // epilogue: each lane owns cols cbase..cbase+9
  {
    float inv = (ssum > 0.f) ? 1.f/ssum : 0.f;
    float sw0 = (float)sah[0].x*inv, sw1 = (float)sah[0].y*inv;
    float sw2 = (float)sah[1].x*inv, sw3 = (float)sah[1].y*inv;
    float bterm = (ssum > 0.f) ? 1.f : 0.f;

    const unsigned* rpu = (const unsigned*)(rskip + (size_t)nn*160 + cbase);
    float o[10];
    float part = 0.f;
    #pragma unroll
    for (int i = 0; i < 5; ++i){
      int c = cbase + 2*i;
      float o0 = (float)acch[i].x*inv + sw0*We[c]   + sw1*We[160+c] + sw2*We[320+c] + sw3*We[480+c] + bterm*be[c];
      float o1 = (float)acch[i].y*inv + sw0*We[c+1] + sw1*We[161+c] + sw2*We[321+c] + sw3*We[481+c] + bterm*be[c+1];
      HU u; u.u = rpu[i];
      float r0f = (float)u.h.x, r1f = (float)u.h.y;
      part += o0*Wb[c]   + r0f*Wb[160+c] + (o0-r0f)*Wb[320+c];
      part += o1*Wb[c+1] + r1f*Wb[161+c] + (o1-r1f)*Wb[321+c];
      o[2*i] = o0; o[2*i+1] = o1;
    }
    part += __shfl_xor(part, 1); part += __shfl_xor(part, 2);
    part += __shfl_xor(part, 4); part += __shfl_xor(part, 8);
    float beta = 1.f/(1.f + __expf(-part));
    if (valid){
      unsigned* hp32 = (unsigned*)(hb + (size_t)nn*JKW + loff);
      #pragma unroll
      for (int i = 0; i < 5; ++i){
        HU u; u.u = rpu[i];
        float r0f = (float)u.h.x, r1f = (float)u.h.y;
        unsigned lo = f2bf(beta*r0f + (1.f-beta)*o[2*i]);
        unsigned hi = f2bf(beta*r1f + (1.f-beta)*o[2*i+1]);
        hp32[cbase/2 + i] = lo | (hi << 16);
      }
    }
  }
}

// ---------------- per-graph gate stats + in-place att normalization ----------------
__global__ __launch_bounds__(256) void k_gatt(float* __restrict__ gate, const int* __restrict__ batch, int N){
  __shared__ float sm[256];
  int g = blockIdx.x, j = threadIdx.x;
  int lo = lbound(batch, N, g), hi = lbound(batch, N, g+1);
  if (hi <= lo) return;
  float m = -INFINITY;
  for (int i = lo + j; i < hi; i += 256) m = fmaxf(m, gate[i]);
  sm[j] = m; __syncthreads();
  #pragma unroll
  for (int off = 128; off; off >>= 1){
    if (j < off) sm[j] = fmaxf(sm[j], sm[j+off]);
    __syncthreads();
  }
  float gm = sm[0]; __syncthreads();
  float s = 0.f;
  for (int i = lo + j; i < hi; i += 256) s += __expf(gate[i] - gm);
  sm[j] = s; __syncthreads();
  #pragma unroll
  for (int off = 128; off; off >>= 1){
    if (j < off) sm[j] += sm[j+off];
    __syncthreads();
  }
  float dg = sm[0];
  float invd = (dg > 0.f) ? 1.f/dg : 0.f;
  for (int i = lo + j; i < hi; i += 256) gate[i] = __expf(gate[i] - gm) * invd;
}

// ---------------- attention pooling: pure weighted accumulation ----------------
__global__ __launch_bounds__(320) void k_pool(const unsigned short* __restrict__ hb, const float* __restrict__ gate,
                                              const int* __restrict__ batch, int N,
                                              float* __restrict__ pooled){
  int g = blockIdx.x, part = blockIdx.y, j = threadIdx.x;
  int lo = lbound(batch, N, g), hi = lbound(batch, N, g+1);
  int len = hi - lo;
  if (len <= 0) return;
  int chunk = (len + (int)gridDim.y - 1) / (int)gridDim.y;
  int a = lo + part*chunk;
  int bnd = a + chunk; if (bnd > hi) bnd = hi;
  if (a >= bnd) return;
  float acc = 0.f;
  #pragma unroll 2
  for (int n = a; n < bnd; ++n){
    acc += gate[n] * bf2f(hb[(size_t)n*JKW + j]);
  }
  atomicAdd(&pooled[g*JKW + j], acc);
}

__global__ __launch_bounds__(320) void k_head(const float* __restrict__ pooled, const float* __restrict__ Wh1,
                                              const float* __restrict__ bh1, const float* __restrict__ Wh2,
                                              const float* __restrict__ bh2, float* __restrict__ out){
  __shared__ float p[320];
  __shared__ float t[320];
  int g = blockIdx.x, tid = threadIdx.x;
  p[tid] = pooled[g*JKW + tid]; __syncthreads();
  float a = bh1[tid];
  for (int i = 0; i < 320; ++i) a += p[i]*Wh1[i*JKW + tid];
  t[tid] = fmaxf(a, 0.f); __syncthreads();
  if (tid < 6){
    float o = bh2[tid];
    for (int j = 0; j < 320; ++j) o += t[j]*Wh2[j*6 + tid];
    out[g*6 + tid] = o;
  }
}

extern "C" void kernel_launch(void* const* d_in, const int* in_sizes, int n_in,
                              void* d_out, int out_size, void* d_ws, size_t ws_size,
                              hipStream_t stream){
  (void)n_in; (void)out_size; (void)ws_size;
  const float* x        = (const float*)d_in[0];
  const int*   eidx     = (const int*)d_in[1];
  const float* edge_attr= (const float*)d_in[2];
  const int*   batch    = (const int*)d_in[3];
  const float* W_in     = (const float*)d_in[4];
  const float* b_in     = (const float*)d_in[5];
  const float* Wq       = (const float*)d_in[6];
  const float* bq       = (const float*)d_in[7];
  const float* Wk       = (const float*)d_in[8];
  const float* bk       = (const float*)d_in[9];
  const float* Wv       = (const float*)d_in[10];
  const float* bv       = (const float*)d_in[11];
  const float* We       = (const float*)d_in[12];
  const float* be       = (const float*)d_in[13];
  const float* Wsk      = (const float*)d_in[14];
  const float* bsk      = (const float*)d_in[15];
  const float* Wb       = (const float*)d_in[16];
  const float* Wg1      = (const float*)d_in[17];
  const float* bg1      = (const float*)d_in[18];
  const float* Wg2      = (const float*)d_in[19];
  const float* Wh1      = (const float*)d_in[21];
  const float* bh1      = (const float*)d_in[22];
  const float* Wh2      = (const float*)d_in[23];
  const float* bh2      = (const float*)d_in[24];

  const int N = in_sizes[0] / 5;
  const int E = in_sizes[1] / 2;
  float* out = (float*)d_out;

  char* w = (char*)d_ws;
  auto alloc = [&](size_t bytes)->char*{ char* p = w; w += (bytes + 255) & ~(size_t)255; return p; };
  unsigned short* hb = (unsigned short*)alloc((size_t)N*JKW*2);
  _Float16* qh  = (_Float16*)alloc((size_t)N*160*2);
  unsigned char* kv8 = (unsigned char*)alloc((size_t)N*320);
  _Float16* rskip = (_Float16*)alloc((size_t)N*160*2);
  float* qwb    = (float*)alloc((size_t)N*20*4);
  unsigned short* Bth  = (unsigned short*)alloc((size_t)2*640*160*2);
  unsigned short* Btgh = (unsigned short*)alloc((size_t)160*320*2);
  float* bpack  = (float*)alloc((size_t)2*640*4);
  int*   cnt    = (int*)alloc((size_t)N*4);
  uint4* edges  = (uint4*)alloc((size_t)N*BCAP*16);
  float* gate   = (float*)alloc((size_t)N*4);
  float* pooled = (float*)alloc(NGRAPH*JKW*4);

  const int* srcI = eidx;
  const int* dstI = eidx + E;

  const int NL = (N*20 + 255)/256;
  const int NZ = (N + 255)/256;
  k_pre<<<NL + 1005 + NZ, 256, 0, stream>>>(x, W_in, b_in, hb,
                                            Wq, Wk, Wv, Wsk, bq, bk, bv, bsk, Wg1,
                                            Bth, bpack, Btgh, cnt, gate, pooled, N);

  const int eb = (E + 255)/256;
  k_fill<<<eb, 256, 0, stream>>>(dstI, srcI, edge_attr, E, cnt, edges);

  const int MB128 = (N + 127)/128;
  for (int l = 0; l < 2; ++l){
    dim3 g1(5, MB128);
    k_mgemm<8,1><<<g1, 256, 0, stream>>>(hb, JKW, Bth + (size_t)l*102400, bpack + l*640,
                                         qh, kv8, rskip, nullptr, nullptr, N, HIDW);
    k_qprep<<<(N*4 + 255)/256, 256, 0, stream>>>(qh, We + l*640, be + l*160, qwb, N);
    k_attn<<<(N + 15)/16, 256, 0, stream>>>(qh, kv8, rskip, qwb, edges, cnt,
                                            We + l*640, be + l*160, Wb + l*480, hb, l*HIDW, N);
  }

  k_mgemm<10,2><<<dim3(1, MB128), 256, 0, stream>>>(hb, JKW, Btgh, bg1, nullptr, nullptr, nullptr,
                                                    Wg2, gate, N, JKW);

  k_gatt<<<NGRAPH, 256, 0, stream>>>(gate, batch, N);
  dim3 g3(NGRAPH, 32);
  k_pool<<<g3, 320, 0, stream>>>(hb, gate, batch, N, pooled);
  k_head<<<NGRAPH, 320, 0, stream>>>(pooled, Wh1, bh1, Wh2, bh2, out);
}

// Round 13
// 414.677 us; speedup vs baseline: 1.2441x; 1.0168x over previous
//
#include <hip/hip_runtime.h>
#include <math.h>
#include <stddef.h>

#define NHEAD 4
#define DHEAD 40
#define HIDW 160
#define JKW 320
#define NGRAPH 32
#define BCAP 64   // edge bucket capacity per node (deg ~ Poisson(10); P(>63) ~ 1e-31)

typedef __attribute__((ext_vector_type(8))) short short8;
typedef __attribute__((ext_vector_type(4))) float f32x4;
typedef __attribute__((ext_vector_type(2))) float f32x2;
typedef __fp16 h2 __attribute__((ext_vector_type(2)));
typedef int i32x4 __attribute__((ext_vector_type(4)));
typedef i32x4 i32x4_a4 __attribute__((aligned(4)));

__device__ inline unsigned short f2bf(float x){
  unsigned u = __float_as_uint(x);
  u += 0x7fff + ((u >> 16) & 1);
  return (unsigned short)(u >> 16);
}
__device__ inline float bf2f(unsigned short h){
  return __uint_as_float(((unsigned)h) << 16);
}
__device__ inline float fdot2(h2 a, h2 b, float c){
  return __builtin_amdgcn_fdot2(a, b, c, false);
}
__device__ inline h2 pk(float a, float b){
  return __builtin_amdgcn_cvt_pkrtz(a, b);
}
union HU { h2 h; int i; unsigned u; float f; };
__device__ inline h2 shfl_h2(h2 v, int xm){
  HU u; u.h = v; u.i = __shfl_xor(u.i, xm); return u.h;
}
__device__ inline h2 asH2(unsigned i){ HU u; u.u = i; return u.h; }

#if __has_builtin(__builtin_amdgcn_cvt_pk_f16_fp8)
__device__ inline h2 cvt8(int s){ return __builtin_amdgcn_cvt_pk_f16_fp8((short)s); }
#else
__device__ inline h2 cvt8(int s){
  f32x2 t = __builtin_amdgcn_cvt_pk_f32_fp8(s, false);
  return pk(t.x, t.y);
}
#endif

__device__ inline int lbound(const int* __restrict__ b, int N, int g){
  int lo = 0, hi = N;
  while (lo < hi){ int mid = (lo + hi) >> 1; if (b[mid] < g) lo = mid + 1; else hi = mid; }
  return lo;
}

// ---------------- fused pre-pass: zero buffers + lin_in + weight pack ----------------
// v3: lin_in vectorized (8 out/thread); Bth pack reads coalesced.
__global__ __launch_bounds__(256) void k_pre(const float* __restrict__ x, const float* __restrict__ W_in,
                                             const float* __restrict__ b_in, unsigned short* __restrict__ hb,
                                             const float* __restrict__ Wq, const float* __restrict__ Wk,
                                             const float* __restrict__ Wv, const float* __restrict__ Ws,
                                             const float* __restrict__ bq, const float* __restrict__ bk,
                                             const float* __restrict__ bv, const float* __restrict__ bs,
                                             const float* __restrict__ Wg1,
                                             unsigned short* __restrict__ Bth, float* __restrict__ bp,
                                             unsigned short* __restrict__ Btgh,
                                             int* __restrict__ cnt, float* __restrict__ gate,
                                             float* __restrict__ pooled, int N){
  int NL = (N*20 + 255)/256;
  int bid = blockIdx.x, tid = threadIdx.x;
  if (bid < NL){
    int idx = bid*256 + tid;
    if (idx >= N*20) return;
    int n = idx / 20, j8 = (idx % 20)*8;
    const float* xr = x + n*5;
    float x0 = xr[0], x1 = xr[1], x2 = xr[2], x3 = xr[3], x4 = xr[4];
    float v[8];
    #pragma unroll
    for (int u = 0; u < 8; ++u) v[u] = b_in[j8+u];
    #pragma unroll
    for (int c = 0; c < 5; ++c){
      float xc = (c==0)?x0:(c==1)?x1:(c==2)?x2:(c==3)?x3:x4;
      const float4 wa = *(const float4*)(W_in + c*HIDW + j8);
      const float4 wb = *(const float4*)(W_in + c*HIDW + j8 + 4);
      v[0] += xc*wa.x; v[1] += xc*wa.y; v[2] += xc*wa.z; v[3] += xc*wa.w;
      v[4] += xc*wb.x; v[5] += xc*wb.y; v[6] += xc*wb.z; v[7] += xc*wb.w;
    }
    short8 o;
    #pragma unroll
    for (int u = 0; u < 8; ++u) o[u] = (short)f2bf(v[u]);
    *(short8*)(hb + (size_t)n*JKW + j8) = o;
  } else if (bid < NL + 1005){
    int idx = (bid - NL)*256 + tid;
    if (idx < 204800){
      int l = idx / 102400, r = idx % 102400;
      int i = r / 640, j = r % 640;            // consecutive tid -> consecutive jj (coalesced W reads)
      int sel = j / HIDW, jj = j % HIDW;
      const float* W = (sel==0) ? Wq : (sel==1) ? Wk : (sel==2) ? Wv : Ws;
      Bth[(size_t)l*102400 + (size_t)j*160 + i] = f2bf(W[(size_t)l*25600 + i*HIDW + jj]);
    } else if (idx < 256000){
      int r = idx - 204800;
      int j = r / 320, i = r % 320;
      Btgh[(size_t)j*320 + i] = f2bf(Wg1[(size_t)i*160 + j]);
    } else if (idx < 257280){
      int r = idx - 256000;
      int l = r / 640, j = r % 640;
      int sel = j / HIDW, jj = j % HIDW;
      const float* bb = (sel==0) ? bq : (sel==1) ? bk : (sel==2) ? bv : bs;
      bp[l*640 + j] = bb[l*160 + jj];
    }
  } else {
    int idx = (bid - NL - 1005)*256 + tid;
    if (idx < N){ cnt[idx] = 0; gate[idx] = 0.f; }
    if (idx < NGRAPH*JKW) pooled[idx] = 0.f;
  }
}

// ---------------- bucketed edge fill ----------------
// v2: single 16B record {src, ea01, ea23, pad} -- one scattered store per edge.
__global__ __launch_bounds__(256) void k_fill(const int* __restrict__ dst, const int* __restrict__ src,
                                              const float* __restrict__ edge_attr, int E,
                                              int* __restrict__ cnt, uint4* __restrict__ edges){
  int e = blockIdx.x*256 + threadIdx.x;
  if (e < E){
    int d = dst[e];
    int p = atomicAdd(&cnt[d], 1);
    if (p < BCAP){
      float4 ea = *(const float4*)(edge_attr + (size_t)e*4);
      HU a, b; a.h = pk(ea.x, ea.y); b.h = pk(ea.z, ea.w);
      edges[(size_t)d*BCAP + p] = make_uint4((unsigned)src[e], a.u, b.u, 0u);
    }
  }
}

// ---------------- bf16 MFMA GEMM v10: TRANSPOSED fragments for packed stores ----------------
// R12 counters: MfmaUtil 5.7%, VALU 17%, occ 27% -- epilogue was 32M scalar
// stores (64 x 1-2B per thread) = ~52us of pure store issue. Fix: swap MFMA
// operands (mfma(bh, ah) computes C^T in-register; operand fragments are
// k-major-symmetric so loads unchanged). Each lane now owns 4 CONSECUTIVE
// cols of one row per (g,s): qh/rskip = one 8B uint2 store; kv8 = two 2B
// stores (fp8 pairs). 160%4==0 -> 4-col groups never straddle sel regions.
// MODE 2: per-row sum reduced over quad (xor16/32), direct gate store.
#define BSTR 40
#define BSTR1 164
template<int NSUB, int MODE>
__global__ __launch_bounds__(256) void k_mgemm(const unsigned short* __restrict__ A, int lda,
                                               const unsigned short* __restrict__ Bh,
                                               const float* __restrict__ bias,
                                               _Float16* __restrict__ qh,
                                               unsigned char* __restrict__ kv8,
                                               _Float16* __restrict__ rskip,
                                               const float* __restrict__ Wg2,
                                               float* __restrict__ gate,
                                               int M, int K){
  __shared__ short sBh[(MODE==1) ? (16*NSUB*BSTR1) : (2*16*NSUB*BSTR)];
  int tid = threadIdx.x;
  int wv = tid >> 6, lane = tid & 63;
  int quad = lane >> 4, l16 = lane & 15;

  int P = gridDim.x, MBy = gridDim.y;
  int bid = blockIdx.y * P + blockIdx.x;       // dispatch-order linear id
  int fullRows = (MBy >> 3) << 3;
  int rowB, panel;
  if (bid < fullRows * P){
    int group = bid / (8*P), rem = bid % (8*P);
    rowB  = group*8 + (rem & 7);
    panel = rem >> 3;
  } else {
    int rem = bid - fullRows*P;
    int R = MBy - fullRows;                    // 1..7 tail rows
    panel = rem / R;
    rowB  = fullRows + rem % R;
  }
  int m0 = rowB*128 + wv*32;
  int col0 = panel * (16*NSUB);

  int ar0 = m0 + l16;      if (ar0 >= M) ar0 = M - 1;
  int ar1 = m0 + 16 + l16; if (ar1 >= M) ar1 = M - 1;
  const unsigned short* Ap0 = A + (size_t)ar0*lda + quad*8;
  const unsigned short* Ap1 = A + (size_t)ar1*lda + quad*8;

  f32x4 acc[2][NSUB];
  #pragma unroll
  for (int g = 0; g < 2; ++g)
    #pragma unroll
    for (int s = 0; s < NSUB; ++s) acc[g][s] = (f32x4){0.f,0.f,0.f,0.f};

  if constexpr (MODE == 1){
    for (int u = tid; u < 16*NSUB*20; u += 256){
      int col = u / 20, q = u % 20;
      *(short8*)(&sBh[col*BSTR1 + q*8]) =
        *(const short8*)(Bh + (size_t)(col0 + col)*K + q*8);
    }
    __syncthreads();
    #pragma unroll
    for (int kk = 0; kk < 5; ++kk){
      int k0 = kk << 5;
      short8 ah0 = *(const short8*)(Ap0 + k0);
      short8 ah1 = *(const short8*)(Ap1 + k0);
      #pragma unroll
      for (int s = 0; s < NSUB; ++s){
        short8 bh = *(const short8*)(&sBh[(s*16 + l16)*BSTR1 + k0 + quad*8]);
        acc[0][s] = __builtin_amdgcn_mfma_f32_16x16x32_bf16(bh, ah0, acc[0][s], 0, 0, 0);
        acc[1][s] = __builtin_amdgcn_mfma_f32_16x16x32_bf16(bh, ah1, acc[1][s], 0, 0, 0);
      }
    }
  } else {
    const int CH = K >> 5;
    for (int u = tid; u < 16*NSUB*4; u += 256){
      int col = u >> 2, q4 = u & 3;
      *(short8*)(&sBh[col*BSTR + q4*8]) =
        *(const short8*)(Bh + (size_t)(col0 + col)*K + q4*8);
    }
    __syncthreads();
    int buf = 0;
    for (int kk = 0; kk < CH; ++kk){
      int k0 = kk << 5;
      if (kk + 1 < CH){
        int kn = k0 + 32;
        for (int u = tid; u < 16*NSUB*4; u += 256){
          int col = u >> 2, q4 = u & 3;
          *(short8*)(&sBh[(buf^1)*16*NSUB*BSTR + col*BSTR + q4*8]) =
            *(const short8*)(Bh + (size_t)(col0 + col)*K + kn + q4*8);
        }
      }
      short8 ah0 = *(const short8*)(Ap0 + k0);
      short8 ah1 = *(const short8*)(Ap1 + k0);
      #pragma unroll
      for (int s = 0; s < NSUB; ++s){
        short8 bh = *(const short8*)(&sBh[buf*16*NSUB*BSTR + (s*16 + l16)*BSTR + quad*8]);
        acc[0][s] = __builtin_amdgcn_mfma_f32_16x16x32_bf16(bh, ah0, acc[0][s], 0, 0, 0);
        acc[1][s] = __builtin_amdgcn_mfma_f32_16x16x32_bf16(bh, ah1, acc[1][s], 0, 0, 0);
      }
      __syncthreads();
      buf ^= 1;
    }
  }

  const float qscale = 0.15811388300841898f; // 1/sqrt(40)
  if (MODE == 1){
    #pragma unroll
    for (int g = 0; g < 2; ++g){
      int row = m0 + g*16 + l16;
      if (row >= M) continue;
      #pragma unroll
      for (int s = 0; s < NSUB; ++s){
        int col4 = col0 + s*16 + quad*4;
        int sel = col4 / 160, cc4 = col4 % 160;
        const float4 bv = *(const float4*)(bias + col4);
        float v0 = acc[g][s][0] + bv.x;
        float v1 = acc[g][s][1] + bv.y;
        float v2 = acc[g][s][2] + bv.z;
        float v3 = acc[g][s][3] + bv.w;
        if (sel == 0){
          HU a, b; a.h = pk(v0*qscale, v1*qscale); b.h = pk(v2*qscale, v3*qscale);
          *(uint2*)(qh + (size_t)row*160 + cc4) = make_uint2(a.u, b.u);
        } else if (sel == 3){
          HU a, b; a.h = pk(v0, v1); b.h = pk(v2, v3);
          *(uint2*)(rskip + (size_t)row*160 + cc4) = make_uint2(a.u, b.u);
        } else {
          int slot = (cc4/40)*4 + (cc4%40)/10, j = cc4%10;
          int off = (sel==2) ? 10 : 0;
          unsigned short e01 = (unsigned short)(__builtin_amdgcn_cvt_pk_fp8_f32(v0, v1, 0, false) & 0xffff);
          unsigned short e23 = (unsigned short)(__builtin_amdgcn_cvt_pk_fp8_f32(v2, v3, 0, false) & 0xffff);
          unsigned char* base = kv8 + (size_t)row*320;
          if (j <= 6){
            *(unsigned short*)(base + slot*20 + off + j)     = e01;
            *(unsigned short*)(base + slot*20 + off + j + 2) = e23;
          } else { // j == 8: split across slot boundary (slot+1 correct incl. 40-crossing)
            *(unsigned short*)(base + slot*20 + off + 8)     = e01;
            *(unsigned short*)(base + (slot+1)*20 + off + 0) = e23;
          }
        }
      }
    }
  } else {
    float vg0 = 0.f, vg1 = 0.f;
    #pragma unroll
    for (int s = 0; s < NSUB; ++s){
      int col4 = col0 + s*16 + quad*4;
      const float4 bv = *(const float4*)(bias + col4);
      const float4 wg = *(const float4*)(Wg2 + col4);
      vg0 += fmaxf(acc[0][s][0]+bv.x,0.f)*wg.x + fmaxf(acc[0][s][1]+bv.y,0.f)*wg.y
           + fmaxf(acc[0][s][2]+bv.z,0.f)*wg.z + fmaxf(acc[0][s][3]+bv.w,0.f)*wg.w;
      vg1 += fmaxf(acc[1][s][0]+bv.x,0.f)*wg.x + fmaxf(acc[1][s][1]+bv.y,0.f)*wg.y
           + fmaxf(acc[1][s][2]+bv.z,0.f)*wg.z + fmaxf(acc[1][s][3]+bv.w,0.f)*wg.w;
    }
    vg0 += __shfl_xor(vg0, 16); vg0 += __shfl_xor(vg0, 32);
    vg1 += __shfl_xor(vg1, 16); vg1 += __shfl_xor(vg1, 32);
    if (quad == 0){
      int row0 = m0 + l16, row1 = m0 + 16 + l16;
      if (row0 < M) gate[row0] = vg0;
      if (row1 < M) gate[row1] = vg1;
    }
  }
}

// ---------------- per-node q-projection precompute ----------------
__global__ __launch_bounds__(256) void k_qprep(const _Float16* __restrict__ qh,
                                               const float* __restrict__ We, const float* __restrict__ be,
                                               float* __restrict__ qwb, int N){
  int idx = blockIdx.x*256 + threadIdx.x;
  if (idx >= N*4) return;
  int n = idx >> 2, h = idx & 3;
  const unsigned* qp = (const unsigned*)(qh + (size_t)n*160 + h*40);
  float w0=0.f,w1=0.f,w2=0.f,w3=0.f,b=0.f;
  #pragma unroll
  for (int i = 0; i < 20; ++i){
    HU u; u.u = qp[i];
    float qa = (float)u.h.x, qb = (float)u.h.y;
    int c = h*40 + 2*i;
    w0 += qa*We[c]       + qb*We[c+1];
    w1 += qa*We[160+c]   + qb*We[161+c];
    w2 += qa*We[320+c]   + qb*We[321+c];
    w3 += qa*We[480+c]   + qb*We[481+c];
    b  += qa*be[c]       + qb*be[c+1];
  }
  float* o = qwb + (size_t)idx*5;
  o[0]=w0; o[1]=w1; o[2]=w2; o[3]=w3; o[4]=b;
}

// ---------------- fused edge attention + beta gate (fp8 kv, no-max softmax) ----------------
// v9: 2-wide edge pipeline (measured best, R12).
__global__ __launch_bounds__(256) void k_attn(const _Float16* __restrict__ qh,
                                              const unsigned char* __restrict__ kv8,
                                              const _Float16* __restrict__ rskip,
                                              const float* __restrict__ qwb,
                                              const uint4* __restrict__ edges,
                                              const int* __restrict__ cnt,
                                              const float* __restrict__ We, const float* __restrict__ be,
                                              const float* __restrict__ Wb,
                                              unsigned short* __restrict__ hb,
                                              int loff, int N){
  int tid = threadIdx.x;
  int grp = tid >> 4;                 // 16 groups per block
  int n = blockIdx.x*16 + grp;
  bool valid = (n < N);
  int nn = valid ? n : (N-1);
  int w = tid & 15;
  int hh = w & 3, t = w >> 2;
  int cbase = DHEAD*hh + 10*t;
  int slot = hh*4 + t;

  h2 qh2[5];
  {
    const unsigned* qp = (const unsigned*)(qh + (size_t)nn*160 + cbase);
    #pragma unroll
    for (int i = 0; i < 5; ++i) qh2[i] = asH2(qp[i]);
  }
  const float* qwp = qwb + ((size_t)nn*4 + hh)*5;
  float qw0 = qwp[0], qw1 = qwp[1], qw2 = qwp[2], qw3 = qwp[3], qb = qwp[4];
  h2 qw01 = pk(qw0, qw1), qw23 = pk(qw2, qw3);

  float ssum = 0.f;
  h2 zh = pk(0.f, 0.f);
  h2 acch[5], sah[2];
  #pragma unroll
  for (int i = 0; i < 5; ++i) acch[i] = zh;
  sah[0] = zh; sah[1] = zh;

  int deg = 0;
  if (valid){ deg = cnt[nn]; if (deg > BCAP) deg = BCAP; }
  int st = nn*BCAP;

  // pipeline: records r0..r3 for edges e..e+3; kv for e, e+1 in registers
  uint4 r0 = make_uint4(0,0,0,0), r1 = make_uint4(0,0,0,0);
  uint4 r2 = make_uint4(0,0,0,0), r3 = make_uint4(0,0,0,0);
  i32x4 k0v = {0,0,0,0}, k1v = {0,0,0,0}; int k0e = 0, k1e = 0;
  if (deg > 0) r0 = edges[st];
  if (deg > 1) r1 = edges[st+1];
  if (deg > 2) r2 = edges[st+2];
  if (deg > 3) r3 = edges[st+3];
  if (deg > 0){
    const unsigned char* kp = kv8 + (size_t)r0.x*320 + slot*20;
    k0v = *(const i32x4_a4*)kp; k0e = *(const int*)(kp+16);
  }
  if (deg > 1){
    const unsigned char* kp = kv8 + (size_t)r1.x*320 + slot*20;
    k1v = *(const i32x4_a4*)kp; k1e = *(const int*)(kp+16);
  }

  for (int e = 0; e < deg; e += 2){
    // prefetch records e+4, e+5
    uint4 n0 = make_uint4(0,0,0,0), n1 = make_uint4(0,0,0,0);
    if (e + 4 < deg) n0 = edges[st + e + 4];
    if (e + 5 < deg) n1 = edges[st + e + 5];
    // prefetch kv e+2, e+3 (records arrived last iteration)
    i32x4 k2v = {0,0,0,0}, k3v = {0,0,0,0}; int k2e = 0, k3e = 0;
    if (e + 2 < deg){
      const unsigned char* kp = kv8 + (size_t)r2.x*320 + slot*20;
      k2v = *(const i32x4_a4*)kp; k2e = *(const int*)(kp+16);
    }
    if (e + 3 < deg){
      const unsigned char* kp = kv8 + (size_t)r3.x*320 + slot*20;
      k3v = *(const i32x4_a4*)kp; k3e = *(const int*)(kp+16);
    }
    // two independent score chains (edge e, edge e+1)
    bool v1 = (e + 1 < deg);
    h2 ea00 = asH2(r0.y), ea01 = asH2(r0.z);
    h2 ea10 = asH2(r1.y), ea11 = asH2(r1.z);
    float p0 = 0.f, p1 = 0.f;
    p0 = fdot2(qh2[0], cvt8(k0v.x), p0);       p1 = fdot2(qh2[0], cvt8(k1v.x), p1);
    p0 = fdot2(qh2[1], cvt8(k0v.x >> 16), p0); p1 = fdot2(qh2[1], cvt8(k1v.x >> 16), p1);
    p0 = fdot2(qh2[2], cvt8(k0v.y), p0);       p1 = fdot2(qh2[2], cvt8(k1v.y), p1);
    p0 = fdot2(qh2[3], cvt8(k0v.y >> 16), p0); p1 = fdot2(qh2[3], cvt8(k1v.y >> 16), p1);
    p0 = fdot2(qh2[4], cvt8(k0v.z), p0);       p1 = fdot2(qh2[4], cvt8(k1v.z), p1);
    p0 += __shfl_xor(p0, 4);                   p1 += __shfl_xor(p1, 4);
    p0 += __shfl_xor(p0, 8);                   p1 += __shfl_xor(p1, 8);
    p0 += qb;                                  p1 += qb;
    p0 = fdot2(ea00, qw01, p0);                p1 = fdot2(ea10, qw01, p1);
    p0 = fdot2(ea01, qw23, p0);                p1 = fdot2(ea11, qw23, p1);

    float ex0 = __expf(p0);
    float ex1 = v1 ? __expf(p1) : 0.f;
    ssum += ex0;
    ssum += ex1;
    h2 eh0 = pk(ex0, ex0), eh1 = pk(ex1, ex1);
    acch[0] += cvt8(k0v.z >> 16)*eh0;  acch[0] += cvt8(k1v.z >> 16)*eh1;
    acch[1] += cvt8(k0v.w)*eh0;        acch[1] += cvt8(k1v.w)*eh1;
    acch[2] += cvt8(k0v.w >> 16)*eh0;  acch[2] += cvt8(k1v.w >> 16)*eh1;
    acch[3] += cvt8(k0e)*eh0;          acch[3] += cvt8(k1e)*eh1;
    acch[4] += cvt8(k0e >> 16)*eh0;    acch[4] += cvt8(k1e >> 16)*eh1;
    sah[0] += ea00*eh0;                sah[0] += ea10*eh1;
    sah[1] += ea01*eh0;                sah[1] += ea11*eh1;

    r0 = r2; r1 = r3; r2 = n0; r3 = n1;
    k0v = k2v; k0e = k2e; k1v = k3v; k1e = k3e;
  }

  // epilogue: each lane owns cols cbase..cbase+9
  {
    float inv = (ssum > 0.f) ? 1.f/ssum : 0.f;
    float sw0 = (float)sah[0].x*inv, sw1 = (float)sah[0].y*inv;
    float sw2 = (float)sah[1].x*inv, sw3 = (float)sah[1].y*inv;
    float bterm = (ssum > 0.f) ? 1.f : 0.f;

    const unsigned* rpu = (const unsigned*)(rskip + (size_t)nn*160 + cbase);
    float o[10];
    float part = 0.f;
    #pragma unroll
    for (int i = 0; i < 5; ++i){
      int c = cbase + 2*i;
      float o0 = (float)acch[i].x*inv + sw0*We[c]   + sw1*We[160+c] + sw2*We[320+c] + sw3*We[480+c] + bterm*be[c];
      float o1 = (float)acch[i].y*inv + sw0*We[c+1] + sw1*We[161+c] + sw2*We[321+c] + sw3*We[481+c] + bterm*be[c+1];
      HU u; u.u = rpu[i];
      float r0f = (float)u.h.x, r1f = (float)u.h.y;
      part += o0*Wb[c]   + r0f*Wb[160+c] + (o0-r0f)*Wb[320+c];
      part += o1*Wb[c+1] + r1f*Wb[161+c] + (o1-r1f)*Wb[321+c];
      o[2*i] = o0; o[2*i+1] = o1;
    }
    part += __shfl_xor(part, 1); part += __shfl_xor(part, 2);
    part += __shfl_xor(part, 4); part += __shfl_xor(part, 8);
    float beta = 1.f/(1.f + __expf(-part));
    if (valid){
      unsigned* hp32 = (unsigned*)(hb + (size_t)nn*JKW + loff);
      #pragma unroll
      for (int i = 0; i < 5; ++i){
        HU u; u.u = rpu[i];
        float r0f = (float)u.h.x, r1f = (float)u.h.y;
        unsigned lo = f2bf(beta*r0f + (1.f-beta)*o[2*i]);
        unsigned hi = f2bf(beta*r1f + (1.f-beta)*o[2*i+1]);
        hp32[cbase/2 + i] = lo | (hi << 16);
      }
    }
  }
}

// ---------------- per-graph gate stats + in-place att normalization ----------------
__global__ __launch_bounds__(256) void k_gatt(float* __restrict__ gate, const int* __restrict__ batch, int N){
  __shared__ float sm[256];
  int g = blockIdx.x, j = threadIdx.x;
  int lo = lbound(batch, N, g), hi = lbound(batch, N, g+1);
  if (hi <= lo) return;
  float m = -INFINITY;
  for (int i = lo + j; i < hi; i += 256) m = fmaxf(m, gate[i]);
  sm[j] = m; __syncthreads();
  #pragma unroll
  for (int off = 128; off; off >>= 1){
    if (j < off) sm[j] = fmaxf(sm[j], sm[j+off]);
    __syncthreads();
  }
  float gm = sm[0]; __syncthreads();
  float s = 0.f;
  for (int i = lo + j; i < hi; i += 256) s += __expf(gate[i] - gm);
  sm[j] = s; __syncthreads();
  #pragma unroll
  for (int off = 128; off; off >>= 1){
    if (j < off) sm[j] += sm[j+off];
    __syncthreads();
  }
  float dg = sm[0];
  float invd = (dg > 0.f) ? 1.f/dg : 0.f;
  for (int i = lo + j; i < hi; i += 256) gate[i] = __expf(gate[i] - gm) * invd;
}

// ---------------- attention pooling: pure weighted accumulation ----------------
__global__ __launch_bounds__(320) void k_pool(const unsigned short* __restrict__ hb, const float* __restrict__ gate,
                                              const int* __restrict__ batch, int N,
                                              float* __restrict__ pooled){
  int g = blockIdx.x, part = blockIdx.y, j = threadIdx.x;
  int lo = lbound(batch, N, g), hi = lbound(batch, N, g+1);
  int len = hi - lo;
  if (len <= 0) return;
  int chunk = (len + (int)gridDim.y - 1) / (int)gridDim.y;
  int a = lo + part*chunk;
  int bnd = a + chunk; if (bnd > hi) bnd = hi;
  if (a >= bnd) return;
  float acc = 0.f;
  #pragma unroll 2
  for (int n = a; n < bnd; ++n){
    acc += gate[n] * bf2f(hb[(size_t)n*JKW + j]);
  }
  atomicAdd(&pooled[g*JKW + j], acc);
}

__global__ __launch_bounds__(320) void k_head(const float* __restrict__ pooled, const float* __restrict__ Wh1,
                                              const float* __restrict__ bh1, const float* __restrict__ Wh2,
                                              const float* __restrict__ bh2, float* __restrict__ out){
  __shared__ float p[320];
  __shared__ float t[320];
  int g = blockIdx.x, tid = threadIdx.x;
  p[tid] = pooled[g*JKW + tid]; __syncthreads();
  float a = bh1[tid];
  for (int i = 0; i < 320; ++i) a += p[i]*Wh1[i*JKW + tid];
  t[tid] = fmaxf(a, 0.f); __syncthreads();
  if (tid < 6){
    float o = bh2[tid];
    for (int j = 0; j < 320; ++j) o += t[j]*Wh2[j*6 + tid];
    out[g*6 + tid] = o;
  }
}

extern "C" void kernel_launch(void* const* d_in, const int* in_sizes, int n_in,
                              void* d_out, int out_size, void* d_ws, size_t ws_size,
                              hipStream_t stream){
  (void)n_in; (void)out_size; (void)ws_size;
  const float* x        = (const float*)d_in[0];
  const int*   eidx     = (const int*)d_in[1];
  const float* edge_attr= (const float*)d_in[2];
  const int*   batch    = (const int*)d_in[3];
  const float* W_in     = (const float*)d_in[4];
  const float* b_in     = (const float*)d_in[5];
  const float* Wq       = (const float*)d_in[6];
  const float* bq       = (const float*)d_in[7];
  const float* Wk       = (const float*)d_in[8];
  const float* bk       = (const float*)d_in[9];
  const float* Wv       = (const float*)d_in[10];
  const float* bv       = (const float*)d_in[11];
  const float* We       = (const float*)d_in[12];
  const float* be       = (const float*)d_in[13];
  const float* Wsk      = (const float*)d_in[14];
  const float* bsk      = (const float*)d_in[15];
  const float* Wb       = (const float*)d_in[16];
  const float* Wg1      = (const float*)d_in[17];
  const float* bg1      = (const float*)d_in[18];
  const float* Wg2      = (const float*)d_in[19];
  const float* Wh1      = (const float*)d_in[21];
  const float* bh1      = (const float*)d_in[22];
  const float* Wh2      = (const float*)d_in[23];
  const float* bh2      = (const float*)d_in[24];

  const int N = in_sizes[0] / 5;
  const int E = in_sizes[1] / 2;
  float* out = (float*)d_out;

  char* w = (char*)d_ws;
  auto alloc = [&](size_t bytes)->char*{ char* p = w; w += (bytes + 255) & ~(size_t)255; return p; };
  unsigned short* hb = (unsigned short*)alloc((size_t)N*JKW*2);
  _Float16* qh  = (_Float16*)alloc((size_t)N*160*2);
  unsigned char* kv8 = (unsigned char*)alloc((size_t)N*320);
  _Float16* rskip = (_Float16*)alloc((size_t)N*160*2);
  float* qwb    = (float*)alloc((size_t)N*20*4);
  unsigned short* Bth  = (unsigned short*)alloc((size_t)2*640*160*2);
  unsigned short* Btgh = (unsigned short*)alloc((size_t)160*320*2);
  float* bpack  = (float*)alloc((size_t)2*640*4);
  int*   cnt    = (int*)alloc((size_t)N*4);
  uint4* edges  = (uint4*)alloc((size_t)N*BCAP*16);
  float* gate   = (float*)alloc((size_t)N*4);
  float* pooled = (float*)alloc(NGRAPH*JKW*4);

  const int* srcI = eidx;
  const int* dstI = eidx + E;

  const int NL = (N*20 + 255)/256;
  const int NZ = (N + 255)/256;
  k_pre<<<NL + 1005 + NZ, 256, 0, stream>>>(x, W_in, b_in, hb,
                                            Wq, Wk, Wv, Wsk, bq, bk, bv, bsk, Wg1,
                                            Bth, bpack, Btgh, cnt, gate, pooled, N);

  const int eb = (E + 255)/256;
  k_fill<<<eb, 256, 0, stream>>>(dstI, srcI, edge_attr, E, cnt, edges);

  const int MB128 = (N + 127)/128;
  for (int l = 0; l < 2; ++l){
    dim3 g1(5, MB128);
    k_mgemm<8,1><<<g1, 256, 0, stream>>>(hb, JKW, Bth + (size_t)l*102400, bpack + l*640,
                                         qh, kv8, rskip, nullptr, nullptr, N, HIDW);
    k_qprep<<<(N*4 + 255)/256, 256, 0, stream>>>(qh, We + l*640, be + l*160, qwb, N);
    k_attn<<<(N + 15)/16, 256, 0, stream>>>(qh, kv8, rskip, qwb, edges, cnt,
                                            We + l*640, be + l*160, Wb + l*480, hb, l*HIDW, N);
  }

  k_mgemm<10,2><<<dim3(1, MB128), 256, 0, stream>>>(hb, JKW, Btgh, bg1, nullptr, nullptr, nullptr,
                                                    Wg2, gate, N, JKW);

  k_gatt<<<NGRAPH, 256, 0, stream>>>(gate, batch, N);
  dim3 g3(NGRAPH, 32);
  k_pool<<<g3, 320, 0, stream>>>(hb, gate, batch, N, pooled);
  k_head<<<NGRAPH, 320, 0, stream>>>(pooled, Wh1, bh1, Wh2, bh2, out);
}